// Round 16
// baseline (122.779 us; speedup 1.0000x reference)
//
#include <hip/hip_runtime.h>
#include <math.h>

constexpr int Dm  = 1024;
constexpr int NH  = 16;
constexpr int SQ  = 2048;
constexpr int NB  = 2;

typedef float f32x4 __attribute__((ext_vector_type(4)));
typedef float f32x16 __attribute__((ext_vector_type(16)));
typedef short bf16x8 __attribute__((ext_vector_type(8)));
typedef __attribute__((address_space(3))) unsigned int lds_u32;
typedef __attribute__((address_space(1))) const unsigned int glb_u32;

__device__ __forceinline__ void gload_lds16(const void* g, void* l) {
    __builtin_amdgcn_global_load_lds((glb_u32*)(uintptr_t)g, (lds_u32*)(uintptr_t)l, 16, 0, 0);
}

__device__ __forceinline__ unsigned short bf_round(float x) {
    unsigned u = __float_as_uint(x);
    unsigned r = u + 0x7fffu + ((u >> 16) & 1u);
    return (unsigned short)(r >> 16);
}

__device__ __forceinline__ float exp2_fast(float x) {
    float r;
    asm("v_exp_f32 %0, %1" : "=v"(r) : "v"(x));
    return r;
}

__device__ __forceinline__ unsigned cvt_pk(float lo, float hi_) {
    unsigned r;
    asm("v_cvt_pk_bf16_f32 %0, %1, %2" : "=v"(r) : "v"(lo), "v"(hi_));
    return r;
}

__device__ __forceinline__ void permlane_swap(unsigned& a, unsigned& b) {
    asm volatile("v_permlane32_swap_b32 %0, %1" : "+v"(a), "+v"(b));
}

__device__ __forceinline__ bf16x8 make_frag(unsigned a, unsigned b, unsigned c, unsigned d) {
    union { unsigned u[4]; bf16x8 v; } uu;
    uu.u[0] = a; uu.u[1] = b; uu.u[2] = c; uu.u[3] = d;
    return uu.v;
}

__device__ __forceinline__ float bfu2f(unsigned lo16) {
    return __uint_as_float(lo16 << 16);
}

// ---------------- prologue: W transpose (z=0..3) + x fp32->bf16 (z=4) ----------------
__global__ __launch_bounds__(256) void prologue(const float* __restrict__ x,
                                                const float* __restrict__ Wq,
                                                const float* __restrict__ Wk,
                                                const float* __restrict__ Wv,
                                                const float* __restrict__ Wo,
                                                unsigned short* __restrict__ xb,
                                                unsigned short* __restrict__ wt) {
    const int z = blockIdx.z;
    const int tid = threadIdx.x;
    if (z == 4) {
        size_t base = ((size_t)blockIdx.y * 16 + blockIdx.x) * 16384;
#pragma unroll
        for (int it = 0; it < 8; ++it) {
            size_t i = base + (size_t)it * 2048 + (size_t)tid * 8;
            float4 a = *(const float4*)&x[i];
            float4 b = *(const float4*)&x[i + 4];
            unsigned short o8[8] __attribute__((aligned(16)));
            o8[0] = bf_round(a.x); o8[1] = bf_round(a.y); o8[2] = bf_round(a.z); o8[3] = bf_round(a.w);
            o8[4] = bf_round(b.x); o8[5] = bf_round(b.y); o8[6] = bf_round(b.z); o8[7] = bf_round(b.w);
            *(uint4*)&xb[i] = *(const uint4*)o8;
        }
        return;
    }
    const float* W = (z == 0) ? Wq : (z == 1) ? Wk : (z == 2) ? Wv : Wo;
    unsigned short* dst = wt + (size_t)z * Dm * Dm;
    __shared__ float T[64][65];
    const int k0 = blockIdx.x * 64, n0 = blockIdx.y * 64;
#pragma unroll
    for (int i = 0; i < 4; ++i) {
        int s = tid + i * 256;
        int kk = s >> 4, c = (s & 15) * 4;
        *(float4*)&T[kk][c] = *(const float4*)&W[(size_t)(k0 + kk) * Dm + n0 + c];
    }
    __syncthreads();
#pragma unroll
    for (int i = 0; i < 2; ++i) {
        int s = tid + i * 256;
        int n = s >> 3, c8 = (s & 7) * 8;
        unsigned short o8[8] __attribute__((aligned(16)));
#pragma unroll
        for (int j = 0; j < 8; ++j) o8[j] = bf_round(T[c8 + j][n]);
        *(uint4*)&dst[(size_t)(n0 + n) * Dm + k0 + c8] = *(const uint4*)o8;
    }
}

// ====================================================================
// 2-phase 256x192 QKV GEMM (round-13 verified)
// ====================================================================
__global__ __launch_bounds__(512) void gemm_qkv192(
    const unsigned short* __restrict__ xb,
    const unsigned short* __restrict__ wt,
    const float* __restrict__ bq, const float* __restrict__ bk,
    const float* __restrict__ bv,
    unsigned short* __restrict__ qbuf, unsigned short* __restrict__ kbuf,
    unsigned short* __restrict__ vtbuf)
{
    __shared__ unsigned short Alds[2][256 * 64];
    __shared__ unsigned short Blds[2][192 * 64];

    const int tid = threadIdx.x;
    const int lane = tid & 63, wid = tid >> 6;
    const int wm = wid >> 2, wn = wid & 3;
    const int l15 = lane & 15, lg = lane >> 4;

    const int bid = blockIdx.x;
    const int swz = (bid & 7) * 32 + (bid >> 3);
    const int bx = swz & 15, by = swz >> 4;
    const int m0 = by * 256, n0 = bx * 192;

    const int srow = wid * 8 + (lane >> 3);
    const int scol = ((lane & 7) ^ ((lane >> 3) & 7)) * 8;

    const unsigned short* Abase = xb + (size_t)m0 * Dm;
    const unsigned short* Bbase = wt + (size_t)n0 * Dm;

#define STAGE_TILE(t)                                                              \
    do {                                                                           \
        const unsigned short* As_ = Abase + (t) * 64;                              \
        const unsigned short* Bs_ = Bbase + (t) * 64;                              \
        unsigned short* Ad_ = Alds[(t) & 1];                                       \
        unsigned short* Bd_ = Blds[(t) & 1];                                       \
        _Pragma("unroll")                                                          \
        for (int i_ = 0; i_ < 4; ++i_)                                             \
            gload_lds16(&As_[(size_t)(i_ * 64 + srow) * Dm + scol],                \
                        &Ad_[i_ * 4096 + wid * 512]);                              \
        _Pragma("unroll")                                                          \
        for (int i_ = 0; i_ < 3; ++i_)                                             \
            gload_lds16(&Bs_[(size_t)(i_ * 64 + srow) * Dm + scol],                \
                        &Bd_[i_ * 4096 + wid * 512]);                              \
    } while (0)

    f32x4 acc[8][3];
#pragma unroll
    for (int mr = 0; mr < 8; ++mr)
#pragma unroll
        for (int nr = 0; nr < 3; ++nr) acc[mr][nr] = (f32x4){0.f, 0.f, 0.f, 0.f};

    STAGE_TILE(0);
    asm volatile("s_waitcnt vmcnt(0)" ::: "memory");
    __builtin_amdgcn_s_barrier();

    for (int t = 0; t < Dm / 64; ++t) {
        unsigned short* Ad = Alds[t & 1];
        unsigned short* Bd = Blds[t & 1];
        if (t + 1 < Dm / 64) STAGE_TILE(t + 1);

        bf16x8 a_[4][2], b_[3][2];

#define RD_A(qm, fr, ks) \
    (*(const bf16x8*)&Ad[(wm * 128 + (qm) * 64 + (fr) * 16 + l15) * 64 + \
                         ((((ks) * 4 + lg) ^ (l15 & 7)) * 8)])
#define RD_B(fc, ks) \
    (*(const bf16x8*)&Bd[(wn * 48 + (fc) * 16 + l15) * 64 + \
                         ((((ks) * 4 + lg) ^ (l15 & 7)) * 8)])

#pragma unroll
        for (int fr = 0; fr < 4; ++fr) {
            a_[fr][0] = RD_A(0, fr, 0); a_[fr][1] = RD_A(0, fr, 1);
        }
#pragma unroll
        for (int fc = 0; fc < 3; ++fc) {
            b_[fc][0] = RD_B(fc, 0); b_[fc][1] = RD_B(fc, 1);
        }
        __builtin_amdgcn_s_barrier();
        __builtin_amdgcn_s_setprio(1);
#pragma unroll
        for (int fr = 0; fr < 4; ++fr)
#pragma unroll
            for (int fc = 0; fc < 3; ++fc)
#pragma unroll
                for (int ks = 0; ks < 2; ++ks)
                    acc[fr][fc] = __builtin_amdgcn_mfma_f32_16x16x32_bf16(
                        a_[fr][ks], b_[fc][ks], acc[fr][fc], 0, 0, 0);
        __builtin_amdgcn_s_setprio(0);
        __builtin_amdgcn_s_barrier();

#pragma unroll
        for (int fr = 0; fr < 4; ++fr) {
            a_[fr][0] = RD_A(1, fr, 0); a_[fr][1] = RD_A(1, fr, 1);
        }
        __builtin_amdgcn_s_barrier();
        __builtin_amdgcn_s_setprio(1);
#pragma unroll
        for (int fr = 0; fr < 4; ++fr)
#pragma unroll
            for (int fc = 0; fc < 3; ++fc)
#pragma unroll
                for (int ks = 0; ks < 2; ++ks)
                    acc[4 + fr][fc] = __builtin_amdgcn_mfma_f32_16x16x32_bf16(
                        a_[fr][ks], b_[fc][ks], acc[4 + fr][fc], 0, 0, 0);
        __builtin_amdgcn_s_setprio(0);
        __builtin_amdgcn_s_barrier();

        asm volatile("s_waitcnt vmcnt(0)" ::: "memory");
        __builtin_amdgcn_s_barrier();
#undef RD_A
#undef RD_B
    }

    const float qscale = 0.18033688011f;   // 1/8 * log2(e)
#pragma unroll
    for (int mr = 0; mr < 8; ++mr) {
#pragma unroll
        for (int nr = 0; nr < 3; ++nr) {
            const int m = m0 + wm * 128 + mr * 16 + lg * 4;
            const int nglob = n0 + wn * 48 + nr * 16 + l15;
            const int zq = nglob >> 10;
            const int nz = nglob & 1023;
            const float* bias = (zq == 0) ? bq : (zq == 1) ? bk : bv;
            const float bb_ = bias[nz];
            if (zq == 0) {
#pragma unroll
                for (int rr = 0; rr < 4; ++rr)
                    qbuf[(size_t)(m + rr) * Dm + nz] =
                        bf_round((acc[mr][nr][rr] + bb_) * qscale);
            } else if (zq == 1) {
#pragma unroll
                for (int rr = 0; rr < 4; ++rr)
                    kbuf[(size_t)(m + rr) * Dm + nz] = bf_round(acc[mr][nr][rr] + bb_);
            } else {
                const int bbv = m >> 11, s = m & (SQ - 1);
                const int hh = nz >> 6, d = nz & 63;
                unsigned short p4[4] __attribute__((aligned(8)));
#pragma unroll
                for (int rr = 0; rr < 4; ++rr) p4[rr] = bf_round(acc[mr][nr][rr] + bb_);
                *(uint2*)&vtbuf[(((size_t)bbv * NH + hh) * 64 + d) * SQ + s] =
                    *(const uint2*)p4;
            }
        }
    }
#undef STAGE_TILE
}

// ====================================================================
// output projection, 2-phase schedule at 128x128
// ====================================================================
__global__ __launch_bounds__(256) void gemm_out8(const unsigned short* __restrict__ A,
                                                 const unsigned short* __restrict__ Bt,
                                                 const float* __restrict__ bias,
                                                 float* __restrict__ Cf) {
    __shared__ unsigned short Alds[2][128 * 64];
    __shared__ unsigned short Blds[2][128 * 64];

    const int tid = threadIdx.x;
    const int lane = tid & 63, wid = tid >> 6;
    const int l15 = lane & 15, lg = lane >> 4;
    const int wr = (wid >> 1) * 64, wc = (wid & 1) * 64;
    const int m0 = blockIdx.y * 128, n0 = blockIdx.x * 128;

    const int srow = (tid >> 3) & 31;
    const int scol = ((tid & 7) ^ (srow & 7)) * 8;

    const unsigned short* Abase = A + (size_t)m0 * Dm;
    const unsigned short* Bbase = Bt + (size_t)n0 * Dm;

#define STAGE_TILE(t)                                                              \
    do {                                                                           \
        const unsigned short* As_ = Abase + (t) * 64;                              \
        const unsigned short* Bs_ = Bbase + (t) * 64;                              \
        unsigned short* Ad_ = Alds[(t) & 1];                                       \
        unsigned short* Bd_ = Blds[(t) & 1];                                       \
        _Pragma("unroll")                                                          \
        for (int i_ = 0; i_ < 4; ++i_) {                                           \
            gload_lds16(&As_[(size_t)(i_ * 32 + srow) * Dm + scol],                \
                        &Ad_[i_ * 2048 + wid * 512]);                              \
            gload_lds16(&Bs_[(size_t)(i_ * 32 + srow) * Dm + scol],                \
                        &Bd_[i_ * 2048 + wid * 512]);                              \
        }                                                                          \
    } while (0)

    f32x4 acc[4][4];
#pragma unroll
    for (int r = 0; r < 4; ++r)
#pragma unroll
        for (int c = 0; c < 4; ++c) acc[r][c] = (f32x4){0.f, 0.f, 0.f, 0.f};

    STAGE_TILE(0);
    asm volatile("s_waitcnt vmcnt(0)" ::: "memory");
    __builtin_amdgcn_s_barrier();

    for (int t = 0; t < Dm / 64; ++t) {
        unsigned short* Ad = Alds[t & 1];
        unsigned short* Bd = Blds[t & 1];
        if (t + 1 < Dm / 64) STAGE_TILE(t + 1);

        bf16x8 a_[4][2], b_[2][2];

#define RD_A(fr, ks) \
    (*(const bf16x8*)&Ad[(wr + (fr) * 16 + l15) * 64 + ((((ks) * 4 + lg) ^ (l15 & 7)) * 8)])
#define RD_B(fc, ks) \
    (*(const bf16x8*)&Bd[(wc + (fc) * 16 + l15) * 64 + ((((ks) * 4 + lg) ^ (l15 & 7)) * 8)])

#pragma unroll
        for (int fr = 0; fr < 4; ++fr) {
            a_[fr][0] = RD_A(fr, 0); a_[fr][1] = RD_A(fr, 1);
        }
#pragma unroll
        for (int fc = 0; fc < 2; ++fc) {
            b_[fc][0] = RD_B(fc, 0); b_[fc][1] = RD_B(fc, 1);
        }
        __builtin_amdgcn_s_barrier();
        __builtin_amdgcn_s_setprio(1);
#pragma unroll
        for (int fr = 0; fr < 4; ++fr)
#pragma unroll
            for (int fc = 0; fc < 2; ++fc)
#pragma unroll
                for (int ks = 0; ks < 2; ++ks)
                    acc[fr][fc] = __builtin_amdgcn_mfma_f32_16x16x32_bf16(
                        a_[fr][ks], b_[fc][ks], acc[fr][fc], 0, 0, 0);
        __builtin_amdgcn_s_setprio(0);
        __builtin_amdgcn_s_barrier();

#pragma unroll
        for (int fc = 0; fc < 2; ++fc) {
            b_[fc][0] = RD_B(2 + fc, 0); b_[fc][1] = RD_B(2 + fc, 1);
        }
        __builtin_amdgcn_s_barrier();
        __builtin_amdgcn_s_setprio(1);
#pragma unroll
        for (int fr = 0; fr < 4; ++fr)
#pragma unroll
            for (int fc = 0; fc < 2; ++fc)
#pragma unroll
                for (int ks = 0; ks < 2; ++ks)
                    acc[fr][2 + fc] = __builtin_amdgcn_mfma_f32_16x16x32_bf16(
                        a_[fr][ks], b_[fc][ks], acc[fr][2 + fc], 0, 0, 0);
        __builtin_amdgcn_s_setprio(0);
        __builtin_amdgcn_s_barrier();

        asm volatile("s_waitcnt vmcnt(0)" ::: "memory");
        __builtin_amdgcn_s_barrier();
#undef RD_A
#undef RD_B
    }

#pragma unroll
    for (int r = 0; r < 4; ++r) {
#pragma unroll
        for (int c = 0; c < 4; ++c) {
            const int mBase = m0 + wr + r * 16 + lg * 4;
            const int n = n0 + wc + c * 16 + l15;
            const float bv_ = bias[n];
#pragma unroll
            for (int rr = 0; rr < 4; ++rr)
                Cf[(size_t)(mBase + rr) * Dm + n] = acc[r][c][rr] + bv_;
        }
    }
#undef STAGE_TILE
}

// ---------------- flash attention core (shared by split / non-split) ----------------
template <int SPLIT>
__global__ __launch_bounds__(256) void attn_core(const unsigned short* q,
                                                 const unsigned short* __restrict__ k,
                                                 const unsigned short* __restrict__ vt,
                                                 unsigned short* ao,
                                                 unsigned* __restrict__ op0,
                                                 unsigned* __restrict__ op1,
                                                 float* __restrict__ ps0,
                                                 float* __restrict__ ps1) {
    __shared__ unsigned short KVs[2][2][64 * 64];  // [buf][0=K,1=Vt], XOR-swizzled
    const int qt = blockIdx.x, h = blockIdx.y;
    const int bz = blockIdx.z;
    const int b = SPLIT ? (bz >> 1) : bz;
    const int half = SPLIT ? (bz & 1) : 0;
    const int tid = threadIdx.x, lane = tid & 63, wid = tid >> 6;
    const int l31 = lane & 31, hi = lane >> 5;

    const size_t qrow0 = (size_t)b * SQ + qt * 128;
    const unsigned short* qp = q + (qrow0 + wid * 32 + l31) * Dm + h * 64;
    bf16x8 qf[4];
#pragma unroll
    for (int ks = 0; ks < 4; ++ks)
        qf[ks] = *(const bf16x8*)&qp[ks * 16 + hi * 8];

    const unsigned short* kb = k + ((size_t)b * SQ + half * (SQ / 2)) * Dm + h * 64;
    const unsigned short* vb = vt + ((size_t)b * NH + h) * 64 * SQ + half * (SQ / 2);

    const int row0 = tid >> 3;
    const int s8 = (tid & 7) * 8;
    const int sw8 = (((tid & 7) ^ (row0 & 7))) * 8;
    const int koff0 = row0 * 64 + sw8;
    const int koff1 = (row0 + 32) * 64 + sw8;

    {   // prologue: stage tile 0 into buf 0
        uint4 k0v = *(const uint4*)&kb[(size_t)row0 * Dm + s8];
        uint4 k1v = *(const uint4*)&kb[(size_t)(row0 + 32) * Dm + s8];
        uint4 v0v = *(const uint4*)&vb[(size_t)row0 * SQ + s8];
        uint4 v1v = *(const uint4*)&vb[(size_t)(row0 + 32) * SQ + s8];
        *(uint4*)&KVs[0][0][koff0] = k0v; *(uint4*)&KVs[0][0][koff1] = k1v;
        *(uint4*)&KVs[0][1][koff0] = v0v; *(uint4*)&KVs[0][1][koff1] = v1v;
    }
    __syncthreads();

    float psum = 0.f;
    f32x16 c0, c1;
#pragma unroll
    for (int i = 0; i < 16; ++i) { c0[i] = 0.f; c1[i] = 0.f; }

    const int NKEYS = SPLIT ? (SQ / 2) : SQ;
    int cur = 0;
    for (int t0 = 0; t0 < NKEYS; t0 += 64) {
        const bool hasNext = (t0 + 64) < NKEYS;
        uint4 kr0, kr1, vr0, vr1;
        if (hasNext) {   // T14: issue next-tile loads early
            const unsigned short* kn = kb + (size_t)(t0 + 64) * Dm;
            const unsigned short* vn = vb + (t0 + 64);
            kr0 = *(const uint4*)&kn[(size_t)row0 * Dm + s8];
            kr1 = *(const uint4*)&kn[(size_t)(row0 + 32) * Dm + s8];
            vr0 = *(const uint4*)&vn[(size_t)row0 * SQ + s8];
            vr1 = *(const uint4*)&vn[(size_t)(row0 + 32) * SQ + s8];
        }
        const unsigned short* Kc = KVs[cur][0];
        const unsigned short* Vc = KVs[cur][1];

#pragma unroll
        for (int kblk = 0; kblk < 2; ++kblk) {
            f32x16 p;
#pragma unroll
            for (int i = 0; i < 16; ++i) p[i] = 0.f;
            __builtin_amdgcn_s_setprio(1);
#pragma unroll
            for (int ks = 0; ks < 4; ++ks) {
                int row = kblk * 32 + l31;
                int slot = ((ks * 2 + hi) ^ (l31 & 7)) * 8;
                bf16x8 kf = *(const bf16x8*)&Kc[row * 64 + slot];
                p = __builtin_amdgcn_mfma_f32_32x32x16_bf16(kf, qf[ks], p, 0, 0, 0);
            }
            __builtin_amdgcn_s_setprio(0);

            float e[16];
#pragma unroll
            for (int i = 0; i < 16; ++i) { e[i] = exp2_fast(p[i]); psum += e[i]; }
            unsigned w0 = cvt_pk(e[0], e[1]),   w1 = cvt_pk(e[2], e[3]);
            unsigned w2 = cvt_pk(e[4], e[5]),   w3 = cvt_pk(e[6], e[7]);
            unsigned w4 = cvt_pk(e[8], e[9]),   w5 = cvt_pk(e[10], e[11]);
            unsigned w6 = cvt_pk(e[12], e[13]), w7 = cvt_pk(e[14], e[15]);
            permlane_swap(w0, w2); permlane_swap(w1, w3);
            permlane_swap(w4, w6); permlane_swap(w5, w7);
            bf16x8 pf0 = make_frag(w0, w1, w2, w3);
            bf16x8 pf1 = make_frag(w4, w5, w6, w7);

            int s0 = ((kblk * 4 + hi) ^ (l31 & 7)) * 8;
            int s1 = ((kblk * 4 + 2 + hi) ^ (l31 & 7)) * 8;
            bf16x8 va0 = *(const bf16x8*)&Vc[l31 * 64 + s0];
            bf16x8 va1 = *(const bf16x8*)&Vc[l31 * 64 + s1];
            bf16x8 vb0 = *(const bf16x8*)&Vc[(32 + l31) * 64 + s0];
            bf16x8 vb1 = *(const bf16x8*)&Vc[(32 + l31) * 64 + s1];
            __builtin_amdgcn_s_setprio(1);
            c0 = __builtin_amdgcn_mfma_f32_32x32x16_bf16(va0, pf0, c0, 0, 0, 0);
            c0 = __builtin_amdgcn_mfma_f32_32x32x16_bf16(va1, pf1, c0, 0, 0, 0);
            c1 = __builtin_amdgcn_mfma_f32_32x32x16_bf16(vb0, pf0, c1, 0, 0, 0);
            c1 = __builtin_amdgcn_mfma_f32_32x32x16_bf16(vb1, pf1, c1, 0, 0, 0);
            __builtin_amdgcn_s_setprio(0);
        }

        if (hasNext) {
            unsigned short* Kn = KVs[cur ^ 1][0];
            unsigned short* Vn = KVs[cur ^ 1][1];
            *(uint4*)&Kn[koff0] = kr0; *(uint4*)&Kn[koff1] = kr1;
            *(uint4*)&Vn[koff0] = vr0; *(uint4*)&Vn[koff1] = vr1;
        }
        __syncthreads();
        cur ^= 1;
    }

    float s = psum + __shfl_xor(psum, 32, 64);
    const int qloc = wid * 32 + l31;

    if (SPLIT) {
        // store packed unnormalized partials: dword dp holds d = (2dp, 2dp+1)
        unsigned* op = half ? op1 : op0;
        float* ps = half ? ps1 : ps0;
        const size_t pbase = (((size_t)b * NH + h) * (SQ / 128) + qt) * 128;
        unsigned* ob = op + pbase * 32;          // 32 dwords (64 d) x 128 q
#pragma unroll
        for (int p = 0; p < 8; ++p) {
            int dp = (p & 1) + 4 * (p >> 1) + 2 * hi;
            ob[dp * 128 + qloc] = cvt_pk(c0[2 * p], c0[2 * p + 1]);
            ob[(16 + dp) * 128 + qloc] = cvt_pk(c1[2 * p], c1[2 * p + 1]);
        }
        if (hi == 0) ps[pbase + qloc] = s;
        return;
    }

    float inv = 1.f / s;
    unsigned short* Olds = (unsigned short*)KVs;
    {
#pragma unroll
        for (int db = 0; db < 2; ++db) {
#pragma unroll
            for (int i = 0; i < 8; ++i) {
                float lo  = (db ? c1[2 * i] : c0[2 * i]) * inv;
                float hi_ = (db ? c1[2 * i + 1] : c0[2 * i + 1]) * inv;
                unsigned w = cvt_pk(lo, hi_);
                int d7 = hi * 4 + (i & 1) * 2;
                int slot = db * 4 + (i >> 1);
                int sw = slot ^ (l31 & 7);
                *(unsigned*)&Olds[qloc * 64 + sw * 8 + d7] = w;
            }
        }
    }
    __syncthreads();
    {
        int r = tid >> 1, hf = tid & 1;
        unsigned short* dst = ao + (qrow0 + r) * Dm + h * 64 + hf * 32;
#pragma unroll
        for (int j = 0; j < 4; ++j) {
            int slot = hf * 4 + j;
            int sw = slot ^ (r & 7);
            *(uint4*)&dst[j * 8] = *(const uint4*)&Olds[r * 64 + sw * 8];
        }
    }
}

// ---------------- split-K combine: ao = (O0 + O1) / (s0 + s1) ----------------
// grid (SQ/128, NH, NB), 128 threads; thread owns one q-row (128B store).
__global__ __launch_bounds__(128) void attn_combine(const unsigned* __restrict__ op0,
                                                    const unsigned* __restrict__ op1,
                                                    const float* __restrict__ ps0,
                                                    const float* __restrict__ ps1,
                                                    unsigned short* __restrict__ ao) {
    const int qt = blockIdx.x, h = blockIdx.y, b = blockIdx.z;
    const int tid = threadIdx.x;                 // q row 0..127
    const size_t pbase = (((size_t)b * NH + h) * (SQ / 128) + qt) * 128;
    const float inv = 1.f / (ps0[pbase + tid] + ps1[pbase + tid]);
    const unsigned* o0 = op0 + pbase * 32;
    const unsigned* o1 = op1 + pbase * 32;

    unsigned out[32] __attribute__((aligned(16)));
#pragma unroll
    for (int dp = 0; dp < 32; ++dp) {
        unsigned u0 = o0[dp * 128 + tid];
        unsigned u1 = o1[dp * 128 + tid];
        float lo = (bfu2f(u0 & 0xffffu) + bfu2f(u1 & 0xffffu)) * inv;
        float hi = (bfu2f(u0 >> 16) + bfu2f(u1 >> 16)) * inv;
        out[dp] = cvt_pk(lo, hi);
    }
    unsigned short* dst = ao + ((size_t)b * SQ + qt * 128 + tid) * Dm + h * 64;
#pragma unroll
    for (int j = 0; j < 8; ++j)
        *(uint4*)&dst[j * 8] = *(const uint4*)&out[j * 4];   // FIX: uint4 (was uint2 -> half row unwritten)
}

extern "C" void kernel_launch(void* const* d_in, const int* in_sizes, int n_in,
                              void* d_out, int out_size, void* d_ws, size_t ws_size,
                              hipStream_t stream) {
    const float* x  = (const float*)d_in[0];
    const float* Wq = (const float*)d_in[1];
    const float* bq = (const float*)d_in[2];
    const float* Wk = (const float*)d_in[3];
    const float* bk = (const float*)d_in[4];
    const float* Wv = (const float*)d_in[5];
    const float* bv = (const float*)d_in[6];
    const float* Wo = (const float*)d_in[7];
    const float* bo = (const float*)d_in[8];
    float* out = (float*)d_out;

    const size_t M = (size_t)NB * SQ;           // 4096
    const size_t elems = M * Dm;                // 4M
    unsigned short* xb    = (unsigned short*)d_ws;
    unsigned short* wtb   = xb + elems;
    unsigned short* qbuf  = wtb + 4ull * Dm * Dm;
    unsigned short* kbuf  = qbuf + elems;
    unsigned short* vtbuf = kbuf + elems;
    // split-K buffers: op0 overlays xb (dead after gemm_qkv192); op1/ps after vtbuf
    unsigned* op0 = (unsigned*)xb;                       // 8 MB (2M dwords)
    unsigned* op1 = (unsigned*)(vtbuf + elems);          // 8 MB
    float* ps0 = (float*)(op1 + 2ull * 1024 * 1024);     // 256 KB
    float* ps1 = ps0 + 65536;                            // 256 KB
    const size_t need = (size_t)((char*)(ps1 + 65536) - (char*)d_ws);
    const bool use_split = ws_size >= need;

    dim3 blk(256);
    hipLaunchKernelGGL(prologue, dim3(16, 16, 5), blk, 0, stream,
                       x, Wq, Wk, Wv, Wo, xb, wtb);

    hipLaunchKernelGGL(gemm_qkv192, dim3(256), dim3(512), 0, stream,
                       xb, wtb, bq, bk, bv, qbuf, kbuf, vtbuf);

    if (use_split) {
        hipLaunchKernelGGL(attn_core<1>, dim3(SQ / 128, NH, NB * 2), blk, 0, stream,
                           qbuf, kbuf, vtbuf, qbuf, op0, op1, ps0, ps1);
        hipLaunchKernelGGL(attn_combine, dim3(SQ / 128, NH, NB), dim3(128), 0, stream,
                           op0, op1, ps0, ps1, qbuf);
    } else {
        hipLaunchKernelGGL(attn_core<0>, dim3(SQ / 128, NH, NB), blk, 0, stream,
                           qbuf, kbuf, vtbuf, qbuf, op0, op1, ps0, ps1);
    }

    hipLaunchKernelGGL(gemm_out8, dim3(Dm / 128, M / 128), blk, 0, stream,
                       qbuf, wtb + 3ull * Dm * Dm, bo, out);
}

// Round 17
// 115.978 us; speedup vs baseline: 1.0586x; 1.0586x over previous
//
#include <hip/hip_runtime.h>
#include <math.h>

constexpr int Dm  = 1024;
constexpr int NH  = 16;
constexpr int SQ  = 2048;
constexpr int NB  = 2;

typedef float f32x4 __attribute__((ext_vector_type(4)));
typedef float f32x16 __attribute__((ext_vector_type(16)));
typedef short bf16x8 __attribute__((ext_vector_type(8)));
typedef __attribute__((address_space(3))) unsigned int lds_u32;
typedef __attribute__((address_space(1))) const unsigned int glb_u32;

__device__ __forceinline__ void gload_lds16(const void* g, void* l) {
    __builtin_amdgcn_global_load_lds((glb_u32*)(uintptr_t)g, (lds_u32*)(uintptr_t)l, 16, 0, 0);
}

__device__ __forceinline__ unsigned short bf_round(float x) {
    unsigned u = __float_as_uint(x);
    unsigned r = u + 0x7fffu + ((u >> 16) & 1u);
    return (unsigned short)(r >> 16);
}

__device__ __forceinline__ float exp2_fast(float x) {
    float r;
    asm("v_exp_f32 %0, %1" : "=v"(r) : "v"(x));
    return r;
}

__device__ __forceinline__ unsigned cvt_pk(float lo, float hi_) {
    unsigned r;
    asm("v_cvt_pk_bf16_f32 %0, %1, %2" : "=v"(r) : "v"(lo), "v"(hi_));
    return r;
}

__device__ __forceinline__ void permlane_swap(unsigned& a, unsigned& b) {
    asm volatile("v_permlane32_swap_b32 %0, %1" : "+v"(a), "+v"(b));
}

__device__ __forceinline__ bf16x8 make_frag(unsigned a, unsigned b, unsigned c, unsigned d) {
    union { unsigned u[4]; bf16x8 v; } uu;
    uu.u[0] = a; uu.u[1] = b; uu.u[2] = c; uu.u[3] = d;
    return uu.v;
}

// ---------------- prologue: W transpose (z=0..3) + x fp32->bf16 (z=4) ----------------
__global__ __launch_bounds__(256) void prologue(const float* __restrict__ x,
                                                const float* __restrict__ Wq,
                                                const float* __restrict__ Wk,
                                                const float* __restrict__ Wv,
                                                const float* __restrict__ Wo,
                                                unsigned short* __restrict__ xb,
                                                unsigned short* __restrict__ wt) {
    const int z = blockIdx.z;
    const int tid = threadIdx.x;
    if (z == 4) {
        size_t base = ((size_t)blockIdx.y * 16 + blockIdx.x) * 16384;
#pragma unroll
        for (int it = 0; it < 8; ++it) {
            size_t i = base + (size_t)it * 2048 + (size_t)tid * 8;
            float4 a = *(const float4*)&x[i];
            float4 b = *(const float4*)&x[i + 4];
            unsigned short o8[8] __attribute__((aligned(16)));
            o8[0] = bf_round(a.x); o8[1] = bf_round(a.y); o8[2] = bf_round(a.z); o8[3] = bf_round(a.w);
            o8[4] = bf_round(b.x); o8[5] = bf_round(b.y); o8[6] = bf_round(b.z); o8[7] = bf_round(b.w);
            *(uint4*)&xb[i] = *(const uint4*)o8;
        }
        return;
    }
    const float* W = (z == 0) ? Wq : (z == 1) ? Wk : (z == 2) ? Wv : Wo;
    unsigned short* dst = wt + (size_t)z * Dm * Dm;
    __shared__ float T[64][65];
    const int k0 = blockIdx.x * 64, n0 = blockIdx.y * 64;
#pragma unroll
    for (int i = 0; i < 4; ++i) {
        int s = tid + i * 256;
        int kk = s >> 4, c = (s & 15) * 4;
        *(float4*)&T[kk][c] = *(const float4*)&W[(size_t)(k0 + kk) * Dm + n0 + c];
    }
    __syncthreads();
#pragma unroll
    for (int i = 0; i < 2; ++i) {
        int s = tid + i * 256;
        int n = s >> 3, c8 = (s & 7) * 8;
        unsigned short o8[8] __attribute__((aligned(16)));
#pragma unroll
        for (int j = 0; j < 8; ++j) o8[j] = bf_round(T[c8 + j][n]);
        *(uint4*)&dst[(size_t)(n0 + n) * Dm + k0 + c8] = *(const uint4*)o8;
    }
}

// ====================================================================
// 2-phase 256x192 QKV GEMM (round-13 verified)
// ====================================================================
__global__ __launch_bounds__(512) void gemm_qkv192(
    const unsigned short* __restrict__ xb,
    const unsigned short* __restrict__ wt,
    const float* __restrict__ bq, const float* __restrict__ bk,
    const float* __restrict__ bv,
    unsigned short* __restrict__ qbuf, unsigned short* __restrict__ kbuf,
    unsigned short* __restrict__ vtbuf)
{
    __shared__ unsigned short Alds[2][256 * 64];
    __shared__ unsigned short Blds[2][192 * 64];

    const int tid = threadIdx.x;
    const int lane = tid & 63, wid = tid >> 6;
    const int wm = wid >> 2, wn = wid & 3;
    const int l15 = lane & 15, lg = lane >> 4;

    const int bid = blockIdx.x;
    const int swz = (bid & 7) * 32 + (bid >> 3);
    const int bx = swz & 15, by = swz >> 4;
    const int m0 = by * 256, n0 = bx * 192;

    const int srow = wid * 8 + (lane >> 3);
    const int scol = ((lane & 7) ^ ((lane >> 3) & 7)) * 8;

    const unsigned short* Abase = xb + (size_t)m0 * Dm;
    const unsigned short* Bbase = wt + (size_t)n0 * Dm;

#define STAGE_TILE(t)                                                              \
    do {                                                                           \
        const unsigned short* As_ = Abase + (t) * 64;                              \
        const unsigned short* Bs_ = Bbase + (t) * 64;                              \
        unsigned short* Ad_ = Alds[(t) & 1];                                       \
        unsigned short* Bd_ = Blds[(t) & 1];                                       \
        _Pragma("unroll")                                                          \
        for (int i_ = 0; i_ < 4; ++i_)                                             \
            gload_lds16(&As_[(size_t)(i_ * 64 + srow) * Dm + scol],                \
                        &Ad_[i_ * 4096 + wid * 512]);                              \
        _Pragma("unroll")                                                          \
        for (int i_ = 0; i_ < 3; ++i_)                                             \
            gload_lds16(&Bs_[(size_t)(i_ * 64 + srow) * Dm + scol],                \
                        &Bd_[i_ * 4096 + wid * 512]);                              \
    } while (0)

    f32x4 acc[8][3];
#pragma unroll
    for (int mr = 0; mr < 8; ++mr)
#pragma unroll
        for (int nr = 0; nr < 3; ++nr) acc[mr][nr] = (f32x4){0.f, 0.f, 0.f, 0.f};

    STAGE_TILE(0);
    asm volatile("s_waitcnt vmcnt(0)" ::: "memory");
    __builtin_amdgcn_s_barrier();

    for (int t = 0; t < Dm / 64; ++t) {
        unsigned short* Ad = Alds[t & 1];
        unsigned short* Bd = Blds[t & 1];
        if (t + 1 < Dm / 64) STAGE_TILE(t + 1);

        bf16x8 a_[4][2], b_[3][2];

#define RD_A(qm, fr, ks) \
    (*(const bf16x8*)&Ad[(wm * 128 + (qm) * 64 + (fr) * 16 + l15) * 64 + \
                         ((((ks) * 4 + lg) ^ (l15 & 7)) * 8)])
#define RD_B(fc, ks) \
    (*(const bf16x8*)&Bd[(wn * 48 + (fc) * 16 + l15) * 64 + \
                         ((((ks) * 4 + lg) ^ (l15 & 7)) * 8)])

#pragma unroll
        for (int fr = 0; fr < 4; ++fr) {
            a_[fr][0] = RD_A(0, fr, 0); a_[fr][1] = RD_A(0, fr, 1);
        }
#pragma unroll
        for (int fc = 0; fc < 3; ++fc) {
            b_[fc][0] = RD_B(fc, 0); b_[fc][1] = RD_B(fc, 1);
        }
        __builtin_amdgcn_s_barrier();
        __builtin_amdgcn_s_setprio(1);
#pragma unroll
        for (int fr = 0; fr < 4; ++fr)
#pragma unroll
            for (int fc = 0; fc < 3; ++fc)
#pragma unroll
                for (int ks = 0; ks < 2; ++ks)
                    acc[fr][fc] = __builtin_amdgcn_mfma_f32_16x16x32_bf16(
                        a_[fr][ks], b_[fc][ks], acc[fr][fc], 0, 0, 0);
        __builtin_amdgcn_s_setprio(0);
        __builtin_amdgcn_s_barrier();

#pragma unroll
        for (int fr = 0; fr < 4; ++fr) {
            a_[fr][0] = RD_A(1, fr, 0); a_[fr][1] = RD_A(1, fr, 1);
        }
        __builtin_amdgcn_s_barrier();
        __builtin_amdgcn_s_setprio(1);
#pragma unroll
        for (int fr = 0; fr < 4; ++fr)
#pragma unroll
            for (int fc = 0; fc < 3; ++fc)
#pragma unroll
                for (int ks = 0; ks < 2; ++ks)
                    acc[4 + fr][fc] = __builtin_amdgcn_mfma_f32_16x16x32_bf16(
                        a_[fr][ks], b_[fc][ks], acc[4 + fr][fc], 0, 0, 0);
        __builtin_amdgcn_s_setprio(0);
        __builtin_amdgcn_s_barrier();

        asm volatile("s_waitcnt vmcnt(0)" ::: "memory");
        __builtin_amdgcn_s_barrier();
#undef RD_A
#undef RD_B
    }

    const float qscale = 0.18033688011f;   // 1/8 * log2(e)
#pragma unroll
    for (int mr = 0; mr < 8; ++mr) {
#pragma unroll
        for (int nr = 0; nr < 3; ++nr) {
            const int m = m0 + wm * 128 + mr * 16 + lg * 4;
            const int nglob = n0 + wn * 48 + nr * 16 + l15;
            const int zq = nglob >> 10;
            const int nz = nglob & 1023;
            const float* bias = (zq == 0) ? bq : (zq == 1) ? bk : bv;
            const float bb_ = bias[nz];
            if (zq == 0) {
#pragma unroll
                for (int rr = 0; rr < 4; ++rr)
                    qbuf[(size_t)(m + rr) * Dm + nz] =
                        bf_round((acc[mr][nr][rr] + bb_) * qscale);
            } else if (zq == 1) {
#pragma unroll
                for (int rr = 0; rr < 4; ++rr)
                    kbuf[(size_t)(m + rr) * Dm + nz] = bf_round(acc[mr][nr][rr] + bb_);
            } else {
                const int bbv = m >> 11, s = m & (SQ - 1);
                const int hh = nz >> 6, d = nz & 63;
                unsigned short p4[4] __attribute__((aligned(8)));
#pragma unroll
                for (int rr = 0; rr < 4; ++rr) p4[rr] = bf_round(acc[mr][nr][rr] + bb_);
                *(uint2*)&vtbuf[(((size_t)bbv * NH + hh) * 64 + d) * SQ + s] =
                    *(const uint2*)p4;
            }
        }
    }
#undef STAGE_TILE
}

// ====================================================================
// output projection, 2-phase schedule at 128x128
// ====================================================================
__global__ __launch_bounds__(256) void gemm_out8(const unsigned short* __restrict__ A,
                                                 const unsigned short* __restrict__ Bt,
                                                 const float* __restrict__ bias,
                                                 float* __restrict__ Cf) {
    __shared__ unsigned short Alds[2][128 * 64];
    __shared__ unsigned short Blds[2][128 * 64];

    const int tid = threadIdx.x;
    const int lane = tid & 63, wid = tid >> 6;
    const int l15 = lane & 15, lg = lane >> 4;
    const int wr = (wid >> 1) * 64, wc = (wid & 1) * 64;
    const int m0 = blockIdx.y * 128, n0 = blockIdx.x * 128;

    const int srow = (tid >> 3) & 31;
    const int scol = ((tid & 7) ^ (srow & 7)) * 8;

    const unsigned short* Abase = A + (size_t)m0 * Dm;
    const unsigned short* Bbase = Bt + (size_t)n0 * Dm;

#define STAGE_TILE(t)                                                              \
    do {                                                                           \
        const unsigned short* As_ = Abase + (t) * 64;                              \
        const unsigned short* Bs_ = Bbase + (t) * 64;                              \
        unsigned short* Ad_ = Alds[(t) & 1];                                       \
        unsigned short* Bd_ = Blds[(t) & 1];                                       \
        _Pragma("unroll")                                                          \
        for (int i_ = 0; i_ < 4; ++i_) {                                           \
            gload_lds16(&As_[(size_t)(i_ * 32 + srow) * Dm + scol],                \
                        &Ad_[i_ * 2048 + wid * 512]);                              \
            gload_lds16(&Bs_[(size_t)(i_ * 32 + srow) * Dm + scol],                \
                        &Bd_[i_ * 2048 + wid * 512]);                              \
        }                                                                          \
    } while (0)

    f32x4 acc[4][4];
#pragma unroll
    for (int r = 0; r < 4; ++r)
#pragma unroll
        for (int c = 0; c < 4; ++c) acc[r][c] = (f32x4){0.f, 0.f, 0.f, 0.f};

    STAGE_TILE(0);
    asm volatile("s_waitcnt vmcnt(0)" ::: "memory");
    __builtin_amdgcn_s_barrier();

    for (int t = 0; t < Dm / 64; ++t) {
        unsigned short* Ad = Alds[t & 1];
        unsigned short* Bd = Blds[t & 1];
        if (t + 1 < Dm / 64) STAGE_TILE(t + 1);

        bf16x8 a_[4][2], b_[2][2];

#define RD_A(fr, ks) \
    (*(const bf16x8*)&Ad[(wr + (fr) * 16 + l15) * 64 + ((((ks) * 4 + lg) ^ (l15 & 7)) * 8)])
#define RD_B(fc, ks) \
    (*(const bf16x8*)&Bd[(wc + (fc) * 16 + l15) * 64 + ((((ks) * 4 + lg) ^ (l15 & 7)) * 8)])

#pragma unroll
        for (int fr = 0; fr < 4; ++fr) {
            a_[fr][0] = RD_A(fr, 0); a_[fr][1] = RD_A(fr, 1);
        }
#pragma unroll
        for (int fc = 0; fc < 2; ++fc) {
            b_[fc][0] = RD_B(fc, 0); b_[fc][1] = RD_B(fc, 1);
        }
        __builtin_amdgcn_s_barrier();
        __builtin_amdgcn_s_setprio(1);
#pragma unroll
        for (int fr = 0; fr < 4; ++fr)
#pragma unroll
            for (int fc = 0; fc < 2; ++fc)
#pragma unroll
                for (int ks = 0; ks < 2; ++ks)
                    acc[fr][fc] = __builtin_amdgcn_mfma_f32_16x16x32_bf16(
                        a_[fr][ks], b_[fc][ks], acc[fr][fc], 0, 0, 0);
        __builtin_amdgcn_s_setprio(0);
        __builtin_amdgcn_s_barrier();

#pragma unroll
        for (int fc = 0; fc < 2; ++fc) {
            b_[fc][0] = RD_B(2 + fc, 0); b_[fc][1] = RD_B(2 + fc, 1);
        }
        __builtin_amdgcn_s_barrier();
        __builtin_amdgcn_s_setprio(1);
#pragma unroll
        for (int fr = 0; fr < 4; ++fr)
#pragma unroll
            for (int fc = 0; fc < 2; ++fc)
#pragma unroll
                for (int ks = 0; ks < 2; ++ks)
                    acc[fr][2 + fc] = __builtin_amdgcn_mfma_f32_16x16x32_bf16(
                        a_[fr][ks], b_[fc][ks], acc[fr][2 + fc], 0, 0, 0);
        __builtin_amdgcn_s_setprio(0);
        __builtin_amdgcn_s_barrier();

        asm volatile("s_waitcnt vmcnt(0)" ::: "memory");
        __builtin_amdgcn_s_barrier();
#undef RD_A
#undef RD_B
    }

#pragma unroll
    for (int r = 0; r < 4; ++r) {
#pragma unroll
        for (int c = 0; c < 4; ++c) {
            const int mBase = m0 + wr + r * 16 + lg * 4;
            const int n = n0 + wc + c * 16 + l15;
            const float bv_ = bias[n];
#pragma unroll
            for (int rr = 0; rr < 4; ++rr)
                Cf[(size_t)(mBase + rr) * Dm + n] = acc[r][c][rr] + bv_;
        }
    }
#undef STAGE_TILE
}

// ---------------- flash attention: round-14 body + paired QK (MFMA/VALU overlap) ----
// Only change vs the 58.2us verified kernel: p0 AND p1 (both kblks' QK^T) are
// computed back-to-back, so softmax0's VALU overlaps QK1's MFMAs in-flight.
// exp/psum/cvt_pk fused pairwise (no e[16] array) to hold VGPR below the cliff.
__global__ __launch_bounds__(256) void attn_bf16(const unsigned short* q,
                                                 const unsigned short* __restrict__ k,
                                                 const unsigned short* __restrict__ vt,
                                                 unsigned short* ao) {
    __shared__ unsigned short KVs[2][2][64 * 64];  // [buf][0=K,1=Vt], XOR-swizzled
    const int qt = blockIdx.x, h = blockIdx.y, b = blockIdx.z;
    const int tid = threadIdx.x, lane = tid & 63, wid = tid >> 6;
    const int l31 = lane & 31, hi = lane >> 5;

    const size_t qrow0 = (size_t)b * SQ + qt * 128;
    const unsigned short* qp = q + (qrow0 + wid * 32 + l31) * Dm + h * 64;
    bf16x8 qf[4];
#pragma unroll
    for (int ks = 0; ks < 4; ++ks)
        qf[ks] = *(const bf16x8*)&qp[ks * 16 + hi * 8];

    const unsigned short* kb = k + (size_t)b * SQ * Dm + h * 64;
    const unsigned short* vb = vt + ((size_t)b * NH + h) * 64 * SQ;

    const int row0 = tid >> 3;
    const int s8 = (tid & 7) * 8;
    const int sw8 = (((tid & 7) ^ (row0 & 7))) * 8;
    const int koff0 = row0 * 64 + sw8;
    const int koff1 = (row0 + 32) * 64 + sw8;

    {   // prologue: stage tile 0 into buf 0
        uint4 k0v = *(const uint4*)&kb[(size_t)row0 * Dm + s8];
        uint4 k1v = *(const uint4*)&kb[(size_t)(row0 + 32) * Dm + s8];
        uint4 v0v = *(const uint4*)&vb[(size_t)row0 * SQ + s8];
        uint4 v1v = *(const uint4*)&vb[(size_t)(row0 + 32) * SQ + s8];
        *(uint4*)&KVs[0][0][koff0] = k0v; *(uint4*)&KVs[0][0][koff1] = k1v;
        *(uint4*)&KVs[0][1][koff0] = v0v; *(uint4*)&KVs[0][1][koff1] = v1v;
    }
    __syncthreads();

    float psum = 0.f;
    f32x16 c0, c1;
#pragma unroll
    for (int i = 0; i < 16; ++i) { c0[i] = 0.f; c1[i] = 0.f; }

    int cur = 0;
    for (int t0 = 0; t0 < SQ; t0 += 64) {
        const bool hasNext = (t0 + 64) < SQ;
        uint4 kr0, kr1, vr0, vr1;
        if (hasNext) {   // T14: issue next-tile loads early
            const unsigned short* kn = kb + (size_t)(t0 + 64) * Dm;
            const unsigned short* vn = vb + (t0 + 64);
            kr0 = *(const uint4*)&kn[(size_t)row0 * Dm + s8];
            kr1 = *(const uint4*)&kn[(size_t)(row0 + 32) * Dm + s8];
            vr0 = *(const uint4*)&vn[(size_t)row0 * SQ + s8];
            vr1 = *(const uint4*)&vn[(size_t)(row0 + 32) * SQ + s8];
        }
        const unsigned short* Kc = KVs[cur][0];
        const unsigned short* Vc = KVs[cur][1];

        // ---- QK^T for BOTH kblks back-to-back (p1's MFMAs cover softmax0) ----
        f32x16 p0, p1;
#pragma unroll
        for (int i = 0; i < 16; ++i) { p0[i] = 0.f; p1[i] = 0.f; }
        __builtin_amdgcn_s_setprio(1);
#pragma unroll
        for (int ks = 0; ks < 4; ++ks) {
            int slot = ((ks * 2 + hi) ^ (l31 & 7)) * 8;
            bf16x8 kf = *(const bf16x8*)&Kc[l31 * 64 + slot];
            p0 = __builtin_amdgcn_mfma_f32_32x32x16_bf16(kf, qf[ks], p0, 0, 0, 0);
        }
#pragma unroll
        for (int ks = 0; ks < 4; ++ks) {
            int slot = ((ks * 2 + hi) ^ (l31 & 7)) * 8;
            bf16x8 kf = *(const bf16x8*)&Kc[(32 + l31) * 64 + slot];
            p1 = __builtin_amdgcn_mfma_f32_32x32x16_bf16(kf, qf[ks], p1, 0, 0, 0);
        }
        __builtin_amdgcn_s_setprio(0);

        // ---- kblk0: softmax (overlaps QK1 in matrix pipe) + PV ----
        {
            unsigned w[8];
#pragma unroll
            for (int i = 0; i < 8; ++i) {
                float ea = exp2_fast(p0[2 * i]);
                float eb = exp2_fast(p0[2 * i + 1]);
                psum += ea; psum += eb;
                w[i] = cvt_pk(ea, eb);
            }
            permlane_swap(w[0], w[2]); permlane_swap(w[1], w[3]);
            permlane_swap(w[4], w[6]); permlane_swap(w[5], w[7]);
            bf16x8 pf0 = make_frag(w[0], w[1], w[2], w[3]);
            bf16x8 pf1 = make_frag(w[4], w[5], w[6], w[7]);

            int s0 = ((0 + hi) ^ (l31 & 7)) * 8;
            int s1 = ((2 + hi) ^ (l31 & 7)) * 8;
            bf16x8 va0 = *(const bf16x8*)&Vc[l31 * 64 + s0];
            bf16x8 va1 = *(const bf16x8*)&Vc[l31 * 64 + s1];
            bf16x8 vb0 = *(const bf16x8*)&Vc[(32 + l31) * 64 + s0];
            bf16x8 vb1 = *(const bf16x8*)&Vc[(32 + l31) * 64 + s1];
            __builtin_amdgcn_s_setprio(1);
            c0 = __builtin_amdgcn_mfma_f32_32x32x16_bf16(va0, pf0, c0, 0, 0, 0);
            c0 = __builtin_amdgcn_mfma_f32_32x32x16_bf16(va1, pf1, c0, 0, 0, 0);
            c1 = __builtin_amdgcn_mfma_f32_32x32x16_bf16(vb0, pf0, c1, 0, 0, 0);
            c1 = __builtin_amdgcn_mfma_f32_32x32x16_bf16(vb1, pf1, c1, 0, 0, 0);
            __builtin_amdgcn_s_setprio(0);
        }

        // ---- kblk1: softmax + PV ----
        {
            unsigned w[8];
#pragma unroll
            for (int i = 0; i < 8; ++i) {
                float ea = exp2_fast(p1[2 * i]);
                float eb = exp2_fast(p1[2 * i + 1]);
                psum += ea; psum += eb;
                w[i] = cvt_pk(ea, eb);
            }
            permlane_swap(w[0], w[2]); permlane_swap(w[1], w[3]);
            permlane_swap(w[4], w[6]); permlane_swap(w[5], w[7]);
            bf16x8 pf0 = make_frag(w[0], w[1], w[2], w[3]);
            bf16x8 pf1 = make_frag(w[4], w[5], w[6], w[7]);

            int s0 = ((4 + hi) ^ (l31 & 7)) * 8;
            int s1 = ((6 + hi) ^ (l31 & 7)) * 8;
            bf16x8 va0 = *(const bf16x8*)&Vc[l31 * 64 + s0];
            bf16x8 va1 = *(const bf16x8*)&Vc[l31 * 64 + s1];
            bf16x8 vb0 = *(const bf16x8*)&Vc[(32 + l31) * 64 + s0];
            bf16x8 vb1 = *(const bf16x8*)&Vc[(32 + l31) * 64 + s1];
            __builtin_amdgcn_s_setprio(1);
            c0 = __builtin_amdgcn_mfma_f32_32x32x16_bf16(va0, pf0, c0, 0, 0, 0);
            c0 = __builtin_amdgcn_mfma_f32_32x32x16_bf16(va1, pf1, c0, 0, 0, 0);
            c1 = __builtin_amdgcn_mfma_f32_32x32x16_bf16(vb0, pf0, c1, 0, 0, 0);
            c1 = __builtin_amdgcn_mfma_f32_32x32x16_bf16(vb1, pf1, c1, 0, 0, 0);
            __builtin_amdgcn_s_setprio(0);
        }

        if (hasNext) {
            unsigned short* Kn = KVs[cur ^ 1][0];
            unsigned short* Vn = KVs[cur ^ 1][1];
            *(uint4*)&Kn[koff0] = kr0; *(uint4*)&Kn[koff1] = kr1;
            *(uint4*)&Vn[koff0] = vr0; *(uint4*)&Vn[koff1] = vr1;
        }
        __syncthreads();
        cur ^= 1;
    }

    float s = psum + __shfl_xor(psum, 32, 64);
    float inv = 1.f / s;

    unsigned short* Olds = (unsigned short*)KVs;
    {
        const int orow = wid * 32 + l31;
#pragma unroll
        for (int db = 0; db < 2; ++db) {
#pragma unroll
            for (int i = 0; i < 8; ++i) {
                float lo  = (db ? c1[2 * i] : c0[2 * i]) * inv;
                float hi_ = (db ? c1[2 * i + 1] : c0[2 * i + 1]) * inv;
                unsigned w = cvt_pk(lo, hi_);
                int d7 = hi * 4 + (i & 1) * 2;
                int slot = db * 4 + (i >> 1);
                int sw = slot ^ (l31 & 7);
                *(unsigned*)&Olds[orow * 64 + sw * 8 + d7] = w;
            }
        }
    }
    __syncthreads();
    {
        int r = tid >> 1, half = tid & 1;
        unsigned short* dst = ao + (qrow0 + r) * Dm + h * 64 + half * 32;
#pragma unroll
        for (int j = 0; j < 4; ++j) {
            int slot = half * 4 + j;
            int sw = slot ^ (r & 7);
            *(uint4*)&dst[j * 8] = *(const uint4*)&Olds[r * 64 + sw * 8];
        }
    }
}

extern "C" void kernel_launch(void* const* d_in, const int* in_sizes, int n_in,
                              void* d_out, int out_size, void* d_ws, size_t ws_size,
                              hipStream_t stream) {
    const float* x  = (const float*)d_in[0];
    const float* Wq = (const float*)d_in[1];
    const float* bq = (const float*)d_in[2];
    const float* Wk = (const float*)d_in[3];
    const float* bk = (const float*)d_in[4];
    const float* Wv = (const float*)d_in[5];
    const float* bv = (const float*)d_in[6];
    const float* Wo = (const float*)d_in[7];
    const float* bo = (const float*)d_in[8];
    float* out = (float*)d_out;

    const size_t M = (size_t)NB * SQ;           // 4096
    const size_t elems = M * Dm;                // 4M
    unsigned short* xb    = (unsigned short*)d_ws;
    unsigned short* wtb   = xb + elems;
    unsigned short* qbuf  = wtb + 4ull * Dm * Dm;
    unsigned short* kbuf  = qbuf + elems;
    unsigned short* vtbuf = kbuf + elems;

    dim3 blk(256);
    hipLaunchKernelGGL(prologue, dim3(16, 16, 5), blk, 0, stream,
                       x, Wq, Wk, Wv, Wo, xb, wtb);

    hipLaunchKernelGGL(gemm_qkv192, dim3(256), dim3(512), 0, stream,
                       xb, wtb, bq, bk, bv, qbuf, kbuf, vtbuf);

    hipLaunchKernelGGL(attn_bf16, dim3(SQ / 128, NH, NB), blk, 0, stream,
                       qbuf, kbuf, vtbuf, qbuf);

    hipLaunchKernelGGL(gemm_out8, dim3(Dm / 128, M / 128), blk, 0, stream,
                       qbuf, wtb + 3ull * Dm * Dm, bo, out);
}

// Round 18
// 112.010 us; speedup vs baseline: 1.0961x; 1.0354x over previous
//
#include <hip/hip_runtime.h>
#include <math.h>

constexpr int Dm  = 1024;
constexpr int NH  = 16;
constexpr int SQ  = 2048;
constexpr int NB  = 2;

typedef float f32x4 __attribute__((ext_vector_type(4)));
typedef float f32x16 __attribute__((ext_vector_type(16)));
typedef short bf16x8 __attribute__((ext_vector_type(8)));
typedef __attribute__((address_space(3))) unsigned int lds_u32;
typedef __attribute__((address_space(1))) const unsigned int glb_u32;

__device__ __forceinline__ void gload_lds16(const void* g, void* l) {
    __builtin_amdgcn_global_load_lds((glb_u32*)(uintptr_t)g, (lds_u32*)(uintptr_t)l, 16, 0, 0);
}

__device__ __forceinline__ unsigned short bf_round(float x) {
    unsigned u = __float_as_uint(x);
    unsigned r = u + 0x7fffu + ((u >> 16) & 1u);
    return (unsigned short)(r >> 16);
}

__device__ __forceinline__ float exp2_fast(float x) {
    float r;
    asm("v_exp_f32 %0, %1" : "=v"(r) : "v"(x));
    return r;
}

__device__ __forceinline__ unsigned cvt_pk(float lo, float hi_) {
    unsigned r;
    asm("v_cvt_pk_bf16_f32 %0, %1, %2" : "=v"(r) : "v"(lo), "v"(hi_));
    return r;
}

__device__ __forceinline__ void permlane_swap(unsigned& a, unsigned& b) {
    asm volatile("v_permlane32_swap_b32 %0, %1" : "+v"(a), "+v"(b));
}

__device__ __forceinline__ bf16x8 make_frag(unsigned a, unsigned b, unsigned c, unsigned d) {
    union { unsigned u[4]; bf16x8 v; } uu;
    uu.u[0] = a; uu.u[1] = b; uu.u[2] = c; uu.u[3] = d;
    return uu.v;
}

// ---------------- prologue: W transpose (z=0..3) + x fp32->bf16 (z=4) ----------------
__global__ __launch_bounds__(256) void prologue(const float* __restrict__ x,
                                                const float* __restrict__ Wq,
                                                const float* __restrict__ Wk,
                                                const float* __restrict__ Wv,
                                                const float* __restrict__ Wo,
                                                unsigned short* __restrict__ xb,
                                                unsigned short* __restrict__ wt) {
    const int z = blockIdx.z;
    const int tid = threadIdx.x;
    if (z == 4) {
        size_t base = ((size_t)blockIdx.y * 16 + blockIdx.x) * 16384;
#pragma unroll
        for (int it = 0; it < 8; ++it) {
            size_t i = base + (size_t)it * 2048 + (size_t)tid * 8;
            float4 a = *(const float4*)&x[i];
            float4 b = *(const float4*)&x[i + 4];
            unsigned short o8[8] __attribute__((aligned(16)));
            o8[0] = bf_round(a.x); o8[1] = bf_round(a.y); o8[2] = bf_round(a.z); o8[3] = bf_round(a.w);
            o8[4] = bf_round(b.x); o8[5] = bf_round(b.y); o8[6] = bf_round(b.z); o8[7] = bf_round(b.w);
            *(uint4*)&xb[i] = *(const uint4*)o8;
        }
        return;
    }
    const float* W = (z == 0) ? Wq : (z == 1) ? Wk : (z == 2) ? Wv : Wo;
    unsigned short* dst = wt + (size_t)z * Dm * Dm;
    __shared__ float T[64][65];
    const int k0 = blockIdx.x * 64, n0 = blockIdx.y * 64;
#pragma unroll
    for (int i = 0; i < 4; ++i) {
        int s = tid + i * 256;
        int kk = s >> 4, c = (s & 15) * 4;
        *(float4*)&T[kk][c] = *(const float4*)&W[(size_t)(k0 + kk) * Dm + n0 + c];
    }
    __syncthreads();
#pragma unroll
    for (int i = 0; i < 2; ++i) {
        int s = tid + i * 256;
        int n = s >> 3, c8 = (s & 7) * 8;
        unsigned short o8[8] __attribute__((aligned(16)));
#pragma unroll
        for (int j = 0; j < 8; ++j) o8[j] = bf_round(T[c8 + j][n]);
        *(uint4*)&dst[(size_t)(n0 + n) * Dm + k0 + c8] = *(const uint4*)o8;
    }
}

// ====================================================================
// single-phase 256x192 QKV GEMM: all reads (A both halves + all B = 22)
// up front, 48 MFMA cluster, 3 barriers/K-tile (was 5).
// ====================================================================
__global__ __launch_bounds__(512) void gemm_qkv192(
    const unsigned short* __restrict__ xb,
    const unsigned short* __restrict__ wt,
    const float* __restrict__ bq, const float* __restrict__ bk,
    const float* __restrict__ bv,
    unsigned short* __restrict__ qbuf, unsigned short* __restrict__ kbuf,
    unsigned short* __restrict__ vtbuf)
{
    __shared__ unsigned short Alds[2][256 * 64];
    __shared__ unsigned short Blds[2][192 * 64];

    const int tid = threadIdx.x;
    const int lane = tid & 63, wid = tid >> 6;
    const int wm = wid >> 2, wn = wid & 3;
    const int l15 = lane & 15, lg = lane >> 4;

    const int bid = blockIdx.x;
    const int swz = (bid & 7) * 32 + (bid >> 3);
    const int bx = swz & 15, by = swz >> 4;
    const int m0 = by * 256, n0 = bx * 192;

    const int srow = wid * 8 + (lane >> 3);
    const int scol = ((lane & 7) ^ ((lane >> 3) & 7)) * 8;

    const unsigned short* Abase = xb + (size_t)m0 * Dm;
    const unsigned short* Bbase = wt + (size_t)n0 * Dm;

#define STAGE_TILE(t)                                                              \
    do {                                                                           \
        const unsigned short* As_ = Abase + (t) * 64;                              \
        const unsigned short* Bs_ = Bbase + (t) * 64;                              \
        unsigned short* Ad_ = Alds[(t) & 1];                                       \
        unsigned short* Bd_ = Blds[(t) & 1];                                       \
        _Pragma("unroll")                                                          \
        for (int i_ = 0; i_ < 4; ++i_)                                             \
            gload_lds16(&As_[(size_t)(i_ * 64 + srow) * Dm + scol],                \
                        &Ad_[i_ * 4096 + wid * 512]);                              \
        _Pragma("unroll")                                                          \
        for (int i_ = 0; i_ < 3; ++i_)                                             \
            gload_lds16(&Bs_[(size_t)(i_ * 64 + srow) * Dm + scol],                \
                        &Bd_[i_ * 4096 + wid * 512]);                              \
    } while (0)

    f32x4 acc[8][3];
#pragma unroll
    for (int mr = 0; mr < 8; ++mr)
#pragma unroll
        for (int nr = 0; nr < 3; ++nr) acc[mr][nr] = (f32x4){0.f, 0.f, 0.f, 0.f};

    STAGE_TILE(0);
    asm volatile("s_waitcnt vmcnt(0)" ::: "memory");
    __builtin_amdgcn_s_barrier();

    for (int t = 0; t < Dm / 64; ++t) {
        unsigned short* Ad = Alds[t & 1];
        unsigned short* Bd = Blds[t & 1];
        if (t + 1 < Dm / 64) STAGE_TILE(t + 1);

        bf16x8 a_[8][2], b_[3][2];

#define RD_A(qm, fr, ks) \
    (*(const bf16x8*)&Ad[(wm * 128 + (qm) * 64 + (fr) * 16 + l15) * 64 + \
                         ((((ks) * 4 + lg) ^ (l15 & 7)) * 8)])
#define RD_B(fc, ks) \
    (*(const bf16x8*)&Bd[(wn * 48 + (fc) * 16 + l15) * 64 + \
                         ((((ks) * 4 + lg) ^ (l15 & 7)) * 8)])

        // ---- all reads: A half0+half1 (16) + all B (6) ----
#pragma unroll
        for (int fr = 0; fr < 4; ++fr) {
            a_[fr][0] = RD_A(0, fr, 0);     a_[fr][1] = RD_A(0, fr, 1);
            a_[4 + fr][0] = RD_A(1, fr, 0); a_[4 + fr][1] = RD_A(1, fr, 1);
        }
#pragma unroll
        for (int fc = 0; fc < 3; ++fc) {
            b_[fc][0] = RD_B(fc, 0); b_[fc][1] = RD_B(fc, 1);
        }
        __builtin_amdgcn_s_barrier();
        __builtin_amdgcn_s_setprio(1);
#pragma unroll
        for (int mr = 0; mr < 8; ++mr)
#pragma unroll
            for (int fc = 0; fc < 3; ++fc)
#pragma unroll
                for (int ks = 0; ks < 2; ++ks)
                    acc[mr][fc] = __builtin_amdgcn_mfma_f32_16x16x32_bf16(
                        a_[mr][ks], b_[fc][ks], acc[mr][fc], 0, 0, 0);
        __builtin_amdgcn_s_setprio(0);
        __builtin_amdgcn_s_barrier();

        asm volatile("s_waitcnt vmcnt(0)" ::: "memory");
        __builtin_amdgcn_s_barrier();
#undef RD_A
#undef RD_B
    }

    const float qscale = 0.18033688011f;   // 1/8 * log2(e)
#pragma unroll
    for (int mr = 0; mr < 8; ++mr) {
#pragma unroll
        for (int nr = 0; nr < 3; ++nr) {
            const int m = m0 + wm * 128 + mr * 16 + lg * 4;
            const int nglob = n0 + wn * 48 + nr * 16 + l15;
            const int zq = nglob >> 10;
            const int nz = nglob & 1023;
            const float* bias = (zq == 0) ? bq : (zq == 1) ? bk : bv;
            const float bb_ = bias[nz];
            if (zq == 0) {
#pragma unroll
                for (int rr = 0; rr < 4; ++rr)
                    qbuf[(size_t)(m + rr) * Dm + nz] =
                        bf_round((acc[mr][nr][rr] + bb_) * qscale);
            } else if (zq == 1) {
#pragma unroll
                for (int rr = 0; rr < 4; ++rr)
                    kbuf[(size_t)(m + rr) * Dm + nz] = bf_round(acc[mr][nr][rr] + bb_);
            } else {
                const int bbv = m >> 11, s = m & (SQ - 1);
                const int hh = nz >> 6, d = nz & 63;
                unsigned short p4[4] __attribute__((aligned(8)));
#pragma unroll
                for (int rr = 0; rr < 4; ++rr) p4[rr] = bf_round(acc[mr][nr][rr] + bb_);
                *(uint2*)&vtbuf[(((size_t)bbv * NH + hh) * 64 + d) * SQ + s] =
                    *(const uint2*)p4;
            }
        }
    }
#undef STAGE_TILE
}

// ====================================================================
// output projection, single-phase 128x128: 16 reads, 32 MFMA, 3 barriers/tile
// ====================================================================
__global__ __launch_bounds__(256) void gemm_out8(const unsigned short* __restrict__ A,
                                                 const unsigned short* __restrict__ Bt,
                                                 const float* __restrict__ bias,
                                                 float* __restrict__ Cf) {
    __shared__ unsigned short Alds[2][128 * 64];
    __shared__ unsigned short Blds[2][128 * 64];

    const int tid = threadIdx.x;
    const int lane = tid & 63, wid = tid >> 6;
    const int l15 = lane & 15, lg = lane >> 4;
    const int wr = (wid >> 1) * 64, wc = (wid & 1) * 64;
    const int m0 = blockIdx.y * 128, n0 = blockIdx.x * 128;

    const int srow = (tid >> 3) & 31;
    const int scol = ((tid & 7) ^ (srow & 7)) * 8;

    const unsigned short* Abase = A + (size_t)m0 * Dm;
    const unsigned short* Bbase = Bt + (size_t)n0 * Dm;

#define STAGE_TILE(t)                                                              \
    do {                                                                           \
        const unsigned short* As_ = Abase + (t) * 64;                              \
        const unsigned short* Bs_ = Bbase + (t) * 64;                              \
        unsigned short* Ad_ = Alds[(t) & 1];                                       \
        unsigned short* Bd_ = Blds[(t) & 1];                                       \
        _Pragma("unroll")                                                          \
        for (int i_ = 0; i_ < 4; ++i_) {                                           \
            gload_lds16(&As_[(size_t)(i_ * 32 + srow) * Dm + scol],                \
                        &Ad_[i_ * 2048 + wid * 512]);                              \
            gload_lds16(&Bs_[(size_t)(i_ * 32 + srow) * Dm + scol],                \
                        &Bd_[i_ * 2048 + wid * 512]);                              \
        }                                                                          \
    } while (0)

    f32x4 acc[4][4];
#pragma unroll
    for (int r = 0; r < 4; ++r)
#pragma unroll
        for (int c = 0; c < 4; ++c) acc[r][c] = (f32x4){0.f, 0.f, 0.f, 0.f};

    STAGE_TILE(0);
    asm volatile("s_waitcnt vmcnt(0)" ::: "memory");
    __builtin_amdgcn_s_barrier();

    for (int t = 0; t < Dm / 64; ++t) {
        unsigned short* Ad = Alds[t & 1];
        unsigned short* Bd = Blds[t & 1];
        if (t + 1 < Dm / 64) STAGE_TILE(t + 1);

        bf16x8 a_[4][2], b_[4][2];

#define RD_A(fr, ks) \
    (*(const bf16x8*)&Ad[(wr + (fr) * 16 + l15) * 64 + ((((ks) * 4 + lg) ^ (l15 & 7)) * 8)])
#define RD_B(fc, ks) \
    (*(const bf16x8*)&Bd[(wc + (fc) * 16 + l15) * 64 + ((((ks) * 4 + lg) ^ (l15 & 7)) * 8)])

#pragma unroll
        for (int fr = 0; fr < 4; ++fr) {
            a_[fr][0] = RD_A(fr, 0); a_[fr][1] = RD_A(fr, 1);
        }
#pragma unroll
        for (int fc = 0; fc < 4; ++fc) {
            b_[fc][0] = RD_B(fc, 0); b_[fc][1] = RD_B(fc, 1);
        }
        __builtin_amdgcn_s_barrier();
        __builtin_amdgcn_s_setprio(1);
#pragma unroll
        for (int fr = 0; fr < 4; ++fr)
#pragma unroll
            for (int fc = 0; fc < 4; ++fc)
#pragma unroll
                for (int ks = 0; ks < 2; ++ks)
                    acc[fr][fc] = __builtin_amdgcn_mfma_f32_16x16x32_bf16(
                        a_[fr][ks], b_[fc][ks], acc[fr][fc], 0, 0, 0);
        __builtin_amdgcn_s_setprio(0);
        __builtin_amdgcn_s_barrier();

        asm volatile("s_waitcnt vmcnt(0)" ::: "memory");
        __builtin_amdgcn_s_barrier();
#undef RD_A
#undef RD_B
    }

#pragma unroll
    for (int r = 0; r < 4; ++r) {
#pragma unroll
        for (int c = 0; c < 4; ++c) {
            const int mBase = m0 + wr + r * 16 + lg * 4;
            const int n = n0 + wc + c * 16 + l15;
            const float bv_ = bias[n];
#pragma unroll
            for (int rr = 0; rr < 4; ++rr)
                Cf[(size_t)(mBase + rr) * Dm + n] = acc[r][c][rr] + bv_;
        }
    }
#undef STAGE_TILE
}

// ---------------- flash attention: round-14 verified body (KVBLK=64, dbuf) ----
__global__ __launch_bounds__(256) void attn_bf16(const unsigned short* q,
                                                 const unsigned short* __restrict__ k,
                                                 const unsigned short* __restrict__ vt,
                                                 unsigned short* ao) {
    __shared__ unsigned short KVs[2][2][64 * 64];  // [buf][0=K,1=Vt], XOR-swizzled
    const int qt = blockIdx.x, h = blockIdx.y, b = blockIdx.z;
    const int tid = threadIdx.x, lane = tid & 63, wid = tid >> 6;
    const int l31 = lane & 31, hi = lane >> 5;

    const size_t qrow0 = (size_t)b * SQ + qt * 128;
    const unsigned short* qp = q + (qrow0 + wid * 32 + l31) * Dm + h * 64;
    bf16x8 qf[4];
#pragma unroll
    for (int ks = 0; ks < 4; ++ks)
        qf[ks] = *(const bf16x8*)&qp[ks * 16 + hi * 8];

    const unsigned short* kb = k + (size_t)b * SQ * Dm + h * 64;
    const unsigned short* vb = vt + ((size_t)b * NH + h) * 64 * SQ;

    const int row0 = tid >> 3;
    const int s8 = (tid & 7) * 8;
    const int sw8 = (((tid & 7) ^ (row0 & 7))) * 8;
    const int koff0 = row0 * 64 + sw8;
    const int koff1 = (row0 + 32) * 64 + sw8;

    {   // prologue: stage tile 0 into buf 0
        uint4 k0v = *(const uint4*)&kb[(size_t)row0 * Dm + s8];
        uint4 k1v = *(const uint4*)&kb[(size_t)(row0 + 32) * Dm + s8];
        uint4 v0v = *(const uint4*)&vb[(size_t)row0 * SQ + s8];
        uint4 v1v = *(const uint4*)&vb[(size_t)(row0 + 32) * SQ + s8];
        *(uint4*)&KVs[0][0][koff0] = k0v; *(uint4*)&KVs[0][0][koff1] = k1v;
        *(uint4*)&KVs[0][1][koff0] = v0v; *(uint4*)&KVs[0][1][koff1] = v1v;
    }
    __syncthreads();

    float psum = 0.f;
    f32x16 c0, c1;
#pragma unroll
    for (int i = 0; i < 16; ++i) { c0[i] = 0.f; c1[i] = 0.f; }

    int cur = 0;
    for (int t0 = 0; t0 < SQ; t0 += 64) {
        const bool hasNext = (t0 + 64) < SQ;
        uint4 kr0, kr1, vr0, vr1;
        if (hasNext) {   // T14: issue next-tile loads early
            const unsigned short* kn = kb + (size_t)(t0 + 64) * Dm;
            const unsigned short* vn = vb + (t0 + 64);
            kr0 = *(const uint4*)&kn[(size_t)row0 * Dm + s8];
            kr1 = *(const uint4*)&kn[(size_t)(row0 + 32) * Dm + s8];
            vr0 = *(const uint4*)&vn[(size_t)row0 * SQ + s8];
            vr1 = *(const uint4*)&vn[(size_t)(row0 + 32) * SQ + s8];
        }
        const unsigned short* Kc = KVs[cur][0];
        const unsigned short* Vc = KVs[cur][1];

#pragma unroll
        for (int kblk = 0; kblk < 2; ++kblk) {
            f32x16 p;
#pragma unroll
            for (int i = 0; i < 16; ++i) p[i] = 0.f;
            __builtin_amdgcn_s_setprio(1);
#pragma unroll
            for (int ks = 0; ks < 4; ++ks) {
                int row = kblk * 32 + l31;
                int slot = ((ks * 2 + hi) ^ (l31 & 7)) * 8;
                bf16x8 kf = *(const bf16x8*)&Kc[row * 64 + slot];
                p = __builtin_amdgcn_mfma_f32_32x32x16_bf16(kf, qf[ks], p, 0, 0, 0);
            }
            __builtin_amdgcn_s_setprio(0);

            float e[16];
#pragma unroll
            for (int i = 0; i < 16; ++i) { e[i] = exp2_fast(p[i]); psum += e[i]; }
            unsigned w0 = cvt_pk(e[0], e[1]),   w1 = cvt_pk(e[2], e[3]);
            unsigned w2 = cvt_pk(e[4], e[5]),   w3 = cvt_pk(e[6], e[7]);
            unsigned w4 = cvt_pk(e[8], e[9]),   w5 = cvt_pk(e[10], e[11]);
            unsigned w6 = cvt_pk(e[12], e[13]), w7 = cvt_pk(e[14], e[15]);
            permlane_swap(w0, w2); permlane_swap(w1, w3);
            permlane_swap(w4, w6); permlane_swap(w5, w7);
            bf16x8 pf0 = make_frag(w0, w1, w2, w3);
            bf16x8 pf1 = make_frag(w4, w5, w6, w7);

            int s0 = ((kblk * 4 + hi) ^ (l31 & 7)) * 8;
            int s1 = ((kblk * 4 + 2 + hi) ^ (l31 & 7)) * 8;
            bf16x8 va0 = *(const bf16x8*)&Vc[l31 * 64 + s0];
            bf16x8 va1 = *(const bf16x8*)&Vc[l31 * 64 + s1];
            bf16x8 vb0 = *(const bf16x8*)&Vc[(32 + l31) * 64 + s0];
            bf16x8 vb1 = *(const bf16x8*)&Vc[(32 + l31) * 64 + s1];
            __builtin_amdgcn_s_setprio(1);
            c0 = __builtin_amdgcn_mfma_f32_32x32x16_bf16(va0, pf0, c0, 0, 0, 0);
            c0 = __builtin_amdgcn_mfma_f32_32x32x16_bf16(va1, pf1, c0, 0, 0, 0);
            c1 = __builtin_amdgcn_mfma_f32_32x32x16_bf16(vb0, pf0, c1, 0, 0, 0);
            c1 = __builtin_amdgcn_mfma_f32_32x32x16_bf16(vb1, pf1, c1, 0, 0, 0);
            __builtin_amdgcn_s_setprio(0);
        }

        if (hasNext) {
            unsigned short* Kn = KVs[cur ^ 1][0];
            unsigned short* Vn = KVs[cur ^ 1][1];
            *(uint4*)&Kn[koff0] = kr0; *(uint4*)&Kn[koff1] = kr1;
            *(uint4*)&Vn[koff0] = vr0; *(uint4*)&Vn[koff1] = vr1;
        }
        __syncthreads();
        cur ^= 1;
    }

    float s = psum + __shfl_xor(psum, 32, 64);
    float inv = 1.f / s;

    unsigned short* Olds = (unsigned short*)KVs;
    {
        const int orow = wid * 32 + l31;
#pragma unroll
        for (int db = 0; db < 2; ++db) {
#pragma unroll
            for (int i = 0; i < 8; ++i) {
                float lo  = (db ? c1[2 * i] : c0[2 * i]) * inv;
                float hi_ = (db ? c1[2 * i + 1] : c0[2 * i + 1]) * inv;
                unsigned w = cvt_pk(lo, hi_);
                int d7 = hi * 4 + (i & 1) * 2;
                int slot = db * 4 + (i >> 1);
                int sw = slot ^ (l31 & 7);
                *(unsigned*)&Olds[orow * 64 + sw * 8 + d7] = w;
            }
        }
    }
    __syncthreads();
    {
        int r = tid >> 1, half = tid & 1;
        unsigned short* dst = ao + (qrow0 + r) * Dm + h * 64 + half * 32;
#pragma unroll
        for (int j = 0; j < 4; ++j) {
            int slot = half * 4 + j;
            int sw = slot ^ (r & 7);
            *(uint4*)&dst[j * 8] = *(const uint4*)&Olds[r * 64 + sw * 8];
        }
    }
}

extern "C" void kernel_launch(void* const* d_in, const int* in_sizes, int n_in,
                              void* d_out, int out_size, void* d_ws, size_t ws_size,
                              hipStream_t stream) {
    const float* x  = (const float*)d_in[0];
    const float* Wq = (const float*)d_in[1];
    const float* bq = (const float*)d_in[2];
    const float* Wk = (const float*)d_in[3];
    const float* bk = (const float*)d_in[4];
    const float* Wv = (const float*)d_in[5];
    const float* bv = (const float*)d_in[6];
    const float* Wo = (const float*)d_in[7];
    const float* bo = (const float*)d_in[8];
    float* out = (float*)d_out;

    const size_t M = (size_t)NB * SQ;           // 4096
    const size_t elems = M * Dm;                // 4M
    unsigned short* xb    = (unsigned short*)d_ws;
    unsigned short* wtb   = xb + elems;
    unsigned short* qbuf  = wtb + 4ull * Dm * Dm;
    unsigned short* kbuf  = qbuf + elems;
    unsigned short* vtbuf = kbuf + elems;

    dim3 blk(256);
    hipLaunchKernelGGL(prologue, dim3(16, 16, 5), blk, 0, stream,
                       x, Wq, Wk, Wv, Wo, xb, wtb);

    hipLaunchKernelGGL(gemm_qkv192, dim3(256), dim3(512), 0, stream,
                       xb, wtb, bq, bk, bv, qbuf, kbuf, vtbuf);

    hipLaunchKernelGGL(attn_bf16, dim3(SQ / 128, NH, NB), blk, 0, stream,
                       qbuf, kbuf, vtbuf, qbuf);

    hipLaunchKernelGGL(gemm_out8, dim3(Dm / 128, M / 128), blk, 0, stream,
                       qbuf, wtb + 3ull * Dm * Dm, bo, out);
}

// Round 19
// 111.780 us; speedup vs baseline: 1.0984x; 1.0021x over previous
//
#include <hip/hip_runtime.h>
#include <math.h>

constexpr int Dm  = 1024;
constexpr int NH  = 16;
constexpr int SQ  = 2048;
constexpr int NB  = 2;

typedef float f32x4 __attribute__((ext_vector_type(4)));
typedef float f32x16 __attribute__((ext_vector_type(16)));
typedef short bf16x8 __attribute__((ext_vector_type(8)));
typedef __attribute__((address_space(3))) unsigned int lds_u32;
typedef __attribute__((address_space(1))) const unsigned int glb_u32;

__device__ __forceinline__ void gload_lds16(const void* g, void* l) {
    __builtin_amdgcn_global_load_lds((glb_u32*)(uintptr_t)g, (lds_u32*)(uintptr_t)l, 16, 0, 0);
}

__device__ __forceinline__ unsigned short bf_round(float x) {
    unsigned u = __float_as_uint(x);
    unsigned r = u + 0x7fffu + ((u >> 16) & 1u);
    return (unsigned short)(r >> 16);
}

__device__ __forceinline__ float exp2_fast(float x) {
    float r;
    asm("v_exp_f32 %0, %1" : "=v"(r) : "v"(x));
    return r;
}

__device__ __forceinline__ unsigned cvt_pk(float lo, float hi_) {
    unsigned r;
    asm("v_cvt_pk_bf16_f32 %0, %1, %2" : "=v"(r) : "v"(lo), "v"(hi_));
    return r;
}

__device__ __forceinline__ void permlane_swap(unsigned& a, unsigned& b) {
    asm volatile("v_permlane32_swap_b32 %0, %1" : "+v"(a), "+v"(b));
}

__device__ __forceinline__ bf16x8 make_frag(unsigned a, unsigned b, unsigned c, unsigned d) {
    union { unsigned u[4]; bf16x8 v; } uu;
    uu.u[0] = a; uu.u[1] = b; uu.u[2] = c; uu.u[3] = d;
    return uu.v;
}

// ---------------- prologue: W transpose (z=0..3) + x fp32->bf16 (z=4) ----------------
__global__ __launch_bounds__(256) void prologue(const float* __restrict__ x,
                                                const float* __restrict__ Wq,
                                                const float* __restrict__ Wk,
                                                const float* __restrict__ Wv,
                                                const float* __restrict__ Wo,
                                                unsigned short* __restrict__ xb,
                                                unsigned short* __restrict__ wt) {
    const int z = blockIdx.z;
    const int tid = threadIdx.x;
    if (z == 4) {
        size_t base = ((size_t)blockIdx.y * 16 + blockIdx.x) * 16384;
#pragma unroll
        for (int it = 0; it < 8; ++it) {
            size_t i = base + (size_t)it * 2048 + (size_t)tid * 8;
            float4 a = *(const float4*)&x[i];
            float4 b = *(const float4*)&x[i + 4];
            unsigned short o8[8] __attribute__((aligned(16)));
            o8[0] = bf_round(a.x); o8[1] = bf_round(a.y); o8[2] = bf_round(a.z); o8[3] = bf_round(a.w);
            o8[4] = bf_round(b.x); o8[5] = bf_round(b.y); o8[6] = bf_round(b.z); o8[7] = bf_round(b.w);
            *(uint4*)&xb[i] = *(const uint4*)o8;
        }
        return;
    }
    const float* W = (z == 0) ? Wq : (z == 1) ? Wk : (z == 2) ? Wv : Wo;
    unsigned short* dst = wt + (size_t)z * Dm * Dm;
    __shared__ float T[64][65];
    const int k0 = blockIdx.x * 64, n0 = blockIdx.y * 64;
#pragma unroll
    for (int i = 0; i < 4; ++i) {
        int s = tid + i * 256;
        int kk = s >> 4, c = (s & 15) * 4;
        *(float4*)&T[kk][c] = *(const float4*)&W[(size_t)(k0 + kk) * Dm + n0 + c];
    }
    __syncthreads();
#pragma unroll
    for (int i = 0; i < 2; ++i) {
        int s = tid + i * 256;
        int n = s >> 3, c8 = (s & 7) * 8;
        unsigned short o8[8] __attribute__((aligned(16)));
#pragma unroll
        for (int j = 0; j < 8; ++j) o8[j] = bf_round(T[c8 + j][n]);
        *(uint4*)&dst[(size_t)(n0 + n) * Dm + k0 + c8] = *(const uint4*)o8;
    }
}

// ====================================================================
// single-phase 256x192 QKV GEMM: all reads (A both halves + all B = 22)
// up front, 48 MFMA cluster, 3 barriers/K-tile (was 5).
// ====================================================================
__global__ __launch_bounds__(512) void gemm_qkv192(
    const unsigned short* __restrict__ xb,
    const unsigned short* __restrict__ wt,
    const float* __restrict__ bq, const float* __restrict__ bk,
    const float* __restrict__ bv,
    unsigned short* __restrict__ qbuf, unsigned short* __restrict__ kbuf,
    unsigned short* __restrict__ vtbuf)
{
    __shared__ unsigned short Alds[2][256 * 64];
    __shared__ unsigned short Blds[2][192 * 64];

    const int tid = threadIdx.x;
    const int lane = tid & 63, wid = tid >> 6;
    const int wm = wid >> 2, wn = wid & 3;
    const int l15 = lane & 15, lg = lane >> 4;

    const int bid = blockIdx.x;
    const int swz = (bid & 7) * 32 + (bid >> 3);
    const int bx = swz & 15, by = swz >> 4;
    const int m0 = by * 256, n0 = bx * 192;

    const int srow = wid * 8 + (lane >> 3);
    const int scol = ((lane & 7) ^ ((lane >> 3) & 7)) * 8;

    const unsigned short* Abase = xb + (size_t)m0 * Dm;
    const unsigned short* Bbase = wt + (size_t)n0 * Dm;

#define STAGE_TILE(t)                                                              \
    do {                                                                           \
        const unsigned short* As_ = Abase + (t) * 64;                              \
        const unsigned short* Bs_ = Bbase + (t) * 64;                              \
        unsigned short* Ad_ = Alds[(t) & 1];                                       \
        unsigned short* Bd_ = Blds[(t) & 1];                                       \
        _Pragma("unroll")                                                          \
        for (int i_ = 0; i_ < 4; ++i_)                                             \
            gload_lds16(&As_[(size_t)(i_ * 64 + srow) * Dm + scol],                \
                        &Ad_[i_ * 4096 + wid * 512]);                              \
        _Pragma("unroll")                                                          \
        for (int i_ = 0; i_ < 3; ++i_)                                             \
            gload_lds16(&Bs_[(size_t)(i_ * 64 + srow) * Dm + scol],                \
                        &Bd_[i_ * 4096 + wid * 512]);                              \
    } while (0)

    f32x4 acc[8][3];
#pragma unroll
    for (int mr = 0; mr < 8; ++mr)
#pragma unroll
        for (int nr = 0; nr < 3; ++nr) acc[mr][nr] = (f32x4){0.f, 0.f, 0.f, 0.f};

    STAGE_TILE(0);
    asm volatile("s_waitcnt vmcnt(0)" ::: "memory");
    __builtin_amdgcn_s_barrier();

    for (int t = 0; t < Dm / 64; ++t) {
        unsigned short* Ad = Alds[t & 1];
        unsigned short* Bd = Blds[t & 1];
        if (t + 1 < Dm / 64) STAGE_TILE(t + 1);

        bf16x8 a_[8][2], b_[3][2];

#define RD_A(qm, fr, ks) \
    (*(const bf16x8*)&Ad[(wm * 128 + (qm) * 64 + (fr) * 16 + l15) * 64 + \
                         ((((ks) * 4 + lg) ^ (l15 & 7)) * 8)])
#define RD_B(fc, ks) \
    (*(const bf16x8*)&Bd[(wn * 48 + (fc) * 16 + l15) * 64 + \
                         ((((ks) * 4 + lg) ^ (l15 & 7)) * 8)])

        // ---- all reads: A half0+half1 (16) + all B (6) ----
#pragma unroll
        for (int fr = 0; fr < 4; ++fr) {
            a_[fr][0] = RD_A(0, fr, 0);     a_[fr][1] = RD_A(0, fr, 1);
            a_[4 + fr][0] = RD_A(1, fr, 0); a_[4 + fr][1] = RD_A(1, fr, 1);
        }
#pragma unroll
        for (int fc = 0; fc < 3; ++fc) {
            b_[fc][0] = RD_B(fc, 0); b_[fc][1] = RD_B(fc, 1);
        }
        __builtin_amdgcn_s_barrier();
        __builtin_amdgcn_s_setprio(1);
#pragma unroll
        for (int mr = 0; mr < 8; ++mr)
#pragma unroll
            for (int fc = 0; fc < 3; ++fc)
#pragma unroll
                for (int ks = 0; ks < 2; ++ks)
                    acc[mr][fc] = __builtin_amdgcn_mfma_f32_16x16x32_bf16(
                        a_[mr][ks], b_[fc][ks], acc[mr][fc], 0, 0, 0);
        __builtin_amdgcn_s_setprio(0);
        __builtin_amdgcn_s_barrier();

        asm volatile("s_waitcnt vmcnt(0)" ::: "memory");
        __builtin_amdgcn_s_barrier();
#undef RD_A
#undef RD_B
    }

    const float qscale = 0.18033688011f;   // 1/8 * log2(e)
#pragma unroll
    for (int mr = 0; mr < 8; ++mr) {
#pragma unroll
        for (int nr = 0; nr < 3; ++nr) {
            const int m = m0 + wm * 128 + mr * 16 + lg * 4;
            const int nglob = n0 + wn * 48 + nr * 16 + l15;
            const int zq = nglob >> 10;
            const int nz = nglob & 1023;
            const float* bias = (zq == 0) ? bq : (zq == 1) ? bk : bv;
            const float bb_ = bias[nz];
            if (zq == 0) {
#pragma unroll
                for (int rr = 0; rr < 4; ++rr)
                    qbuf[(size_t)(m + rr) * Dm + nz] =
                        bf_round((acc[mr][nr][rr] + bb_) * qscale);
            } else if (zq == 1) {
#pragma unroll
                for (int rr = 0; rr < 4; ++rr)
                    kbuf[(size_t)(m + rr) * Dm + nz] = bf_round(acc[mr][nr][rr] + bb_);
            } else {
                const int bbv = m >> 11, s = m & (SQ - 1);
                const int hh = nz >> 6, d = nz & 63;
                unsigned short p4[4] __attribute__((aligned(8)));
#pragma unroll
                for (int rr = 0; rr < 4; ++rr) p4[rr] = bf_round(acc[mr][nr][rr] + bb_);
                *(uint2*)&vtbuf[(((size_t)bbv * NH + hh) * 64 + d) * SQ + s] =
                    *(const uint2*)p4;
            }
        }
    }
#undef STAGE_TILE
}

// ====================================================================
// output projection, single-phase 128x128: 16 reads, 32 MFMA, 3 barriers/tile
// ====================================================================
__global__ __launch_bounds__(256) void gemm_out8(const unsigned short* __restrict__ A,
                                                 const unsigned short* __restrict__ Bt,
                                                 const float* __restrict__ bias,
                                                 float* __restrict__ Cf) {
    __shared__ unsigned short Alds[2][128 * 64];
    __shared__ unsigned short Blds[2][128 * 64];

    const int tid = threadIdx.x;
    const int lane = tid & 63, wid = tid >> 6;
    const int l15 = lane & 15, lg = lane >> 4;
    const int wr = (wid >> 1) * 64, wc = (wid & 1) * 64;
    const int m0 = blockIdx.y * 128, n0 = blockIdx.x * 128;

    const int srow = (tid >> 3) & 31;
    const int scol = ((tid & 7) ^ (srow & 7)) * 8;

    const unsigned short* Abase = A + (size_t)m0 * Dm;
    const unsigned short* Bbase = Bt + (size_t)n0 * Dm;

#define STAGE_TILE(t)                                                              \
    do {                                                                           \
        const unsigned short* As_ = Abase + (t) * 64;                              \
        const unsigned short* Bs_ = Bbase + (t) * 64;                              \
        unsigned short* Ad_ = Alds[(t) & 1];                                       \
        unsigned short* Bd_ = Blds[(t) & 1];                                       \
        _Pragma("unroll")                                                          \
        for (int i_ = 0; i_ < 4; ++i_) {                                           \
            gload_lds16(&As_[(size_t)(i_ * 32 + srow) * Dm + scol],                \
                        &Ad_[i_ * 2048 + wid * 512]);                              \
            gload_lds16(&Bs_[(size_t)(i_ * 32 + srow) * Dm + scol],                \
                        &Bd_[i_ * 2048 + wid * 512]);                              \
        }                                                                          \
    } while (0)

    f32x4 acc[4][4];
#pragma unroll
    for (int r = 0; r < 4; ++r)
#pragma unroll
        for (int c = 0; c < 4; ++c) acc[r][c] = (f32x4){0.f, 0.f, 0.f, 0.f};

    STAGE_TILE(0);
    asm volatile("s_waitcnt vmcnt(0)" ::: "memory");
    __builtin_amdgcn_s_barrier();

    for (int t = 0; t < Dm / 64; ++t) {
        unsigned short* Ad = Alds[t & 1];
        unsigned short* Bd = Blds[t & 1];
        if (t + 1 < Dm / 64) STAGE_TILE(t + 1);

        bf16x8 a_[4][2], b_[4][2];

#define RD_A(fr, ks) \
    (*(const bf16x8*)&Ad[(wr + (fr) * 16 + l15) * 64 + ((((ks) * 4 + lg) ^ (l15 & 7)) * 8)])
#define RD_B(fc, ks) \
    (*(const bf16x8*)&Bd[(wc + (fc) * 16 + l15) * 64 + ((((ks) * 4 + lg) ^ (l15 & 7)) * 8)])

#pragma unroll
        for (int fr = 0; fr < 4; ++fr) {
            a_[fr][0] = RD_A(fr, 0); a_[fr][1] = RD_A(fr, 1);
        }
#pragma unroll
        for (int fc = 0; fc < 4; ++fc) {
            b_[fc][0] = RD_B(fc, 0); b_[fc][1] = RD_B(fc, 1);
        }
        __builtin_amdgcn_s_barrier();
        __builtin_amdgcn_s_setprio(1);
#pragma unroll
        for (int fr = 0; fr < 4; ++fr)
#pragma unroll
            for (int fc = 0; fc < 4; ++fc)
#pragma unroll
                for (int ks = 0; ks < 2; ++ks)
                    acc[fr][fc] = __builtin_amdgcn_mfma_f32_16x16x32_bf16(
                        a_[fr][ks], b_[fc][ks], acc[fr][fc], 0, 0, 0);
        __builtin_amdgcn_s_setprio(0);
        __builtin_amdgcn_s_barrier();

        asm volatile("s_waitcnt vmcnt(0)" ::: "memory");
        __builtin_amdgcn_s_barrier();
#undef RD_A
#undef RD_B
    }

#pragma unroll
    for (int r = 0; r < 4; ++r) {
#pragma unroll
        for (int c = 0; c < 4; ++c) {
            const int mBase = m0 + wr + r * 16 + lg * 4;
            const int n = n0 + wc + c * 16 + l15;
            const float bv_ = bias[n];
#pragma unroll
            for (int rr = 0; rr < 4; ++rr)
                Cf[(size_t)(mBase + rr) * Dm + n] = acc[r][c][rr] + bv_;
        }
    }
#undef STAGE_TILE
}

// ---------------- flash attention: round-14 verified body (KVBLK=64, dbuf) ----
__global__ __launch_bounds__(256) void attn_bf16(const unsigned short* q,
                                                 const unsigned short* __restrict__ k,
                                                 const unsigned short* __restrict__ vt,
                                                 unsigned short* ao) {
    __shared__ unsigned short KVs[2][2][64 * 64];  // [buf][0=K,1=Vt], XOR-swizzled
    const int qt = blockIdx.x, h = blockIdx.y, b = blockIdx.z;
    const int tid = threadIdx.x, lane = tid & 63, wid = tid >> 6;
    const int l31 = lane & 31, hi = lane >> 5;

    const size_t qrow0 = (size_t)b * SQ + qt * 128;
    const unsigned short* qp = q + (qrow0 + wid * 32 + l31) * Dm + h * 64;
    bf16x8 qf[4];
#pragma unroll
    for (int ks = 0; ks < 4; ++ks)
        qf[ks] = *(const bf16x8*)&qp[ks * 16 + hi * 8];

    const unsigned short* kb = k + (size_t)b * SQ * Dm + h * 64;
    const unsigned short* vb = vt + ((size_t)b * NH + h) * 64 * SQ;

    const int row0 = tid >> 3;
    const int s8 = (tid & 7) * 8;
    const int sw8 = (((tid & 7) ^ (row0 & 7))) * 8;
    const int koff0 = row0 * 64 + sw8;
    const int koff1 = (row0 + 32) * 64 + sw8;

    {   // prologue: stage tile 0 into buf 0
        uint4 k0v = *(const uint4*)&kb[(size_t)row0 * Dm + s8];
        uint4 k1v = *(const uint4*)&kb[(size_t)(row0 + 32) * Dm + s8];
        uint4 v0v = *(const uint4*)&vb[(size_t)row0 * SQ + s8];
        uint4 v1v = *(const uint4*)&vb[(size_t)(row0 + 32) * SQ + s8];
        *(uint4*)&KVs[0][0][koff0] = k0v; *(uint4*)&KVs[0][0][koff1] = k1v;
        *(uint4*)&KVs[0][1][koff0] = v0v; *(uint4*)&KVs[0][1][koff1] = v1v;
    }
    __syncthreads();

    float psum = 0.f;
    f32x16 c0, c1;
#pragma unroll
    for (int i = 0; i < 16; ++i) { c0[i] = 0.f; c1[i] = 0.f; }

    int cur = 0;
    for (int t0 = 0; t0 < SQ; t0 += 64) {
        const bool hasNext = (t0 + 64) < SQ;
        uint4 kr0, kr1, vr0, vr1;
        if (hasNext) {   // T14: issue next-tile loads early
            const unsigned short* kn = kb + (size_t)(t0 + 64) * Dm;
            const unsigned short* vn = vb + (t0 + 64);
            kr0 = *(const uint4*)&kn[(size_t)row0 * Dm + s8];
            kr1 = *(const uint4*)&kn[(size_t)(row0 + 32) * Dm + s8];
            vr0 = *(const uint4*)&vn[(size_t)row0 * SQ + s8];
            vr1 = *(const uint4*)&vn[(size_t)(row0 + 32) * SQ + s8];
        }
        const unsigned short* Kc = KVs[cur][0];
        const unsigned short* Vc = KVs[cur][1];

#pragma unroll
        for (int kblk = 0; kblk < 2; ++kblk) {
            f32x16 p;
#pragma unroll
            for (int i = 0; i < 16; ++i) p[i] = 0.f;
            __builtin_amdgcn_s_setprio(1);
#pragma unroll
            for (int ks = 0; ks < 4; ++ks) {
                int row = kblk * 32 + l31;
                int slot = ((ks * 2 + hi) ^ (l31 & 7)) * 8;
                bf16x8 kf = *(const bf16x8*)&Kc[row * 64 + slot];
                p = __builtin_amdgcn_mfma_f32_32x32x16_bf16(kf, qf[ks], p, 0, 0, 0);
            }
            __builtin_amdgcn_s_setprio(0);

            float e[16];
#pragma unroll
            for (int i = 0; i < 16; ++i) { e[i] = exp2_fast(p[i]); psum += e[i]; }
            unsigned w0 = cvt_pk(e[0], e[1]),   w1 = cvt_pk(e[2], e[3]);
            unsigned w2 = cvt_pk(e[4], e[5]),   w3 = cvt_pk(e[6], e[7]);
            unsigned w4 = cvt_pk(e[8], e[9]),   w5 = cvt_pk(e[10], e[11]);
            unsigned w6 = cvt_pk(e[12], e[13]), w7 = cvt_pk(e[14], e[15]);
            permlane_swap(w0, w2); permlane_swap(w1, w3);
            permlane_swap(w4, w6); permlane_swap(w5, w7);
            bf16x8 pf0 = make_frag(w0, w1, w2, w3);
            bf16x8 pf1 = make_frag(w4, w5, w6, w7);

            int s0 = ((kblk * 4 + hi) ^ (l31 & 7)) * 8;
            int s1 = ((kblk * 4 + 2 + hi) ^ (l31 & 7)) * 8;
            bf16x8 va0 = *(const bf16x8*)&Vc[l31 * 64 + s0];
            bf16x8 va1 = *(const bf16x8*)&Vc[l31 * 64 + s1];
            bf16x8 vb0 = *(const bf16x8*)&Vc[(32 + l31) * 64 + s0];
            bf16x8 vb1 = *(const bf16x8*)&Vc[(32 + l31) * 64 + s1];
            __builtin_amdgcn_s_setprio(1);
            c0 = __builtin_amdgcn_mfma_f32_32x32x16_bf16(va0, pf0, c0, 0, 0, 0);
            c0 = __builtin_amdgcn_mfma_f32_32x32x16_bf16(va1, pf1, c0, 0, 0, 0);
            c1 = __builtin_amdgcn_mfma_f32_32x32x16_bf16(vb0, pf0, c1, 0, 0, 0);
            c1 = __builtin_amdgcn_mfma_f32_32x32x16_bf16(vb1, pf1, c1, 0, 0, 0);
            __builtin_amdgcn_s_setprio(0);
        }

        if (hasNext) {
            unsigned short* Kn = KVs[cur ^ 1][0];
            unsigned short* Vn = KVs[cur ^ 1][1];
            *(uint4*)&Kn[koff0] = kr0; *(uint4*)&Kn[koff1] = kr1;
            *(uint4*)&Vn[koff0] = vr0; *(uint4*)&Vn[koff1] = vr1;
        }
        __syncthreads();
        cur ^= 1;
    }

    float s = psum + __shfl_xor(psum, 32, 64);
    float inv = 1.f / s;

    unsigned short* Olds = (unsigned short*)KVs;
    {
        const int orow = wid * 32 + l31;
#pragma unroll
        for (int db = 0; db < 2; ++db) {
#pragma unroll
            for (int i = 0; i < 8; ++i) {
                float lo  = (db ? c1[2 * i] : c0[2 * i]) * inv;
                float hi_ = (db ? c1[2 * i + 1] : c0[2 * i + 1]) * inv;
                unsigned w = cvt_pk(lo, hi_);
                int d7 = hi * 4 + (i & 1) * 2;
                int slot = db * 4 + (i >> 1);
                int sw = slot ^ (l31 & 7);
                *(unsigned*)&Olds[orow * 64 + sw * 8 + d7] = w;
            }
        }
    }
    __syncthreads();
    {
        int r = tid >> 1, half = tid & 1;
        unsigned short* dst = ao + (qrow0 + r) * Dm + h * 64 + half * 32;
#pragma unroll
        for (int j = 0; j < 4; ++j) {
            int slot = half * 4 + j;
            int sw = slot ^ (r & 7);
            *(uint4*)&dst[j * 8] = *(const uint4*)&Olds[r * 64 + sw * 8];
        }
    }
}

extern "C" void kernel_launch(void* const* d_in, const int* in_sizes, int n_in,
                              void* d_out, int out_size, void* d_ws, size_t ws_size,
                              hipStream_t stream) {
    const float* x  = (const float*)d_in[0];
    const float* Wq = (const float*)d_in[1];
    const float* bq = (const float*)d_in[2];
    const float* Wk = (const float*)d_in[3];
    const float* bk = (const float*)d_in[4];
    const float* Wv = (const float*)d_in[5];
    const float* bv = (const float*)d_in[6];
    const float* Wo = (const float*)d_in[7];
    const float* bo = (const float*)d_in[8];
    float* out = (float*)d_out;

    const size_t M = (size_t)NB * SQ;           // 4096
    const size_t elems = M * Dm;                // 4M
    unsigned short* xb    = (unsigned short*)d_ws;
    unsigned short* wtb   = xb + elems;
    unsigned short* qbuf  = wtb + 4ull * Dm * Dm;
    unsigned short* kbuf  = qbuf + elems;
    unsigned short* vtbuf = kbuf + elems;

    dim3 blk(256);
    hipLaunchKernelGGL(prologue, dim3(16, 16, 5), blk, 0, stream,
                       x, Wq, Wk, Wv, Wo, xb, wtb);

    hipLaunchKernelGGL(gemm_qkv192, dim3(256), dim3(512), 0, stream,
                       xb, wtb, bq, bk, bv, qbuf, kbuf, vtbuf);

    hipLaunchKernelGGL(attn_bf16, dim3(SQ / 128, NH, NB), blk, 0, stream,
                       qbuf, kbuf, vtbuf, qbuf);

    hipLaunchKernelGGL(gemm_out8, dim3(Dm / 128, M / 128), blk, 0, stream,
                       qbuf, wtb + 3ull * Dm * Dm, bo, out);
}

// Round 20
// 110.688 us; speedup vs baseline: 1.1092x; 1.0099x over previous
//
#include <hip/hip_runtime.h>
#include <math.h>

constexpr int Dm  = 1024;
constexpr int NH  = 16;
constexpr int SQ  = 2048;
constexpr int NB  = 2;

typedef float f32x4 __attribute__((ext_vector_type(4)));
typedef float f32x16 __attribute__((ext_vector_type(16)));
typedef short bf16x8 __attribute__((ext_vector_type(8)));
typedef __attribute__((address_space(3))) unsigned int lds_u32;
typedef __attribute__((address_space(1))) const unsigned int glb_u32;

__device__ __forceinline__ void gload_lds16(const void* g, void* l) {
    __builtin_amdgcn_global_load_lds((glb_u32*)(uintptr_t)g, (lds_u32*)(uintptr_t)l, 16, 0, 0);
}

__device__ __forceinline__ unsigned short bf_round(float x) {
    unsigned u = __float_as_uint(x);
    unsigned r = u + 0x7fffu + ((u >> 16) & 1u);
    return (unsigned short)(r >> 16);
}

__device__ __forceinline__ float exp2_fast(float x) {
    float r;
    asm("v_exp_f32 %0, %1" : "=v"(r) : "v"(x));
    return r;
}

__device__ __forceinline__ unsigned cvt_pk(float lo, float hi_) {
    unsigned r;
    asm("v_cvt_pk_bf16_f32 %0, %1, %2" : "=v"(r) : "v"(lo), "v"(hi_));
    return r;
}

__device__ __forceinline__ void permlane_swap(unsigned& a, unsigned& b) {
    asm volatile("v_permlane32_swap_b32 %0, %1" : "+v"(a), "+v"(b));
}

__device__ __forceinline__ bf16x8 make_frag(unsigned a, unsigned b, unsigned c, unsigned d) {
    union { unsigned u[4]; bf16x8 v; } uu;
    uu.u[0] = a; uu.u[1] = b; uu.u[2] = c; uu.u[3] = d;
    return uu.v;
}

// ---------------- prologue: W transpose (z=0..3) + x fp32->bf16 (z=4) ----------------
__global__ __launch_bounds__(256) void prologue(const float* __restrict__ x,
                                                const float* __restrict__ Wq,
                                                const float* __restrict__ Wk,
                                                const float* __restrict__ Wv,
                                                const float* __restrict__ Wo,
                                                unsigned short* __restrict__ xb,
                                                unsigned short* __restrict__ wt) {
    const int z = blockIdx.z;
    const int tid = threadIdx.x;
    if (z == 4) {
        size_t base = ((size_t)blockIdx.y * 16 + blockIdx.x) * 16384;
#pragma unroll
        for (int it = 0; it < 8; ++it) {
            size_t i = base + (size_t)it * 2048 + (size_t)tid * 8;
            float4 a = *(const float4*)&x[i];
            float4 b = *(const float4*)&x[i + 4];
            unsigned short o8[8] __attribute__((aligned(16)));
            o8[0] = bf_round(a.x); o8[1] = bf_round(a.y); o8[2] = bf_round(a.z); o8[3] = bf_round(a.w);
            o8[4] = bf_round(b.x); o8[5] = bf_round(b.y); o8[6] = bf_round(b.z); o8[7] = bf_round(b.w);
            *(uint4*)&xb[i] = *(const uint4*)o8;
        }
        return;
    }
    const float* W = (z == 0) ? Wq : (z == 1) ? Wk : (z == 2) ? Wv : Wo;
    unsigned short* dst = wt + (size_t)z * Dm * Dm;
    __shared__ float T[64][65];
    const int k0 = blockIdx.x * 64, n0 = blockIdx.y * 64;
#pragma unroll
    for (int i = 0; i < 4; ++i) {
        int s = tid + i * 256;
        int kk = s >> 4, c = (s & 15) * 4;
        *(float4*)&T[kk][c] = *(const float4*)&W[(size_t)(k0 + kk) * Dm + n0 + c];
    }
    __syncthreads();
#pragma unroll
    for (int i = 0; i < 2; ++i) {
        int s = tid + i * 256;
        int n = s >> 3, c8 = (s & 7) * 8;
        unsigned short o8[8] __attribute__((aligned(16)));
#pragma unroll
        for (int j = 0; j < 8; ++j) o8[j] = bf_round(T[c8 + j][n]);
        *(uint4*)&dst[(size_t)(n0 + n) * Dm + k0 + c8] = *(const uint4*)o8;
    }
}

// ====================================================================
// single-phase 256x192 QKV GEMM, ONE barrier per K-tile.
// Ordering proof: reads of buf t are protected by prev tile's
// vmcnt(0)+barrier (all waves' gload_lds drained, all waves synced);
// STAGE(t+2) (overwrites buf t) is issued only after this tile's
// barrier, and every wave's reads of buf t precede it in program order.
// ====================================================================
__global__ __launch_bounds__(512) void gemm_qkv192(
    const unsigned short* __restrict__ xb,
    const unsigned short* __restrict__ wt,
    const float* __restrict__ bq, const float* __restrict__ bk,
    const float* __restrict__ bv,
    unsigned short* __restrict__ qbuf, unsigned short* __restrict__ kbuf,
    unsigned short* __restrict__ vtbuf)
{
    __shared__ unsigned short Alds[2][256 * 64];
    __shared__ unsigned short Blds[2][192 * 64];

    const int tid = threadIdx.x;
    const int lane = tid & 63, wid = tid >> 6;
    const int wm = wid >> 2, wn = wid & 3;
    const int l15 = lane & 15, lg = lane >> 4;

    const int bid = blockIdx.x;
    const int swz = (bid & 7) * 32 + (bid >> 3);
    const int bx = swz & 15, by = swz >> 4;
    const int m0 = by * 256, n0 = bx * 192;

    const int srow = wid * 8 + (lane >> 3);
    const int scol = ((lane & 7) ^ ((lane >> 3) & 7)) * 8;

    const unsigned short* Abase = xb + (size_t)m0 * Dm;
    const unsigned short* Bbase = wt + (size_t)n0 * Dm;

#define STAGE_TILE(t)                                                              \
    do {                                                                           \
        const unsigned short* As_ = Abase + (t) * 64;                              \
        const unsigned short* Bs_ = Bbase + (t) * 64;                              \
        unsigned short* Ad_ = Alds[(t) & 1];                                       \
        unsigned short* Bd_ = Blds[(t) & 1];                                       \
        _Pragma("unroll")                                                          \
        for (int i_ = 0; i_ < 4; ++i_)                                             \
            gload_lds16(&As_[(size_t)(i_ * 64 + srow) * Dm + scol],                \
                        &Ad_[i_ * 4096 + wid * 512]);                              \
        _Pragma("unroll")                                                          \
        for (int i_ = 0; i_ < 3; ++i_)                                             \
            gload_lds16(&Bs_[(size_t)(i_ * 64 + srow) * Dm + scol],                \
                        &Bd_[i_ * 4096 + wid * 512]);                              \
    } while (0)

    f32x4 acc[8][3];
#pragma unroll
    for (int mr = 0; mr < 8; ++mr)
#pragma unroll
        for (int nr = 0; nr < 3; ++nr) acc[mr][nr] = (f32x4){0.f, 0.f, 0.f, 0.f};

    STAGE_TILE(0);
    asm volatile("s_waitcnt vmcnt(0)" ::: "memory");
    __builtin_amdgcn_s_barrier();

    for (int t = 0; t < Dm / 64; ++t) {
        unsigned short* Ad = Alds[t & 1];
        unsigned short* Bd = Blds[t & 1];
        if (t + 1 < Dm / 64) STAGE_TILE(t + 1);

        bf16x8 a_[8][2], b_[3][2];

#define RD_A(qm, fr, ks) \
    (*(const bf16x8*)&Ad[(wm * 128 + (qm) * 64 + (fr) * 16 + l15) * 64 + \
                         ((((ks) * 4 + lg) ^ (l15 & 7)) * 8)])
#define RD_B(fc, ks) \
    (*(const bf16x8*)&Bd[(wn * 48 + (fc) * 16 + l15) * 64 + \
                         ((((ks) * 4 + lg) ^ (l15 & 7)) * 8)])

#pragma unroll
        for (int fr = 0; fr < 4; ++fr) {
            a_[fr][0] = RD_A(0, fr, 0);     a_[fr][1] = RD_A(0, fr, 1);
            a_[4 + fr][0] = RD_A(1, fr, 0); a_[4 + fr][1] = RD_A(1, fr, 1);
        }
#pragma unroll
        for (int fc = 0; fc < 3; ++fc) {
            b_[fc][0] = RD_B(fc, 0); b_[fc][1] = RD_B(fc, 1);
        }
        __builtin_amdgcn_s_setprio(1);
#pragma unroll
        for (int mr = 0; mr < 8; ++mr)
#pragma unroll
            for (int fc = 0; fc < 3; ++fc)
#pragma unroll
                for (int ks = 0; ks < 2; ++ks)
                    acc[mr][fc] = __builtin_amdgcn_mfma_f32_16x16x32_bf16(
                        a_[mr][ks], b_[fc][ks], acc[mr][fc], 0, 0, 0);
        __builtin_amdgcn_s_setprio(0);

        asm volatile("s_waitcnt vmcnt(0)" ::: "memory");
        __builtin_amdgcn_s_barrier();        // single barrier per K-tile
#undef RD_A
#undef RD_B
    }

    const float qscale = 0.18033688011f;   // 1/8 * log2(e)
#pragma unroll
    for (int mr = 0; mr < 8; ++mr) {
#pragma unroll
        for (int nr = 0; nr < 3; ++nr) {
            const int m = m0 + wm * 128 + mr * 16 + lg * 4;
            const int nglob = n0 + wn * 48 + nr * 16 + l15;
            const int zq = nglob >> 10;
            const int nz = nglob & 1023;
            const float* bias = (zq == 0) ? bq : (zq == 1) ? bk : bv;
            const float bb_ = bias[nz];
            if (zq == 0) {
#pragma unroll
                for (int rr = 0; rr < 4; ++rr)
                    qbuf[(size_t)(m + rr) * Dm + nz] =
                        bf_round((acc[mr][nr][rr] + bb_) * qscale);
            } else if (zq == 1) {
#pragma unroll
                for (int rr = 0; rr < 4; ++rr)
                    kbuf[(size_t)(m + rr) * Dm + nz] = bf_round(acc[mr][nr][rr] + bb_);
            } else {
                const int bbv = m >> 11, s = m & (SQ - 1);
                const int hh = nz >> 6, d = nz & 63;
                unsigned short p4[4] __attribute__((aligned(8)));
#pragma unroll
                for (int rr = 0; rr < 4; ++rr) p4[rr] = bf_round(acc[mr][nr][rr] + bb_);
                *(uint2*)&vtbuf[(((size_t)bbv * NH + hh) * 64 + d) * SQ + s] =
                    *(const uint2*)p4;
            }
        }
    }
#undef STAGE_TILE
}

// ====================================================================
// output projection, single-phase 128x128, ONE barrier per K-tile
// ====================================================================
__global__ __launch_bounds__(256) void gemm_out8(const unsigned short* __restrict__ A,
                                                 const unsigned short* __restrict__ Bt,
                                                 const float* __restrict__ bias,
                                                 float* __restrict__ Cf) {
    __shared__ unsigned short Alds[2][128 * 64];
    __shared__ unsigned short Blds[2][128 * 64];

    const int tid = threadIdx.x;
    const int lane = tid & 63, wid = tid >> 6;
    const int l15 = lane & 15, lg = lane >> 4;
    const int wr = (wid >> 1) * 64, wc = (wid & 1) * 64;
    const int m0 = blockIdx.y * 128, n0 = blockIdx.x * 128;

    const int srow = (tid >> 3) & 31;
    const int scol = ((tid & 7) ^ (srow & 7)) * 8;

    const unsigned short* Abase = A + (size_t)m0 * Dm;
    const unsigned short* Bbase = Bt + (size_t)n0 * Dm;

#define STAGE_TILE(t)                                                              \
    do {                                                                           \
        const unsigned short* As_ = Abase + (t) * 64;                              \
        const unsigned short* Bs_ = Bbase + (t) * 64;                              \
        unsigned short* Ad_ = Alds[(t) & 1];                                       \
        unsigned short* Bd_ = Blds[(t) & 1];                                       \
        _Pragma("unroll")                                                          \
        for (int i_ = 0; i_ < 4; ++i_) {                                           \
            gload_lds16(&As_[(size_t)(i_ * 32 + srow) * Dm + scol],                \
                        &Ad_[i_ * 2048 + wid * 512]);                              \
            gload_lds16(&Bs_[(size_t)(i_ * 32 + srow) * Dm + scol],                \
                        &Bd_[i_ * 2048 + wid * 512]);                              \
        }                                                                          \
    } while (0)

    f32x4 acc[4][4];
#pragma unroll
    for (int r = 0; r < 4; ++r)
#pragma unroll
        for (int c = 0; c < 4; ++c) acc[r][c] = (f32x4){0.f, 0.f, 0.f, 0.f};

    STAGE_TILE(0);
    asm volatile("s_waitcnt vmcnt(0)" ::: "memory");
    __builtin_amdgcn_s_barrier();

    for (int t = 0; t < Dm / 64; ++t) {
        unsigned short* Ad = Alds[t & 1];
        unsigned short* Bd = Blds[t & 1];
        if (t + 1 < Dm / 64) STAGE_TILE(t + 1);

        bf16x8 a_[4][2], b_[4][2];

#define RD_A(fr, ks) \
    (*(const bf16x8*)&Ad[(wr + (fr) * 16 + l15) * 64 + ((((ks) * 4 + lg) ^ (l15 & 7)) * 8)])
#define RD_B(fc, ks) \
    (*(const bf16x8*)&Bd[(wc + (fc) * 16 + l15) * 64 + ((((ks) * 4 + lg) ^ (l15 & 7)) * 8)])

#pragma unroll
        for (int fr = 0; fr < 4; ++fr) {
            a_[fr][0] = RD_A(fr, 0); a_[fr][1] = RD_A(fr, 1);
        }
#pragma unroll
        for (int fc = 0; fc < 4; ++fc) {
            b_[fc][0] = RD_B(fc, 0); b_[fc][1] = RD_B(fc, 1);
        }
        __builtin_amdgcn_s_setprio(1);
#pragma unroll
        for (int fr = 0; fr < 4; ++fr)
#pragma unroll
            for (int fc = 0; fc < 4; ++fc)
#pragma unroll
                for (int ks = 0; ks < 2; ++ks)
                    acc[fr][fc] = __builtin_amdgcn_mfma_f32_16x16x32_bf16(
                        a_[fr][ks], b_[fc][ks], acc[fr][fc], 0, 0, 0);
        __builtin_amdgcn_s_setprio(0);

        asm volatile("s_waitcnt vmcnt(0)" ::: "memory");
        __builtin_amdgcn_s_barrier();        // single barrier per K-tile
#undef RD_A
#undef RD_B
    }

#pragma unroll
    for (int r = 0; r < 4; ++r) {
#pragma unroll
        for (int c = 0; c < 4; ++c) {
            const int mBase = m0 + wr + r * 16 + lg * 4;
            const int n = n0 + wc + c * 16 + l15;
            const float bv_ = bias[n];
#pragma unroll
            for (int rr = 0; rr < 4; ++rr)
                Cf[(size_t)(mBase + rr) * Dm + n] = acc[r][c][rr] + bv_;
        }
    }
#undef STAGE_TILE
}

// ---------------- flash attention: round-14 verified body (KVBLK=64, dbuf) ----
__global__ __launch_bounds__(256) void attn_bf16(const unsigned short* q,
                                                 const unsigned short* __restrict__ k,
                                                 const unsigned short* __restrict__ vt,
                                                 unsigned short* ao) {
    __shared__ unsigned short KVs[2][2][64 * 64];  // [buf][0=K,1=Vt], XOR-swizzled
    const int qt = blockIdx.x, h = blockIdx.y, b = blockIdx.z;
    const int tid = threadIdx.x, lane = tid & 63, wid = tid >> 6;
    const int l31 = lane & 31, hi = lane >> 5;

    const size_t qrow0 = (size_t)b * SQ + qt * 128;
    const unsigned short* qp = q + (qrow0 + wid * 32 + l31) * Dm + h * 64;
    bf16x8 qf[4];
#pragma unroll
    for (int ks = 0; ks < 4; ++ks)
        qf[ks] = *(const bf16x8*)&qp[ks * 16 + hi * 8];

    const unsigned short* kb = k + (size_t)b * SQ * Dm + h * 64;
    const unsigned short* vb = vt + ((size_t)b * NH + h) * 64 * SQ;

    const int row0 = tid >> 3;
    const int s8 = (tid & 7) * 8;
    const int sw8 = (((tid & 7) ^ (row0 & 7))) * 8;
    const int koff0 = row0 * 64 + sw8;
    const int koff1 = (row0 + 32) * 64 + sw8;

    {   // prologue: stage tile 0 into buf 0
        uint4 k0v = *(const uint4*)&kb[(size_t)row0 * Dm + s8];
        uint4 k1v = *(const uint4*)&kb[(size_t)(row0 + 32) * Dm + s8];
        uint4 v0v = *(const uint4*)&vb[(size_t)row0 * SQ + s8];
        uint4 v1v = *(const uint4*)&vb[(size_t)(row0 + 32) * SQ + s8];
        *(uint4*)&KVs[0][0][koff0] = k0v; *(uint4*)&KVs[0][0][koff1] = k1v;
        *(uint4*)&KVs[0][1][koff0] = v0v; *(uint4*)&KVs[0][1][koff1] = v1v;
    }
    __syncthreads();

    float psum = 0.f;
    f32x16 c0, c1;
#pragma unroll
    for (int i = 0; i < 16; ++i) { c0[i] = 0.f; c1[i] = 0.f; }

    int cur = 0;
    for (int t0 = 0; t0 < SQ; t0 += 64) {
        const bool hasNext = (t0 + 64) < SQ;
        uint4 kr0, kr1, vr0, vr1;
        if (hasNext) {   // T14: issue next-tile loads early
            const unsigned short* kn = kb + (size_t)(t0 + 64) * Dm;
            const unsigned short* vn = vb + (t0 + 64);
            kr0 = *(const uint4*)&kn[(size_t)row0 * Dm + s8];
            kr1 = *(const uint4*)&kn[(size_t)(row0 + 32) * Dm + s8];
            vr0 = *(const uint4*)&vn[(size_t)row0 * SQ + s8];
            vr1 = *(const uint4*)&vn[(size_t)(row0 + 32) * SQ + s8];
        }
        const unsigned short* Kc = KVs[cur][0];
        const unsigned short* Vc = KVs[cur][1];

#pragma unroll
        for (int kblk = 0; kblk < 2; ++kblk) {
            f32x16 p;
#pragma unroll
            for (int i = 0; i < 16; ++i) p[i] = 0.f;
            __builtin_amdgcn_s_setprio(1);
#pragma unroll
            for (int ks = 0; ks < 4; ++ks) {
                int row = kblk * 32 + l31;
                int slot = ((ks * 2 + hi) ^ (l31 & 7)) * 8;
                bf16x8 kf = *(const bf16x8*)&Kc[row * 64 + slot];
                p = __builtin_amdgcn_mfma_f32_32x32x16_bf16(kf, qf[ks], p, 0, 0, 0);
            }
            __builtin_amdgcn_s_setprio(0);

            float e[16];
#pragma unroll
            for (int i = 0; i < 16; ++i) { e[i] = exp2_fast(p[i]); psum += e[i]; }
            unsigned w0 = cvt_pk(e[0], e[1]),   w1 = cvt_pk(e[2], e[3]);
            unsigned w2 = cvt_pk(e[4], e[5]),   w3 = cvt_pk(e[6], e[7]);
            unsigned w4 = cvt_pk(e[8], e[9]),   w5 = cvt_pk(e[10], e[11]);
            unsigned w6 = cvt_pk(e[12], e[13]), w7 = cvt_pk(e[14], e[15]);
            permlane_swap(w0, w2); permlane_swap(w1, w3);
            permlane_swap(w4, w6); permlane_swap(w5, w7);
            bf16x8 pf0 = make_frag(w0, w1, w2, w3);
            bf16x8 pf1 = make_frag(w4, w5, w6, w7);

            int s0 = ((kblk * 4 + hi) ^ (l31 & 7)) * 8;
            int s1 = ((kblk * 4 + 2 + hi) ^ (l31 & 7)) * 8;
            bf16x8 va0 = *(const bf16x8*)&Vc[l31 * 64 + s0];
            bf16x8 va1 = *(const bf16x8*)&Vc[l31 * 64 + s1];
            bf16x8 vb0 = *(const bf16x8*)&Vc[(32 + l31) * 64 + s0];
            bf16x8 vb1 = *(const bf16x8*)&Vc[(32 + l31) * 64 + s1];
            __builtin_amdgcn_s_setprio(1);
            c0 = __builtin_amdgcn_mfma_f32_32x32x16_bf16(va0, pf0, c0, 0, 0, 0);
            c0 = __builtin_amdgcn_mfma_f32_32x32x16_bf16(va1, pf1, c0, 0, 0, 0);
            c1 = __builtin_amdgcn_mfma_f32_32x32x16_bf16(vb0, pf0, c1, 0, 0, 0);
            c1 = __builtin_amdgcn_mfma_f32_32x32x16_bf16(vb1, pf1, c1, 0, 0, 0);
            __builtin_amdgcn_s_setprio(0);
        }

        if (hasNext) {
            unsigned short* Kn = KVs[cur ^ 1][0];
            unsigned short* Vn = KVs[cur ^ 1][1];
            *(uint4*)&Kn[koff0] = kr0; *(uint4*)&Kn[koff1] = kr1;
            *(uint4*)&Vn[koff0] = vr0; *(uint4*)&Vn[koff1] = vr1;
        }
        __syncthreads();
        cur ^= 1;
    }

    float s = psum + __shfl_xor(psum, 32, 64);
    float inv = 1.f / s;

    unsigned short* Olds = (unsigned short*)KVs;
    {
        const int orow = wid * 32 + l31;
#pragma unroll
        for (int db = 0; db < 2; ++db) {
#pragma unroll
            for (int i = 0; i < 8; ++i) {
                float lo  = (db ? c1[2 * i] : c0[2 * i]) * inv;
                float hi_ = (db ? c1[2 * i + 1] : c0[2 * i + 1]) * inv;
                unsigned w = cvt_pk(lo, hi_);
                int d7 = hi * 4 + (i & 1) * 2;
                int slot = db * 4 + (i >> 1);
                int sw = slot ^ (l31 & 7);
                *(unsigned*)&Olds[orow * 64 + sw * 8 + d7] = w;
            }
        }
    }
    __syncthreads();
    {
        int r = tid >> 1, half = tid & 1;
        unsigned short* dst = ao + (qrow0 + r) * Dm + h * 64 + half * 32;
#pragma unroll
        for (int j = 0; j < 4; ++j) {
            int slot = half * 4 + j;
            int sw = slot ^ (r & 7);
            *(uint4*)&dst[j * 8] = *(const uint4*)&Olds[r * 64 + sw * 8];
        }
    }
}

extern "C" void kernel_launch(void* const* d_in, const int* in_sizes, int n_in,
                              void* d_out, int out_size, void* d_ws, size_t ws_size,
                              hipStream_t stream) {
    const float* x  = (const float*)d_in[0];
    const float* Wq = (const float*)d_in[1];
    const float* bq = (const float*)d_in[2];
    const float* Wk = (const float*)d_in[3];
    const float* bk = (const float*)d_in[4];
    const float* Wv = (const float*)d_in[5];
    const float* bv = (const float*)d_in[6];
    const float* Wo = (const float*)d_in[7];
    const float* bo = (const float*)d_in[8];
    float* out = (float*)d_out;

    const size_t M = (size_t)NB * SQ;           // 4096
    const size_t elems = M * Dm;                // 4M
    unsigned short* xb    = (unsigned short*)d_ws;
    unsigned short* wtb   = xb + elems;
    unsigned short* qbuf  = wtb + 4ull * Dm * Dm;
    unsigned short* kbuf  = qbuf + elems;
    unsigned short* vtbuf = kbuf + elems;

    dim3 blk(256);
    hipLaunchKernelGGL(prologue, dim3(16, 16, 5), blk, 0, stream,
                       x, Wq, Wk, Wv, Wo, xb, wtb);

    hipLaunchKernelGGL(gemm_qkv192, dim3(256), dim3(512), 0, stream,
                       xb, wtb, bq, bk, bv, qbuf, kbuf, vtbuf);

    hipLaunchKernelGGL(attn_bf16, dim3(SQ / 128, NH, NB), blk, 0, stream,
                       qbuf, kbuf, vtbuf, qbuf);

    hipLaunchKernelGGL(gemm_out8, dim3(Dm / 128, M / 128), blk, 0, stream,
                       qbuf, wtb + 3ull * Dm * Dm, bo, out);
}

// Round 21
// 108.818 us; speedup vs baseline: 1.1283x; 1.0172x over previous
//
#include <hip/hip_runtime.h>
#include <math.h>

constexpr int Dm  = 1024;
constexpr int NH  = 16;
constexpr int SQ  = 2048;
constexpr int NB  = 2;

typedef float f32x4 __attribute__((ext_vector_type(4)));
typedef float f32x16 __attribute__((ext_vector_type(16)));
typedef short bf16x8 __attribute__((ext_vector_type(8)));
typedef __attribute__((address_space(3))) unsigned int lds_u32;
typedef __attribute__((address_space(1))) const unsigned int glb_u32;

__device__ __forceinline__ void gload_lds16(const void* g, void* l) {
    __builtin_amdgcn_global_load_lds((glb_u32*)(uintptr_t)g, (lds_u32*)(uintptr_t)l, 16, 0, 0);
}

__device__ __forceinline__ unsigned short bf_round(float x) {
    unsigned u = __float_as_uint(x);
    unsigned r = u + 0x7fffu + ((u >> 16) & 1u);
    return (unsigned short)(r >> 16);
}

__device__ __forceinline__ float exp2_fast(float x) {
    float r;
    asm("v_exp_f32 %0, %1" : "=v"(r) : "v"(x));
    return r;
}

__device__ __forceinline__ unsigned cvt_pk(float lo, float hi_) {
    unsigned r;
    asm("v_cvt_pk_bf16_f32 %0, %1, %2" : "=v"(r) : "v"(lo), "v"(hi_));
    return r;
}

__device__ __forceinline__ void permlane_swap(unsigned& a, unsigned& b) {
    asm volatile("v_permlane32_swap_b32 %0, %1" : "+v"(a), "+v"(b));
}

__device__ __forceinline__ bf16x8 make_frag(unsigned a, unsigned b, unsigned c, unsigned d) {
    union { unsigned u[4]; bf16x8 v; } uu;
    uu.u[0] = a; uu.u[1] = b; uu.u[2] = c; uu.u[3] = d;
    return uu.v;
}

// ---------------- prologue: W transpose (z=0..3) + x fp32->bf16 (z=4) ----------------
__global__ __launch_bounds__(256) void prologue(const float* __restrict__ x,
                                                const float* __restrict__ Wq,
                                                const float* __restrict__ Wk,
                                                const float* __restrict__ Wv,
                                                const float* __restrict__ Wo,
                                                unsigned short* __restrict__ xb,
                                                unsigned short* __restrict__ wt) {
    const int z = blockIdx.z;
    const int tid = threadIdx.x;
    if (z == 4) {
        size_t base = ((size_t)blockIdx.y * 16 + blockIdx.x) * 16384;
#pragma unroll
        for (int it = 0; it < 8; ++it) {
            size_t i = base + (size_t)it * 2048 + (size_t)tid * 8;
            float4 a = *(const float4*)&x[i];
            float4 b = *(const float4*)&x[i + 4];
            unsigned short o8[8] __attribute__((aligned(16)));
            o8[0] = bf_round(a.x); o8[1] = bf_round(a.y); o8[2] = bf_round(a.z); o8[3] = bf_round(a.w);
            o8[4] = bf_round(b.x); o8[5] = bf_round(b.y); o8[6] = bf_round(b.z); o8[7] = bf_round(b.w);
            *(uint4*)&xb[i] = *(const uint4*)o8;
        }
        return;
    }
    const float* W = (z == 0) ? Wq : (z == 1) ? Wk : (z == 2) ? Wv : Wo;
    unsigned short* dst = wt + (size_t)z * Dm * Dm;
    __shared__ float T[64][65];
    const int k0 = blockIdx.x * 64, n0 = blockIdx.y * 64;
#pragma unroll
    for (int i = 0; i < 4; ++i) {
        int s = tid + i * 256;
        int kk = s >> 4, c = (s & 15) * 4;
        *(float4*)&T[kk][c] = *(const float4*)&W[(size_t)(k0 + kk) * Dm + n0 + c];
    }
    __syncthreads();
#pragma unroll
    for (int i = 0; i < 2; ++i) {
        int s = tid + i * 256;
        int n = s >> 3, c8 = (s & 7) * 8;
        unsigned short o8[8] __attribute__((aligned(16)));
#pragma unroll
        for (int j = 0; j < 8; ++j) o8[j] = bf_round(T[c8 + j][n]);
        *(uint4*)&dst[(size_t)(n0 + n) * Dm + k0 + c8] = *(const uint4*)o8;
    }
}

// ====================================================================
// single-phase 256x192 QKV GEMM, ONE barrier per K-tile (round-20 verified)
// ====================================================================
__global__ __launch_bounds__(512) void gemm_qkv192(
    const unsigned short* __restrict__ xb,
    const unsigned short* __restrict__ wt,
    const float* __restrict__ bq, const float* __restrict__ bk,
    const float* __restrict__ bv,
    unsigned short* __restrict__ qbuf, unsigned short* __restrict__ kbuf,
    unsigned short* __restrict__ vtbuf)
{
    __shared__ unsigned short Alds[2][256 * 64];
    __shared__ unsigned short Blds[2][192 * 64];

    const int tid = threadIdx.x;
    const int lane = tid & 63, wid = tid >> 6;
    const int wm = wid >> 2, wn = wid & 3;
    const int l15 = lane & 15, lg = lane >> 4;

    const int bid = blockIdx.x;
    const int swz = (bid & 7) * 32 + (bid >> 3);
    const int bx = swz & 15, by = swz >> 4;
    const int m0 = by * 256, n0 = bx * 192;

    const int srow = wid * 8 + (lane >> 3);
    const int scol = ((lane & 7) ^ ((lane >> 3) & 7)) * 8;

    const unsigned short* Abase = xb + (size_t)m0 * Dm;
    const unsigned short* Bbase = wt + (size_t)n0 * Dm;

#define STAGE_TILE(t)                                                              \
    do {                                                                           \
        const unsigned short* As_ = Abase + (t) * 64;                              \
        const unsigned short* Bs_ = Bbase + (t) * 64;                              \
        unsigned short* Ad_ = Alds[(t) & 1];                                       \
        unsigned short* Bd_ = Blds[(t) & 1];                                       \
        _Pragma("unroll")                                                          \
        for (int i_ = 0; i_ < 4; ++i_)                                             \
            gload_lds16(&As_[(size_t)(i_ * 64 + srow) * Dm + scol],                \
                        &Ad_[i_ * 4096 + wid * 512]);                              \
        _Pragma("unroll")                                                          \
        for (int i_ = 0; i_ < 3; ++i_)                                             \
            gload_lds16(&Bs_[(size_t)(i_ * 64 + srow) * Dm + scol],                \
                        &Bd_[i_ * 4096 + wid * 512]);                              \
    } while (0)

    f32x4 acc[8][3];
#pragma unroll
    for (int mr = 0; mr < 8; ++mr)
#pragma unroll
        for (int nr = 0; nr < 3; ++nr) acc[mr][nr] = (f32x4){0.f, 0.f, 0.f, 0.f};

    STAGE_TILE(0);
    asm volatile("s_waitcnt vmcnt(0)" ::: "memory");
    __builtin_amdgcn_s_barrier();

    for (int t = 0; t < Dm / 64; ++t) {
        unsigned short* Ad = Alds[t & 1];
        unsigned short* Bd = Blds[t & 1];
        if (t + 1 < Dm / 64) STAGE_TILE(t + 1);

        bf16x8 a_[8][2], b_[3][2];

#define RD_A(qm, fr, ks) \
    (*(const bf16x8*)&Ad[(wm * 128 + (qm) * 64 + (fr) * 16 + l15) * 64 + \
                         ((((ks) * 4 + lg) ^ (l15 & 7)) * 8)])
#define RD_B(fc, ks) \
    (*(const bf16x8*)&Bd[(wn * 48 + (fc) * 16 + l15) * 64 + \
                         ((((ks) * 4 + lg) ^ (l15 & 7)) * 8)])

#pragma unroll
        for (int fr = 0; fr < 4; ++fr) {
            a_[fr][0] = RD_A(0, fr, 0);     a_[fr][1] = RD_A(0, fr, 1);
            a_[4 + fr][0] = RD_A(1, fr, 0); a_[4 + fr][1] = RD_A(1, fr, 1);
        }
#pragma unroll
        for (int fc = 0; fc < 3; ++fc) {
            b_[fc][0] = RD_B(fc, 0); b_[fc][1] = RD_B(fc, 1);
        }
        __builtin_amdgcn_s_setprio(1);
#pragma unroll
        for (int mr = 0; mr < 8; ++mr)
#pragma unroll
            for (int fc = 0; fc < 3; ++fc)
#pragma unroll
                for (int ks = 0; ks < 2; ++ks)
                    acc[mr][fc] = __builtin_amdgcn_mfma_f32_16x16x32_bf16(
                        a_[mr][ks], b_[fc][ks], acc[mr][fc], 0, 0, 0);
        __builtin_amdgcn_s_setprio(0);

        asm volatile("s_waitcnt vmcnt(0)" ::: "memory");
        __builtin_amdgcn_s_barrier();        // single barrier per K-tile
#undef RD_A
#undef RD_B
    }

    const float qscale = 0.18033688011f;   // 1/8 * log2(e)
#pragma unroll
    for (int mr = 0; mr < 8; ++mr) {
#pragma unroll
        for (int nr = 0; nr < 3; ++nr) {
            const int m = m0 + wm * 128 + mr * 16 + lg * 4;
            const int nglob = n0 + wn * 48 + nr * 16 + l15;
            const int zq = nglob >> 10;
            const int nz = nglob & 1023;
            const float* bias = (zq == 0) ? bq : (zq == 1) ? bk : bv;
            const float bb_ = bias[nz];
            if (zq == 0) {
#pragma unroll
                for (int rr = 0; rr < 4; ++rr)
                    qbuf[(size_t)(m + rr) * Dm + nz] =
                        bf_round((acc[mr][nr][rr] + bb_) * qscale);
            } else if (zq == 1) {
#pragma unroll
                for (int rr = 0; rr < 4; ++rr)
                    kbuf[(size_t)(m + rr) * Dm + nz] = bf_round(acc[mr][nr][rr] + bb_);
            } else {
                const int bbv = m >> 11, s = m & (SQ - 1);
                const int hh = nz >> 6, d = nz & 63;
                unsigned short p4[4] __attribute__((aligned(8)));
#pragma unroll
                for (int rr = 0; rr < 4; ++rr) p4[rr] = bf_round(acc[mr][nr][rr] + bb_);
                *(uint2*)&vtbuf[(((size_t)bbv * NH + hh) * 64 + d) * SQ + s] =
                    *(const uint2*)p4;
            }
        }
    }
#undef STAGE_TILE
}

// ====================================================================
// output projection, single-phase 128x128, ONE barrier per K-tile (round-20)
// ====================================================================
__global__ __launch_bounds__(256) void gemm_out8(const unsigned short* __restrict__ A,
                                                 const unsigned short* __restrict__ Bt,
                                                 const float* __restrict__ bias,
                                                 float* __restrict__ Cf) {
    __shared__ unsigned short Alds[2][128 * 64];
    __shared__ unsigned short Blds[2][128 * 64];

    const int tid = threadIdx.x;
    const int lane = tid & 63, wid = tid >> 6;
    const int l15 = lane & 15, lg = lane >> 4;
    const int wr = (wid >> 1) * 64, wc = (wid & 1) * 64;
    const int m0 = blockIdx.y * 128, n0 = blockIdx.x * 128;

    const int srow = (tid >> 3) & 31;
    const int scol = ((tid & 7) ^ (srow & 7)) * 8;

    const unsigned short* Abase = A + (size_t)m0 * Dm;
    const unsigned short* Bbase = Bt + (size_t)n0 * Dm;

#define STAGE_TILE(t)                                                              \
    do {                                                                           \
        const unsigned short* As_ = Abase + (t) * 64;                              \
        const unsigned short* Bs_ = Bbase + (t) * 64;                              \
        unsigned short* Ad_ = Alds[(t) & 1];                                       \
        unsigned short* Bd_ = Blds[(t) & 1];                                       \
        _Pragma("unroll")                                                          \
        for (int i_ = 0; i_ < 4; ++i_) {                                           \
            gload_lds16(&As_[(size_t)(i_ * 32 + srow) * Dm + scol],                \
                        &Ad_[i_ * 2048 + wid * 512]);                              \
            gload_lds16(&Bs_[(size_t)(i_ * 32 + srow) * Dm + scol],                \
                        &Bd_[i_ * 2048 + wid * 512]);                              \
        }                                                                          \
    } while (0)

    f32x4 acc[4][4];
#pragma unroll
    for (int r = 0; r < 4; ++r)
#pragma unroll
        for (int c = 0; c < 4; ++c) acc[r][c] = (f32x4){0.f, 0.f, 0.f, 0.f};

    STAGE_TILE(0);
    asm volatile("s_waitcnt vmcnt(0)" ::: "memory");
    __builtin_amdgcn_s_barrier();

    for (int t = 0; t < Dm / 64; ++t) {
        unsigned short* Ad = Alds[t & 1];
        unsigned short* Bd = Blds[t & 1];
        if (t + 1 < Dm / 64) STAGE_TILE(t + 1);

        bf16x8 a_[4][2], b_[4][2];

#define RD_A(fr, ks) \
    (*(const bf16x8*)&Ad[(wr + (fr) * 16 + l15) * 64 + ((((ks) * 4 + lg) ^ (l15 & 7)) * 8)])
#define RD_B(fc, ks) \
    (*(const bf16x8*)&Bd[(wc + (fc) * 16 + l15) * 64 + ((((ks) * 4 + lg) ^ (l15 & 7)) * 8)])

#pragma unroll
        for (int fr = 0; fr < 4; ++fr) {
            a_[fr][0] = RD_A(fr, 0); a_[fr][1] = RD_A(fr, 1);
        }
#pragma unroll
        for (int fc = 0; fc < 4; ++fc) {
            b_[fc][0] = RD_B(fc, 0); b_[fc][1] = RD_B(fc, 1);
        }
        __builtin_amdgcn_s_setprio(1);
#pragma unroll
        for (int fr = 0; fr < 4; ++fr)
#pragma unroll
            for (int fc = 0; fc < 4; ++fc)
#pragma unroll
                for (int ks = 0; ks < 2; ++ks)
                    acc[fr][fc] = __builtin_amdgcn_mfma_f32_16x16x32_bf16(
                        a_[fr][ks], b_[fc][ks], acc[fr][fc], 0, 0, 0);
        __builtin_amdgcn_s_setprio(0);

        asm volatile("s_waitcnt vmcnt(0)" ::: "memory");
        __builtin_amdgcn_s_barrier();        // single barrier per K-tile
#undef RD_A
#undef RD_B
    }

#pragma unroll
    for (int r = 0; r < 4; ++r) {
#pragma unroll
        for (int c = 0; c < 4; ++c) {
            const int mBase = m0 + wr + r * 16 + lg * 4;
            const int n = n0 + wc + c * 16 + l15;
            const float bv_ = bias[n];
#pragma unroll
            for (int rr = 0; rr < 4; ++rr)
                Cf[(size_t)(mBase + rr) * Dm + n] = acc[r][c][rr] + bv_;
        }
    }
#undef STAGE_TILE
}

// ---------------- flash attention: round-14 compute body, gload_lds staging ----
// Staging now uses global_load_lds with pre-swizzled global source (rule #21):
// lane (row r, phys slot p) fetches global chunk p^(r&7) into linear dest ->
// byte-identical LDS layout to the verified reg-staged version; read side
// unchanged. Removes 4 ds_write_b128/wave/tile and the prefetch registers.
__global__ __launch_bounds__(256) void attn_bf16(const unsigned short* q,
                                                 const unsigned short* __restrict__ k,
                                                 const unsigned short* __restrict__ vt,
                                                 unsigned short* ao) {
    __shared__ unsigned short KVs[2][2][64 * 64];  // [buf][0=K,1=Vt], XOR-swizzled
    const int qt = blockIdx.x, h = blockIdx.y, b = blockIdx.z;
    const int tid = threadIdx.x, lane = tid & 63, wid = tid >> 6;
    const int l31 = lane & 31, hi = lane >> 5;

    const size_t qrow0 = (size_t)b * SQ + qt * 128;
    const unsigned short* qp = q + (qrow0 + wid * 32 + l31) * Dm + h * 64;
    bf16x8 qf[4];
#pragma unroll
    for (int ks = 0; ks < 4; ++ks)
        qf[ks] = *(const bf16x8*)&qp[ks * 16 + hi * 8];

    const unsigned short* kb = k + (size_t)b * SQ * Dm + h * 64;
    const unsigned short* vb = vt + ((size_t)b * NH + h) * 64 * SQ;

    // gload staging geometry: wave w covers rows w*8 + (lane>>3) (+32 per line);
    // global chunk = (lane&7) ^ ((lane>>3)&7); LDS dest linear (base + lane*16B).
    const int wrow = wid * 8 + (lane >> 3);
    const int gcol = ((lane & 7) ^ ((lane >> 3) & 7)) * 8;

#define STAGE_KV(buf, T0)                                                          \
    do {                                                                           \
        unsigned short* Kd_ = &KVs[buf][0][0];                                     \
        unsigned short* Vd_ = &KVs[buf][1][0];                                     \
        _Pragma("unroll")                                                          \
        for (int i_ = 0; i_ < 2; ++i_) {                                           \
            gload_lds16(&kb[(size_t)((T0) + wrow + 32 * i_) * Dm + gcol],          \
                        &Kd_[i_ * 2048 + wid * 512]);                              \
            gload_lds16(&vb[(size_t)(wrow + 32 * i_) * SQ + (T0) + gcol],          \
                        &Vd_[i_ * 2048 + wid * 512]);                              \
        }                                                                          \
    } while (0)

    STAGE_KV(0, 0);
    asm volatile("s_waitcnt vmcnt(0)" ::: "memory");
    __builtin_amdgcn_s_barrier();

    float psum = 0.f;
    f32x16 c0, c1;
#pragma unroll
    for (int i = 0; i < 16; ++i) { c0[i] = 0.f; c1[i] = 0.f; }

    int cur = 0;
    for (int t0 = 0; t0 < SQ; t0 += 64) {
        if (t0 + 64 < SQ) STAGE_KV(cur ^ 1, t0 + 64);   // issue early; drains at tile end
        const unsigned short* Kc = KVs[cur][0];
        const unsigned short* Vc = KVs[cur][1];

#pragma unroll
        for (int kblk = 0; kblk < 2; ++kblk) {
            f32x16 p;
#pragma unroll
            for (int i = 0; i < 16; ++i) p[i] = 0.f;
            __builtin_amdgcn_s_setprio(1);
#pragma unroll
            for (int ks = 0; ks < 4; ++ks) {
                int row = kblk * 32 + l31;
                int slot = ((ks * 2 + hi) ^ (l31 & 7)) * 8;
                bf16x8 kf = *(const bf16x8*)&Kc[row * 64 + slot];
                p = __builtin_amdgcn_mfma_f32_32x32x16_bf16(kf, qf[ks], p, 0, 0, 0);
            }
            __builtin_amdgcn_s_setprio(0);

            float e[16];
#pragma unroll
            for (int i = 0; i < 16; ++i) { e[i] = exp2_fast(p[i]); psum += e[i]; }
            unsigned w0 = cvt_pk(e[0], e[1]),   w1 = cvt_pk(e[2], e[3]);
            unsigned w2 = cvt_pk(e[4], e[5]),   w3 = cvt_pk(e[6], e[7]);
            unsigned w4 = cvt_pk(e[8], e[9]),   w5 = cvt_pk(e[10], e[11]);
            unsigned w6 = cvt_pk(e[12], e[13]), w7 = cvt_pk(e[14], e[15]);
            permlane_swap(w0, w2); permlane_swap(w1, w3);
            permlane_swap(w4, w6); permlane_swap(w5, w7);
            bf16x8 pf0 = make_frag(w0, w1, w2, w3);
            bf16x8 pf1 = make_frag(w4, w5, w6, w7);

            int s0 = ((kblk * 4 + hi) ^ (l31 & 7)) * 8;
            int s1 = ((kblk * 4 + 2 + hi) ^ (l31 & 7)) * 8;
            bf16x8 va0 = *(const bf16x8*)&Vc[l31 * 64 + s0];
            bf16x8 va1 = *(const bf16x8*)&Vc[l31 * 64 + s1];
            bf16x8 vb0 = *(const bf16x8*)&Vc[(32 + l31) * 64 + s0];
            bf16x8 vb1 = *(const bf16x8*)&Vc[(32 + l31) * 64 + s1];
            __builtin_amdgcn_s_setprio(1);
            c0 = __builtin_amdgcn_mfma_f32_32x32x16_bf16(va0, pf0, c0, 0, 0, 0);
            c0 = __builtin_amdgcn_mfma_f32_32x32x16_bf16(va1, pf1, c0, 0, 0, 0);
            c1 = __builtin_amdgcn_mfma_f32_32x32x16_bf16(vb0, pf0, c1, 0, 0, 0);
            c1 = __builtin_amdgcn_mfma_f32_32x32x16_bf16(vb1, pf1, c1, 0, 0, 0);
            __builtin_amdgcn_s_setprio(0);
        }

        asm volatile("s_waitcnt vmcnt(0)" ::: "memory");
        __syncthreads();   // single barrier per tile: next buf staged, cur retired
        cur ^= 1;
    }

    float s = psum + __shfl_xor(psum, 32, 64);
    float inv = 1.f / s;

    unsigned short* Olds = (unsigned short*)KVs;
    {
        const int orow = wid * 32 + l31;
#pragma unroll
        for (int db = 0; db < 2; ++db) {
#pragma unroll
            for (int i = 0; i < 8; ++i) {
                float lo  = (db ? c1[2 * i] : c0[2 * i]) * inv;
                float hi_ = (db ? c1[2 * i + 1] : c0[2 * i + 1]) * inv;
                unsigned w = cvt_pk(lo, hi_);
                int d7 = hi * 4 + (i & 1) * 2;
                int slot = db * 4 + (i >> 1);
                int sw = slot ^ (l31 & 7);
                *(unsigned*)&Olds[orow * 64 + sw * 8 + d7] = w;
            }
        }
    }
    __syncthreads();
    {
        int r = tid >> 1, half = tid & 1;
        unsigned short* dst = ao + (qrow0 + r) * Dm + h * 64 + half * 32;
#pragma unroll
        for (int j = 0; j < 4; ++j) {
            int slot = half * 4 + j;
            int sw = slot ^ (r & 7);
            *(uint4*)&dst[j * 8] = *(const uint4*)&Olds[r * 64 + sw * 8];
        }
    }
#undef STAGE_KV
}

extern "C" void kernel_launch(void* const* d_in, const int* in_sizes, int n_in,
                              void* d_out, int out_size, void* d_ws, size_t ws_size,
                              hipStream_t stream) {
    const float* x  = (const float*)d_in[0];
    const float* Wq = (const float*)d_in[1];
    const float* bq = (const float*)d_in[2];
    const float* Wk = (const float*)d_in[3];
    const float* bk = (const float*)d_in[4];
    const float* Wv = (const float*)d_in[5];
    const float* bv = (const float*)d_in[6];
    const float* Wo = (const float*)d_in[7];
    const float* bo = (const float*)d_in[8];
    float* out = (float*)d_out;

    const size_t M = (size_t)NB * SQ;           // 4096
    const size_t elems = M * Dm;                // 4M
    unsigned short* xb    = (unsigned short*)d_ws;
    unsigned short* wtb   = xb + elems;
    unsigned short* qbuf  = wtb + 4ull * Dm * Dm;
    unsigned short* kbuf  = qbuf + elems;
    unsigned short* vtbuf = kbuf + elems;

    dim3 blk(256);
    hipLaunchKernelGGL(prologue, dim3(16, 16, 5), blk, 0, stream,
                       x, Wq, Wk, Wv, Wo, xb, wtb);

    hipLaunchKernelGGL(gemm_qkv192, dim3(256), dim3(512), 0, stream,
                       xb, wtb, bq, bk, bv, qbuf, kbuf, vtbuf);

    hipLaunchKernelGGL(attn_bf16, dim3(SQ / 128, NH, NB), blk, 0, stream,
                       qbuf, kbuf, vtbuf, qbuf);

    hipLaunchKernelGGL(gemm_out8, dim3(Dm / 128, M / 128), blk, 0, stream,
                       qbuf, wtb + 3ull * Dm * Dm, bo, out);
}

// Round 22
// 106.944 us; speedup vs baseline: 1.1481x; 1.0175x over previous
//
#include <hip/hip_runtime.h>
#include <math.h>

constexpr int Dm  = 1024;
constexpr int NH  = 16;
constexpr int SQ  = 2048;
constexpr int NB  = 2;

typedef float f32x4 __attribute__((ext_vector_type(4)));
typedef float f32x16 __attribute__((ext_vector_type(16)));
typedef short bf16x8 __attribute__((ext_vector_type(8)));
typedef __attribute__((address_space(3))) unsigned int lds_u32;
typedef __attribute__((address_space(1))) const unsigned int glb_u32;

__device__ __forceinline__ void gload_lds16(const void* g, void* l) {
    __builtin_amdgcn_global_load_lds((glb_u32*)(uintptr_t)g, (lds_u32*)(uintptr_t)l, 16, 0, 0);
}

__device__ __forceinline__ unsigned short bf_round(float x) {
    unsigned u = __float_as_uint(x);
    unsigned r = u + 0x7fffu + ((u >> 16) & 1u);
    return (unsigned short)(r >> 16);
}

__device__ __forceinline__ float exp2_fast(float x) {
    float r;
    asm("v_exp_f32 %0, %1" : "=v"(r) : "v"(x));
    return r;
}

__device__ __forceinline__ unsigned cvt_pk(float lo, float hi_) {
    unsigned r;
    asm("v_cvt_pk_bf16_f32 %0, %1, %2" : "=v"(r) : "v"(lo), "v"(hi_));
    return r;
}

__device__ __forceinline__ void permlane_swap(unsigned& a, unsigned& b) {
    asm volatile("v_permlane32_swap_b32 %0, %1" : "+v"(a), "+v"(b));
}

__device__ __forceinline__ bf16x8 make_frag(unsigned a, unsigned b, unsigned c, unsigned d) {
    union { unsigned u[4]; bf16x8 v; } uu;
    uu.u[0] = a; uu.u[1] = b; uu.u[2] = c; uu.u[3] = d;
    return uu.v;
}

// ---------------- prologue: W transpose (z=0..3) + x fp32->bf16 (z=4) ----------------
__global__ __launch_bounds__(256) void prologue(const float* __restrict__ x,
                                                const float* __restrict__ Wq,
                                                const float* __restrict__ Wk,
                                                const float* __restrict__ Wv,
                                                const float* __restrict__ Wo,
                                                unsigned short* __restrict__ xb,
                                                unsigned short* __restrict__ wt) {
    const int z = blockIdx.z;
    const int tid = threadIdx.x;
    if (z == 4) {
        size_t base = ((size_t)blockIdx.y * 16 + blockIdx.x) * 16384;
#pragma unroll
        for (int it = 0; it < 8; ++it) {
            size_t i = base + (size_t)it * 2048 + (size_t)tid * 8;
            float4 a = *(const float4*)&x[i];
            float4 b = *(const float4*)&x[i + 4];
            unsigned short o8[8] __attribute__((aligned(16)));
            o8[0] = bf_round(a.x); o8[1] = bf_round(a.y); o8[2] = bf_round(a.z); o8[3] = bf_round(a.w);
            o8[4] = bf_round(b.x); o8[5] = bf_round(b.y); o8[6] = bf_round(b.z); o8[7] = bf_round(b.w);
            *(uint4*)&xb[i] = *(const uint4*)o8;
        }
        return;
    }
    const float* W = (z == 0) ? Wq : (z == 1) ? Wk : (z == 2) ? Wv : Wo;
    unsigned short* dst = wt + (size_t)z * Dm * Dm;
    __shared__ float T[64][65];
    const int k0 = blockIdx.x * 64, n0 = blockIdx.y * 64;
#pragma unroll
    for (int i = 0; i < 4; ++i) {
        int s = tid + i * 256;
        int kk = s >> 4, c = (s & 15) * 4;
        *(float4*)&T[kk][c] = *(const float4*)&W[(size_t)(k0 + kk) * Dm + n0 + c];
    }
    __syncthreads();
#pragma unroll
    for (int i = 0; i < 2; ++i) {
        int s = tid + i * 256;
        int n = s >> 3, c8 = (s & 7) * 8;
        unsigned short o8[8] __attribute__((aligned(16)));
#pragma unroll
        for (int j = 0; j < 8; ++j) o8[j] = bf_round(T[c8 + j][n]);
        *(uint4*)&dst[(size_t)(n0 + n) * Dm + k0 + c8] = *(const uint4*)o8;
    }
}

// ====================================================================
// single-phase 256x192 QKV GEMM, ONE barrier per K-tile (round-20/21 verified)
// ====================================================================
__global__ __launch_bounds__(512) void gemm_qkv192(
    const unsigned short* __restrict__ xb,
    const unsigned short* __restrict__ wt,
    const float* __restrict__ bq, const float* __restrict__ bk,
    const float* __restrict__ bv,
    unsigned short* __restrict__ qbuf, unsigned short* __restrict__ kbuf,
    unsigned short* __restrict__ vtbuf)
{
    __shared__ unsigned short Alds[2][256 * 64];
    __shared__ unsigned short Blds[2][192 * 64];

    const int tid = threadIdx.x;
    const int lane = tid & 63, wid = tid >> 6;
    const int wm = wid >> 2, wn = wid & 3;
    const int l15 = lane & 15, lg = lane >> 4;

    const int bid = blockIdx.x;
    const int swz = (bid & 7) * 32 + (bid >> 3);
    const int bx = swz & 15, by = swz >> 4;
    const int m0 = by * 256, n0 = bx * 192;

    const int srow = wid * 8 + (lane >> 3);
    const int scol = ((lane & 7) ^ ((lane >> 3) & 7)) * 8;

    const unsigned short* Abase = xb + (size_t)m0 * Dm;
    const unsigned short* Bbase = wt + (size_t)n0 * Dm;

#define STAGE_TILE(t)                                                              \
    do {                                                                           \
        const unsigned short* As_ = Abase + (t) * 64;                              \
        const unsigned short* Bs_ = Bbase + (t) * 64;                              \
        unsigned short* Ad_ = Alds[(t) & 1];                                       \
        unsigned short* Bd_ = Blds[(t) & 1];                                       \
        _Pragma("unroll")                                                          \
        for (int i_ = 0; i_ < 4; ++i_)                                             \
            gload_lds16(&As_[(size_t)(i_ * 64 + srow) * Dm + scol],                \
                        &Ad_[i_ * 4096 + wid * 512]);                              \
        _Pragma("unroll")                                                          \
        for (int i_ = 0; i_ < 3; ++i_)                                             \
            gload_lds16(&Bs_[(size_t)(i_ * 64 + srow) * Dm + scol],                \
                        &Bd_[i_ * 4096 + wid * 512]);                              \
    } while (0)

    f32x4 acc[8][3];
#pragma unroll
    for (int mr = 0; mr < 8; ++mr)
#pragma unroll
        for (int nr = 0; nr < 3; ++nr) acc[mr][nr] = (f32x4){0.f, 0.f, 0.f, 0.f};

    STAGE_TILE(0);
    asm volatile("s_waitcnt vmcnt(0)" ::: "memory");
    __builtin_amdgcn_s_barrier();

    for (int t = 0; t < Dm / 64; ++t) {
        unsigned short* Ad = Alds[t & 1];
        unsigned short* Bd = Blds[t & 1];
        if (t + 1 < Dm / 64) STAGE_TILE(t + 1);

        bf16x8 a_[8][2], b_[3][2];

#define RD_A(qm, fr, ks) \
    (*(const bf16x8*)&Ad[(wm * 128 + (qm) * 64 + (fr) * 16 + l15) * 64 + \
                         ((((ks) * 4 + lg) ^ (l15 & 7)) * 8)])
#define RD_B(fc, ks) \
    (*(const bf16x8*)&Bd[(wn * 48 + (fc) * 16 + l15) * 64 + \
                         ((((ks) * 4 + lg) ^ (l15 & 7)) * 8)])

#pragma unroll
        for (int fr = 0; fr < 4; ++fr) {
            a_[fr][0] = RD_A(0, fr, 0);     a_[fr][1] = RD_A(0, fr, 1);
            a_[4 + fr][0] = RD_A(1, fr, 0); a_[4 + fr][1] = RD_A(1, fr, 1);
        }
#pragma unroll
        for (int fc = 0; fc < 3; ++fc) {
            b_[fc][0] = RD_B(fc, 0); b_[fc][1] = RD_B(fc, 1);
        }
        __builtin_amdgcn_s_setprio(1);
#pragma unroll
        for (int mr = 0; mr < 8; ++mr)
#pragma unroll
            for (int fc = 0; fc < 3; ++fc)
#pragma unroll
                for (int ks = 0; ks < 2; ++ks)
                    acc[mr][fc] = __builtin_amdgcn_mfma_f32_16x16x32_bf16(
                        a_[mr][ks], b_[fc][ks], acc[mr][fc], 0, 0, 0);
        __builtin_amdgcn_s_setprio(0);

        asm volatile("s_waitcnt vmcnt(0)" ::: "memory");
        __builtin_amdgcn_s_barrier();        // single barrier per K-tile
#undef RD_A
#undef RD_B
    }

    const float qscale = 0.18033688011f;   // 1/8 * log2(e)
#pragma unroll
    for (int mr = 0; mr < 8; ++mr) {
#pragma unroll
        for (int nr = 0; nr < 3; ++nr) {
            const int m = m0 + wm * 128 + mr * 16 + lg * 4;
            const int nglob = n0 + wn * 48 + nr * 16 + l15;
            const int zq = nglob >> 10;
            const int nz = nglob & 1023;
            const float* bias = (zq == 0) ? bq : (zq == 1) ? bk : bv;
            const float bb_ = bias[nz];
            if (zq == 0) {
#pragma unroll
                for (int rr = 0; rr < 4; ++rr)
                    qbuf[(size_t)(m + rr) * Dm + nz] =
                        bf_round((acc[mr][nr][rr] + bb_) * qscale);
            } else if (zq == 1) {
#pragma unroll
                for (int rr = 0; rr < 4; ++rr)
                    kbuf[(size_t)(m + rr) * Dm + nz] = bf_round(acc[mr][nr][rr] + bb_);
            } else {
                const int bbv = m >> 11, s = m & (SQ - 1);
                const int hh = nz >> 6, d = nz & 63;
                unsigned short p4[4] __attribute__((aligned(8)));
#pragma unroll
                for (int rr = 0; rr < 4; ++rr) p4[rr] = bf_round(acc[mr][nr][rr] + bb_);
                *(uint2*)&vtbuf[(((size_t)bbv * NH + hh) * 64 + d) * SQ + s] =
                    *(const uint2*)p4;
            }
        }
    }
#undef STAGE_TILE
}

// ====================================================================
// output projection, single-phase 128x128, ONE barrier per K-tile (round-20)
// ====================================================================
__global__ __launch_bounds__(256) void gemm_out8(const unsigned short* __restrict__ A,
                                                 const unsigned short* __restrict__ Bt,
                                                 const float* __restrict__ bias,
                                                 float* __restrict__ Cf) {
    __shared__ unsigned short Alds[2][128 * 64];
    __shared__ unsigned short Blds[2][128 * 64];

    const int tid = threadIdx.x;
    const int lane = tid & 63, wid = tid >> 6;
    const int l15 = lane & 15, lg = lane >> 4;
    const int wr = (wid >> 1) * 64, wc = (wid & 1) * 64;
    const int m0 = blockIdx.y * 128, n0 = blockIdx.x * 128;

    const int srow = (tid >> 3) & 31;
    const int scol = ((tid & 7) ^ (srow & 7)) * 8;

    const unsigned short* Abase = A + (size_t)m0 * Dm;
    const unsigned short* Bbase = Bt + (size_t)n0 * Dm;

#define STAGE_TILE(t)                                                              \
    do {                                                                           \
        const unsigned short* As_ = Abase + (t) * 64;                              \
        const unsigned short* Bs_ = Bbase + (t) * 64;                              \
        unsigned short* Ad_ = Alds[(t) & 1];                                       \
        unsigned short* Bd_ = Blds[(t) & 1];                                       \
        _Pragma("unroll")                                                          \
        for (int i_ = 0; i_ < 4; ++i_) {                                           \
            gload_lds16(&As_[(size_t)(i_ * 32 + srow) * Dm + scol],                \
                        &Ad_[i_ * 2048 + wid * 512]);                              \
            gload_lds16(&Bs_[(size_t)(i_ * 32 + srow) * Dm + scol],                \
                        &Bd_[i_ * 2048 + wid * 512]);                              \
        }                                                                          \
    } while (0)

    f32x4 acc[4][4];
#pragma unroll
    for (int r = 0; r < 4; ++r)
#pragma unroll
        for (int c = 0; c < 4; ++c) acc[r][c] = (f32x4){0.f, 0.f, 0.f, 0.f};

    STAGE_TILE(0);
    asm volatile("s_waitcnt vmcnt(0)" ::: "memory");
    __builtin_amdgcn_s_barrier();

    for (int t = 0; t < Dm / 64; ++t) {
        unsigned short* Ad = Alds[t & 1];
        unsigned short* Bd = Blds[t & 1];
        if (t + 1 < Dm / 64) STAGE_TILE(t + 1);

        bf16x8 a_[4][2], b_[4][2];

#define RD_A(fr, ks) \
    (*(const bf16x8*)&Ad[(wr + (fr) * 16 + l15) * 64 + ((((ks) * 4 + lg) ^ (l15 & 7)) * 8)])
#define RD_B(fc, ks) \
    (*(const bf16x8*)&Bd[(wc + (fc) * 16 + l15) * 64 + ((((ks) * 4 + lg) ^ (l15 & 7)) * 8)])

#pragma unroll
        for (int fr = 0; fr < 4; ++fr) {
            a_[fr][0] = RD_A(fr, 0); a_[fr][1] = RD_A(fr, 1);
        }
#pragma unroll
        for (int fc = 0; fc < 4; ++fc) {
            b_[fc][0] = RD_B(fc, 0); b_[fc][1] = RD_B(fc, 1);
        }
        __builtin_amdgcn_s_setprio(1);
#pragma unroll
        for (int fr = 0; fr < 4; ++fr)
#pragma unroll
            for (int fc = 0; fc < 4; ++fc)
#pragma unroll
                for (int ks = 0; ks < 2; ++ks)
                    acc[fr][fc] = __builtin_amdgcn_mfma_f32_16x16x32_bf16(
                        a_[fr][ks], b_[fc][ks], acc[fr][fc], 0, 0, 0);
        __builtin_amdgcn_s_setprio(0);

        asm volatile("s_waitcnt vmcnt(0)" ::: "memory");
        __builtin_amdgcn_s_barrier();        // single barrier per K-tile
#undef RD_A
#undef RD_B
    }

#pragma unroll
    for (int r = 0; r < 4; ++r) {
#pragma unroll
        for (int c = 0; c < 4; ++c) {
            const int mBase = m0 + wr + r * 16 + lg * 4;
            const int n = n0 + wc + c * 16 + l15;
            const float bv_ = bias[n];
#pragma unroll
            for (int rr = 0; rr < 4; ++rr)
                Cf[(size_t)(mBase + rr) * Dm + n] = acc[r][c][rr] + bv_;
        }
    }
#undef STAGE_TILE
}

// ---------------- flash attention: round-21 body + XCD-affine block remap ----
// 1D grid of 512: bid = qt*32 + (b*16 + h). All 16 qt-blocks sharing one
// (b,h)'s K/V have identical bid%8 -> same XCD -> K/V (512 KB) stays in that
// XCD's L2 (4 groups x 512 KB = 2 MB < 4 MB). Compute body unchanged.
__global__ __launch_bounds__(256) void attn_bf16(const unsigned short* q,
                                                 const unsigned short* __restrict__ k,
                                                 const unsigned short* __restrict__ vt,
                                                 unsigned short* ao) {
    __shared__ unsigned short KVs[2][2][64 * 64];  // [buf][0=K,1=Vt], XOR-swizzled
    const int bid = blockIdx.x;
    const int qt = bid >> 5;            // 0..15
    const int g  = bid & 31;            // b*16 + h
    const int b  = g >> 4, h = g & 15;
    const int tid = threadIdx.x, lane = tid & 63, wid = tid >> 6;
    const int l31 = lane & 31, hi = lane >> 5;

    const size_t qrow0 = (size_t)b * SQ + qt * 128;
    const unsigned short* qp = q + (qrow0 + wid * 32 + l31) * Dm + h * 64;
    bf16x8 qf[4];
#pragma unroll
    for (int ks = 0; ks < 4; ++ks)
        qf[ks] = *(const bf16x8*)&qp[ks * 16 + hi * 8];

    const unsigned short* kb = k + (size_t)b * SQ * Dm + h * 64;
    const unsigned short* vb = vt + ((size_t)b * NH + h) * 64 * SQ;

    const int wrow = wid * 8 + (lane >> 3);
    const int gcol = ((lane & 7) ^ ((lane >> 3) & 7)) * 8;

#define STAGE_KV(buf, T0)                                                          \
    do {                                                                           \
        unsigned short* Kd_ = &KVs[buf][0][0];                                     \
        unsigned short* Vd_ = &KVs[buf][1][0];                                     \
        _Pragma("unroll")                                                          \
        for (int i_ = 0; i_ < 2; ++i_) {                                           \
            gload_lds16(&kb[(size_t)((T0) + wrow + 32 * i_) * Dm + gcol],          \
                        &Kd_[i_ * 2048 + wid * 512]);                              \
            gload_lds16(&vb[(size_t)(wrow + 32 * i_) * SQ + (T0) + gcol],          \
                        &Vd_[i_ * 2048 + wid * 512]);                              \
        }                                                                          \
    } while (0)

    STAGE_KV(0, 0);
    asm volatile("s_waitcnt vmcnt(0)" ::: "memory");
    __builtin_amdgcn_s_barrier();

    float psum = 0.f;
    f32x16 c0, c1;
#pragma unroll
    for (int i = 0; i < 16; ++i) { c0[i] = 0.f; c1[i] = 0.f; }

    int cur = 0;
    for (int t0 = 0; t0 < SQ; t0 += 64) {
        if (t0 + 64 < SQ) STAGE_KV(cur ^ 1, t0 + 64);   // issue early; drains at tile end
        const unsigned short* Kc = KVs[cur][0];
        const unsigned short* Vc = KVs[cur][1];

#pragma unroll
        for (int kblk = 0; kblk < 2; ++kblk) {
            f32x16 p;
#pragma unroll
            for (int i = 0; i < 16; ++i) p[i] = 0.f;
            __builtin_amdgcn_s_setprio(1);
#pragma unroll
            for (int ks = 0; ks < 4; ++ks) {
                int row = kblk * 32 + l31;
                int slot = ((ks * 2 + hi) ^ (l31 & 7)) * 8;
                bf16x8 kf = *(const bf16x8*)&Kc[row * 64 + slot];
                p = __builtin_amdgcn_mfma_f32_32x32x16_bf16(kf, qf[ks], p, 0, 0, 0);
            }
            __builtin_amdgcn_s_setprio(0);

            float e[16];
#pragma unroll
            for (int i = 0; i < 16; ++i) { e[i] = exp2_fast(p[i]); psum += e[i]; }
            unsigned w0 = cvt_pk(e[0], e[1]),   w1 = cvt_pk(e[2], e[3]);
            unsigned w2 = cvt_pk(e[4], e[5]),   w3 = cvt_pk(e[6], e[7]);
            unsigned w4 = cvt_pk(e[8], e[9]),   w5 = cvt_pk(e[10], e[11]);
            unsigned w6 = cvt_pk(e[12], e[13]), w7 = cvt_pk(e[14], e[15]);
            permlane_swap(w0, w2); permlane_swap(w1, w3);
            permlane_swap(w4, w6); permlane_swap(w5, w7);
            bf16x8 pf0 = make_frag(w0, w1, w2, w3);
            bf16x8 pf1 = make_frag(w4, w5, w6, w7);

            int s0 = ((kblk * 4 + hi) ^ (l31 & 7)) * 8;
            int s1 = ((kblk * 4 + 2 + hi) ^ (l31 & 7)) * 8;
            bf16x8 va0 = *(const bf16x8*)&Vc[l31 * 64 + s0];
            bf16x8 va1 = *(const bf16x8*)&Vc[l31 * 64 + s1];
            bf16x8 vb0 = *(const bf16x8*)&Vc[(32 + l31) * 64 + s0];
            bf16x8 vb1 = *(const bf16x8*)&Vc[(32 + l31) * 64 + s1];
            __builtin_amdgcn_s_setprio(1);
            c0 = __builtin_amdgcn_mfma_f32_32x32x16_bf16(va0, pf0, c0, 0, 0, 0);
            c0 = __builtin_amdgcn_mfma_f32_32x32x16_bf16(va1, pf1, c0, 0, 0, 0);
            c1 = __builtin_amdgcn_mfma_f32_32x32x16_bf16(vb0, pf0, c1, 0, 0, 0);
            c1 = __builtin_amdgcn_mfma_f32_32x32x16_bf16(vb1, pf1, c1, 0, 0, 0);
            __builtin_amdgcn_s_setprio(0);
        }

        asm volatile("s_waitcnt vmcnt(0)" ::: "memory");
        __syncthreads();   // single barrier per tile
        cur ^= 1;
    }

    float s = psum + __shfl_xor(psum, 32, 64);
    float inv = 1.f / s;

    unsigned short* Olds = (unsigned short*)KVs;
    {
        const int orow = wid * 32 + l31;
#pragma unroll
        for (int db = 0; db < 2; ++db) {
#pragma unroll
            for (int i = 0; i < 8; ++i) {
                float lo  = (db ? c1[2 * i] : c0[2 * i]) * inv;
                float hi_ = (db ? c1[2 * i + 1] : c0[2 * i + 1]) * inv;
                unsigned w = cvt_pk(lo, hi_);
                int d7 = hi * 4 + (i & 1) * 2;
                int slot = db * 4 + (i >> 1);
                int sw = slot ^ (l31 & 7);
                *(unsigned*)&Olds[orow * 64 + sw * 8 + d7] = w;
            }
        }
    }
    __syncthreads();
    {
        int r = tid >> 1, half = tid & 1;
        unsigned short* dst = ao + (qrow0 + r) * Dm + h * 64 + half * 32;
#pragma unroll
        for (int j = 0; j < 4; ++j) {
            int slot = half * 4 + j;
            int sw = slot ^ (r & 7);
            *(uint4*)&dst[j * 8] = *(const uint4*)&Olds[r * 64 + sw * 8];
        }
    }
#undef STAGE_KV
}

extern "C" void kernel_launch(void* const* d_in, const int* in_sizes, int n_in,
                              void* d_out, int out_size, void* d_ws, size_t ws_size,
                              hipStream_t stream) {
    const float* x  = (const float*)d_in[0];
    const float* Wq = (const float*)d_in[1];
    const float* bq = (const float*)d_in[2];
    const float* Wk = (const float*)d_in[3];
    const float* bk = (const float*)d_in[4];
    const float* Wv = (const float*)d_in[5];
    const float* bv = (const float*)d_in[6];
    const float* Wo = (const float*)d_in[7];
    const float* bo = (const float*)d_in[8];
    float* out = (float*)d_out;

    const size_t M = (size_t)NB * SQ;           // 4096
    const size_t elems = M * Dm;                // 4M
    unsigned short* xb    = (unsigned short*)d_ws;
    unsigned short* wtb   = xb + elems;
    unsigned short* qbuf  = wtb + 4ull * Dm * Dm;
    unsigned short* kbuf  = qbuf + elems;
    unsigned short* vtbuf = kbuf + elems;

    dim3 blk(256);
    hipLaunchKernelGGL(prologue, dim3(16, 16, 5), blk, 0, stream,
                       x, Wq, Wk, Wv, Wo, xb, wtb);

    hipLaunchKernelGGL(gemm_qkv192, dim3(256), dim3(512), 0, stream,
                       xb, wtb, bq, bk, bv, qbuf, kbuf, vtbuf);

    hipLaunchKernelGGL(attn_bf16, dim3(512), blk, 0, stream,
                       qbuf, kbuf, vtbuf, qbuf);

    hipLaunchKernelGGL(gemm_out8, dim3(Dm / 128, M / 128), blk, 0, stream,
                       qbuf, wtb + 3ull * Dm * Dm, bo, out);
}

// Round 23
// 106.818 us; speedup vs baseline: 1.1494x; 1.0012x over previous
//
#include <hip/hip_runtime.h>
#include <math.h>

constexpr int Dm  = 1024;
constexpr int NH  = 16;
constexpr int SQ  = 2048;
constexpr int NB  = 2;

typedef float f32x4 __attribute__((ext_vector_type(4)));
typedef float f32x16 __attribute__((ext_vector_type(16)));
typedef short bf16x8 __attribute__((ext_vector_type(8)));
typedef __attribute__((address_space(3))) unsigned int lds_u32;
typedef __attribute__((address_space(1))) const unsigned int glb_u32;

__device__ __forceinline__ void gload_lds16(const void* g, void* l) {
    __builtin_amdgcn_global_load_lds((glb_u32*)(uintptr_t)g, (lds_u32*)(uintptr_t)l, 16, 0, 0);
}

__device__ __forceinline__ unsigned short bf_round(float x) {
    unsigned u = __float_as_uint(x);
    unsigned r = u + 0x7fffu + ((u >> 16) & 1u);
    return (unsigned short)(r >> 16);
}

__device__ __forceinline__ float exp2_fast(float x) {
    float r;
    asm("v_exp_f32 %0, %1" : "=v"(r) : "v"(x));
    return r;
}

__device__ __forceinline__ unsigned cvt_pk(float lo, float hi_) {
    unsigned r;
    asm("v_cvt_pk_bf16_f32 %0, %1, %2" : "=v"(r) : "v"(lo), "v"(hi_));
    return r;
}

__device__ __forceinline__ void permlane_swap(unsigned& a, unsigned& b) {
    asm volatile("v_permlane32_swap_b32 %0, %1" : "+v"(a), "+v"(b));
}

__device__ __forceinline__ bf16x8 make_frag(unsigned a, unsigned b, unsigned c, unsigned d) {
    union { unsigned u[4]; bf16x8 v; } uu;
    uu.u[0] = a; uu.u[1] = b; uu.u[2] = c; uu.u[3] = d;
    return uu.v;
}

// ---------------- prologue: W transpose (z=0..3) + x fp32->bf16 (z=4) ----------------
__global__ __launch_bounds__(256) void prologue(const float* __restrict__ x,
                                                const float* __restrict__ Wq,
                                                const float* __restrict__ Wk,
                                                const float* __restrict__ Wv,
                                                const float* __restrict__ Wo,
                                                unsigned short* __restrict__ xb,
                                                unsigned short* __restrict__ wt) {
    const int z = blockIdx.z;
    const int tid = threadIdx.x;
    if (z == 4) {
        size_t base = ((size_t)blockIdx.y * 16 + blockIdx.x) * 16384;
#pragma unroll
        for (int it = 0; it < 8; ++it) {
            size_t i = base + (size_t)it * 2048 + (size_t)tid * 8;
            float4 a = *(const float4*)&x[i];
            float4 b = *(const float4*)&x[i + 4];
            unsigned short o8[8] __attribute__((aligned(16)));
            o8[0] = bf_round(a.x); o8[1] = bf_round(a.y); o8[2] = bf_round(a.z); o8[3] = bf_round(a.w);
            o8[4] = bf_round(b.x); o8[5] = bf_round(b.y); o8[6] = bf_round(b.z); o8[7] = bf_round(b.w);
            *(uint4*)&xb[i] = *(const uint4*)o8;
        }
        return;
    }
    const float* W = (z == 0) ? Wq : (z == 1) ? Wk : (z == 2) ? Wv : Wo;
    unsigned short* dst = wt + (size_t)z * Dm * Dm;
    __shared__ float T[64][65];
    const int k0 = blockIdx.x * 64, n0 = blockIdx.y * 64;
#pragma unroll
    for (int i = 0; i < 4; ++i) {
        int s = tid + i * 256;
        int kk = s >> 4, c = (s & 15) * 4;
        *(float4*)&T[kk][c] = *(const float4*)&W[(size_t)(k0 + kk) * Dm + n0 + c];
    }
    __syncthreads();
#pragma unroll
    for (int i = 0; i < 2; ++i) {
        int s = tid + i * 256;
        int n = s >> 3, c8 = (s & 7) * 8;
        unsigned short o8[8] __attribute__((aligned(16)));
#pragma unroll
        for (int j = 0; j < 8; ++j) o8[j] = bf_round(T[c8 + j][n]);
        *(uint4*)&dst[(size_t)(n0 + n) * Dm + k0 + c8] = *(const uint4*)o8;
    }
}

// ====================================================================
// single-phase 256x192 QKV GEMM, ONE barrier per K-tile (round-20/21 verified)
// ====================================================================
__global__ __launch_bounds__(512) void gemm_qkv192(
    const unsigned short* __restrict__ xb,
    const unsigned short* __restrict__ wt,
    const float* __restrict__ bq, const float* __restrict__ bk,
    const float* __restrict__ bv,
    unsigned short* __restrict__ qbuf, unsigned short* __restrict__ kbuf,
    unsigned short* __restrict__ vtbuf)
{
    __shared__ unsigned short Alds[2][256 * 64];
    __shared__ unsigned short Blds[2][192 * 64];

    const int tid = threadIdx.x;
    const int lane = tid & 63, wid = tid >> 6;
    const int wm = wid >> 2, wn = wid & 3;
    const int l15 = lane & 15, lg = lane >> 4;

    const int bid = blockIdx.x;
    const int swz = (bid & 7) * 32 + (bid >> 3);
    const int bx = swz & 15, by = swz >> 4;
    const int m0 = by * 256, n0 = bx * 192;

    const int srow = wid * 8 + (lane >> 3);
    const int scol = ((lane & 7) ^ ((lane >> 3) & 7)) * 8;

    const unsigned short* Abase = xb + (size_t)m0 * Dm;
    const unsigned short* Bbase = wt + (size_t)n0 * Dm;

#define STAGE_TILE(t)                                                              \
    do {                                                                           \
        const unsigned short* As_ = Abase + (t) * 64;                              \
        const unsigned short* Bs_ = Bbase + (t) * 64;                              \
        unsigned short* Ad_ = Alds[(t) & 1];                                       \
        unsigned short* Bd_ = Blds[(t) & 1];                                       \
        _Pragma("unroll")                                                          \
        for (int i_ = 0; i_ < 4; ++i_)                                             \
            gload_lds16(&As_[(size_t)(i_ * 64 + srow) * Dm + scol],                \
                        &Ad_[i_ * 4096 + wid * 512]);                              \
        _Pragma("unroll")                                                          \
        for (int i_ = 0; i_ < 3; ++i_)                                             \
            gload_lds16(&Bs_[(size_t)(i_ * 64 + srow) * Dm + scol],                \
                        &Bd_[i_ * 4096 + wid * 512]);                              \
    } while (0)

    f32x4 acc[8][3];
#pragma unroll
    for (int mr = 0; mr < 8; ++mr)
#pragma unroll
        for (int nr = 0; nr < 3; ++nr) acc[mr][nr] = (f32x4){0.f, 0.f, 0.f, 0.f};

    STAGE_TILE(0);
    asm volatile("s_waitcnt vmcnt(0)" ::: "memory");
    __builtin_amdgcn_s_barrier();

    for (int t = 0; t < Dm / 64; ++t) {
        unsigned short* Ad = Alds[t & 1];
        unsigned short* Bd = Blds[t & 1];
        if (t + 1 < Dm / 64) STAGE_TILE(t + 1);

        bf16x8 a_[8][2], b_[3][2];

#define RD_A(qm, fr, ks) \
    (*(const bf16x8*)&Ad[(wm * 128 + (qm) * 64 + (fr) * 16 + l15) * 64 + \
                         ((((ks) * 4 + lg) ^ (l15 & 7)) * 8)])
#define RD_B(fc, ks) \
    (*(const bf16x8*)&Bd[(wn * 48 + (fc) * 16 + l15) * 64 + \
                         ((((ks) * 4 + lg) ^ (l15 & 7)) * 8)])

#pragma unroll
        for (int fr = 0; fr < 4; ++fr) {
            a_[fr][0] = RD_A(0, fr, 0);     a_[fr][1] = RD_A(0, fr, 1);
            a_[4 + fr][0] = RD_A(1, fr, 0); a_[4 + fr][1] = RD_A(1, fr, 1);
        }
#pragma unroll
        for (int fc = 0; fc < 3; ++fc) {
            b_[fc][0] = RD_B(fc, 0); b_[fc][1] = RD_B(fc, 1);
        }
        __builtin_amdgcn_s_setprio(1);
#pragma unroll
        for (int mr = 0; mr < 8; ++mr)
#pragma unroll
            for (int fc = 0; fc < 3; ++fc)
#pragma unroll
                for (int ks = 0; ks < 2; ++ks)
                    acc[mr][fc] = __builtin_amdgcn_mfma_f32_16x16x32_bf16(
                        a_[mr][ks], b_[fc][ks], acc[mr][fc], 0, 0, 0);
        __builtin_amdgcn_s_setprio(0);

        asm volatile("s_waitcnt vmcnt(0)" ::: "memory");
        __builtin_amdgcn_s_barrier();        // single barrier per K-tile
#undef RD_A
#undef RD_B
    }

    const float qscale = 0.18033688011f;   // 1/8 * log2(e)
#pragma unroll
    for (int mr = 0; mr < 8; ++mr) {
#pragma unroll
        for (int nr = 0; nr < 3; ++nr) {
            const int m = m0 + wm * 128 + mr * 16 + lg * 4;
            const int nglob = n0 + wn * 48 + nr * 16 + l15;
            const int zq = nglob >> 10;
            const int nz = nglob & 1023;
            const float* bias = (zq == 0) ? bq : (zq == 1) ? bk : bv;
            const float bb_ = bias[nz];
            if (zq == 0) {
#pragma unroll
                for (int rr = 0; rr < 4; ++rr)
                    qbuf[(size_t)(m + rr) * Dm + nz] =
                        bf_round((acc[mr][nr][rr] + bb_) * qscale);
            } else if (zq == 1) {
#pragma unroll
                for (int rr = 0; rr < 4; ++rr)
                    kbuf[(size_t)(m + rr) * Dm + nz] = bf_round(acc[mr][nr][rr] + bb_);
            } else {
                const int bbv = m >> 11, s = m & (SQ - 1);
                const int hh = nz >> 6, d = nz & 63;
                unsigned short p4[4] __attribute__((aligned(8)));
#pragma unroll
                for (int rr = 0; rr < 4; ++rr) p4[rr] = bf_round(acc[mr][nr][rr] + bb_);
                *(uint2*)&vtbuf[(((size_t)bbv * NH + hh) * 64 + d) * SQ + s] =
                    *(const uint2*)p4;
            }
        }
    }
#undef STAGE_TILE
}

// ====================================================================
// output projection, single-phase 128x128, ONE barrier per K-tile (round-20)
// ====================================================================
__global__ __launch_bounds__(256) void gemm_out8(const unsigned short* __restrict__ A,
                                                 const unsigned short* __restrict__ Bt,
                                                 const float* __restrict__ bias,
                                                 float* __restrict__ Cf) {
    __shared__ unsigned short Alds[2][128 * 64];
    __shared__ unsigned short Blds[2][128 * 64];

    const int tid = threadIdx.x;
    const int lane = tid & 63, wid = tid >> 6;
    const int l15 = lane & 15, lg = lane >> 4;
    const int wr = (wid >> 1) * 64, wc = (wid & 1) * 64;
    const int m0 = blockIdx.y * 128, n0 = blockIdx.x * 128;

    const int srow = (tid >> 3) & 31;
    const int scol = ((tid & 7) ^ (srow & 7)) * 8;

    const unsigned short* Abase = A + (size_t)m0 * Dm;
    const unsigned short* Bbase = Bt + (size_t)n0 * Dm;

#define STAGE_TILE(t)                                                              \
    do {                                                                           \
        const unsigned short* As_ = Abase + (t) * 64;                              \
        const unsigned short* Bs_ = Bbase + (t) * 64;                              \
        unsigned short* Ad_ = Alds[(t) & 1];                                       \
        unsigned short* Bd_ = Blds[(t) & 1];                                       \
        _Pragma("unroll")                                                          \
        for (int i_ = 0; i_ < 4; ++i_) {                                           \
            gload_lds16(&As_[(size_t)(i_ * 32 + srow) * Dm + scol],                \
                        &Ad_[i_ * 2048 + wid * 512]);                              \
            gload_lds16(&Bs_[(size_t)(i_ * 32 + srow) * Dm + scol],                \
                        &Bd_[i_ * 2048 + wid * 512]);                              \
        }                                                                          \
    } while (0)

    f32x4 acc[4][4];
#pragma unroll
    for (int r = 0; r < 4; ++r)
#pragma unroll
        for (int c = 0; c < 4; ++c) acc[r][c] = (f32x4){0.f, 0.f, 0.f, 0.f};

    STAGE_TILE(0);
    asm volatile("s_waitcnt vmcnt(0)" ::: "memory");
    __builtin_amdgcn_s_barrier();

    for (int t = 0; t < Dm / 64; ++t) {
        unsigned short* Ad = Alds[t & 1];
        unsigned short* Bd = Blds[t & 1];
        if (t + 1 < Dm / 64) STAGE_TILE(t + 1);

        bf16x8 a_[4][2], b_[4][2];

#define RD_A(fr, ks) \
    (*(const bf16x8*)&Ad[(wr + (fr) * 16 + l15) * 64 + ((((ks) * 4 + lg) ^ (l15 & 7)) * 8)])
#define RD_B(fc, ks) \
    (*(const bf16x8*)&Bd[(wc + (fc) * 16 + l15) * 64 + ((((ks) * 4 + lg) ^ (l15 & 7)) * 8)])

#pragma unroll
        for (int fr = 0; fr < 4; ++fr) {
            a_[fr][0] = RD_A(fr, 0); a_[fr][1] = RD_A(fr, 1);
        }
#pragma unroll
        for (int fc = 0; fc < 4; ++fc) {
            b_[fc][0] = RD_B(fc, 0); b_[fc][1] = RD_B(fc, 1);
        }
        __builtin_amdgcn_s_setprio(1);
#pragma unroll
        for (int fr = 0; fr < 4; ++fr)
#pragma unroll
            for (int fc = 0; fc < 4; ++fc)
#pragma unroll
                for (int ks = 0; ks < 2; ++ks)
                    acc[fr][fc] = __builtin_amdgcn_mfma_f32_16x16x32_bf16(
                        a_[fr][ks], b_[fc][ks], acc[fr][fc], 0, 0, 0);
        __builtin_amdgcn_s_setprio(0);

        asm volatile("s_waitcnt vmcnt(0)" ::: "memory");
        __builtin_amdgcn_s_barrier();        // single barrier per K-tile
#undef RD_A
#undef RD_B
    }

#pragma unroll
    for (int r = 0; r < 4; ++r) {
#pragma unroll
        for (int c = 0; c < 4; ++c) {
            const int mBase = m0 + wr + r * 16 + lg * 4;
            const int n = n0 + wc + c * 16 + l15;
            const float bv_ = bias[n];
#pragma unroll
            for (int rr = 0; rr < 4; ++rr)
                Cf[(size_t)(mBase + rr) * Dm + n] = acc[r][c][rr] + bv_;
        }
    }
#undef STAGE_TILE
}

// ---------------- flash attention: round-21 body + XCD-affine block remap ----
// 1D grid of 512: bid = qt*32 + (b*16 + h). All 16 qt-blocks sharing one
// (b,h)'s K/V have identical bid%8 -> same XCD -> K/V (512 KB) stays in that
// XCD's L2 (4 groups x 512 KB = 2 MB < 4 MB). Compute body unchanged.
__global__ __launch_bounds__(256) void attn_bf16(const unsigned short* q,
                                                 const unsigned short* __restrict__ k,
                                                 const unsigned short* __restrict__ vt,
                                                 unsigned short* ao) {
    __shared__ unsigned short KVs[2][2][64 * 64];  // [buf][0=K,1=Vt], XOR-swizzled
    const int bid = blockIdx.x;
    const int qt = bid >> 5;            // 0..15
    const int g  = bid & 31;            // b*16 + h
    const int b  = g >> 4, h = g & 15;
    const int tid = threadIdx.x, lane = tid & 63, wid = tid >> 6;
    const int l31 = lane & 31, hi = lane >> 5;

    const size_t qrow0 = (size_t)b * SQ + qt * 128;
    const unsigned short* qp = q + (qrow0 + wid * 32 + l31) * Dm + h * 64;
    bf16x8 qf[4];
#pragma unroll
    for (int ks = 0; ks < 4; ++ks)
        qf[ks] = *(const bf16x8*)&qp[ks * 16 + hi * 8];

    const unsigned short* kb = k + (size_t)b * SQ * Dm + h * 64;
    const unsigned short* vb = vt + ((size_t)b * NH + h) * 64 * SQ;

    const int wrow = wid * 8 + (lane >> 3);
    const int gcol = ((lane & 7) ^ ((lane >> 3) & 7)) * 8;

#define STAGE_KV(buf, T0)                                                          \
    do {                                                                           \
        unsigned short* Kd_ = &KVs[buf][0][0];                                     \
        unsigned short* Vd_ = &KVs[buf][1][0];                                     \
        _Pragma("unroll")                                                          \
        for (int i_ = 0; i_ < 2; ++i_) {                                           \
            gload_lds16(&kb[(size_t)((T0) + wrow + 32 * i_) * Dm + gcol],          \
                        &Kd_[i_ * 2048 + wid * 512]);                              \
            gload_lds16(&vb[(size_t)(wrow + 32 * i_) * SQ + (T0) + gcol],          \
                        &Vd_[i_ * 2048 + wid * 512]);                              \
        }                                                                          \
    } while (0)

    STAGE_KV(0, 0);
    asm volatile("s_waitcnt vmcnt(0)" ::: "memory");
    __builtin_amdgcn_s_barrier();

    float psum = 0.f;
    f32x16 c0, c1;
#pragma unroll
    for (int i = 0; i < 16; ++i) { c0[i] = 0.f; c1[i] = 0.f; }

    int cur = 0;
    for (int t0 = 0; t0 < SQ; t0 += 64) {
        if (t0 + 64 < SQ) STAGE_KV(cur ^ 1, t0 + 64);   // issue early; drains at tile end
        const unsigned short* Kc = KVs[cur][0];
        const unsigned short* Vc = KVs[cur][1];

#pragma unroll
        for (int kblk = 0; kblk < 2; ++kblk) {
            f32x16 p;
#pragma unroll
            for (int i = 0; i < 16; ++i) p[i] = 0.f;
            __builtin_amdgcn_s_setprio(1);
#pragma unroll
            for (int ks = 0; ks < 4; ++ks) {
                int row = kblk * 32 + l31;
                int slot = ((ks * 2 + hi) ^ (l31 & 7)) * 8;
                bf16x8 kf = *(const bf16x8*)&Kc[row * 64 + slot];
                p = __builtin_amdgcn_mfma_f32_32x32x16_bf16(kf, qf[ks], p, 0, 0, 0);
            }
            __builtin_amdgcn_s_setprio(0);

            float e[16];
#pragma unroll
            for (int i = 0; i < 16; ++i) { e[i] = exp2_fast(p[i]); psum += e[i]; }
            unsigned w0 = cvt_pk(e[0], e[1]),   w1 = cvt_pk(e[2], e[3]);
            unsigned w2 = cvt_pk(e[4], e[5]),   w3 = cvt_pk(e[6], e[7]);
            unsigned w4 = cvt_pk(e[8], e[9]),   w5 = cvt_pk(e[10], e[11]);
            unsigned w6 = cvt_pk(e[12], e[13]), w7 = cvt_pk(e[14], e[15]);
            permlane_swap(w0, w2); permlane_swap(w1, w3);
            permlane_swap(w4, w6); permlane_swap(w5, w7);
            bf16x8 pf0 = make_frag(w0, w1, w2, w3);
            bf16x8 pf1 = make_frag(w4, w5, w6, w7);

            int s0 = ((kblk * 4 + hi) ^ (l31 & 7)) * 8;
            int s1 = ((kblk * 4 + 2 + hi) ^ (l31 & 7)) * 8;
            bf16x8 va0 = *(const bf16x8*)&Vc[l31 * 64 + s0];
            bf16x8 va1 = *(const bf16x8*)&Vc[l31 * 64 + s1];
            bf16x8 vb0 = *(const bf16x8*)&Vc[(32 + l31) * 64 + s0];
            bf16x8 vb1 = *(const bf16x8*)&Vc[(32 + l31) * 64 + s1];
            __builtin_amdgcn_s_setprio(1);
            c0 = __builtin_amdgcn_mfma_f32_32x32x16_bf16(va0, pf0, c0, 0, 0, 0);
            c0 = __builtin_amdgcn_mfma_f32_32x32x16_bf16(va1, pf1, c0, 0, 0, 0);
            c1 = __builtin_amdgcn_mfma_f32_32x32x16_bf16(vb0, pf0, c1, 0, 0, 0);
            c1 = __builtin_amdgcn_mfma_f32_32x32x16_bf16(vb1, pf1, c1, 0, 0, 0);
            __builtin_amdgcn_s_setprio(0);
        }

        asm volatile("s_waitcnt vmcnt(0)" ::: "memory");
        __syncthreads();   // single barrier per tile
        cur ^= 1;
    }

    float s = psum + __shfl_xor(psum, 32, 64);
    float inv = 1.f / s;

    unsigned short* Olds = (unsigned short*)KVs;
    {
        const int orow = wid * 32 + l31;
#pragma unroll
        for (int db = 0; db < 2; ++db) {
#pragma unroll
            for (int i = 0; i < 8; ++i) {
                float lo  = (db ? c1[2 * i] : c0[2 * i]) * inv;
                float hi_ = (db ? c1[2 * i + 1] : c0[2 * i + 1]) * inv;
                unsigned w = cvt_pk(lo, hi_);
                int d7 = hi * 4 + (i & 1) * 2;
                int slot = db * 4 + (i >> 1);
                int sw = slot ^ (l31 & 7);
                *(unsigned*)&Olds[orow * 64 + sw * 8 + d7] = w;
            }
        }
    }
    __syncthreads();
    {
        int r = tid >> 1, half = tid & 1;
        unsigned short* dst = ao + (qrow0 + r) * Dm + h * 64 + half * 32;
#pragma unroll
        for (int j = 0; j < 4; ++j) {
            int slot = half * 4 + j;
            int sw = slot ^ (r & 7);
            *(uint4*)&dst[j * 8] = *(const uint4*)&Olds[r * 64 + sw * 8];
        }
    }
#undef STAGE_KV
}

extern "C" void kernel_launch(void* const* d_in, const int* in_sizes, int n_in,
                              void* d_out, int out_size, void* d_ws, size_t ws_size,
                              hipStream_t stream) {
    const float* x  = (const float*)d_in[0];
    const float* Wq = (const float*)d_in[1];
    const float* bq = (const float*)d_in[2];
    const float* Wk = (const float*)d_in[3];
    const float* bk = (const float*)d_in[4];
    const float* Wv = (const float*)d_in[5];
    const float* bv = (const float*)d_in[6];
    const float* Wo = (const float*)d_in[7];
    const float* bo = (const float*)d_in[8];
    float* out = (float*)d_out;

    const size_t M = (size_t)NB * SQ;           // 4096
    const size_t elems = M * Dm;                // 4M
    unsigned short* xb    = (unsigned short*)d_ws;
    unsigned short* wtb   = xb + elems;
    unsigned short* qbuf  = wtb + 4ull * Dm * Dm;
    unsigned short* kbuf  = qbuf + elems;
    unsigned short* vtbuf = kbuf + elems;

    dim3 blk(256);
    hipLaunchKernelGGL(prologue, dim3(16, 16, 5), blk, 0, stream,
                       x, Wq, Wk, Wv, Wo, xb, wtb);

    hipLaunchKernelGGL(gemm_qkv192, dim3(256), dim3(512), 0, stream,
                       xb, wtb, bq, bk, bv, qbuf, kbuf, vtbuf);

    hipLaunchKernelGGL(attn_bf16, dim3(512), blk, 0, stream,
                       qbuf, kbuf, vtbuf, qbuf);

    hipLaunchKernelGGL(gemm_out8, dim3(Dm / 128, M / 128), blk, 0, stream,
                       qbuf, wtb + 3ull * Dm * Dm, bo, out);
}